// Round 1
// baseline (3921.202 us; speedup 1.0000x reference)
//
#include <hip/hip_runtime.h>
#include <hip/hip_bf16.h>
#include <math.h>

#define L_SEQ 2048
#define DM    2048
#define NH    16
#define DH    128
#define HVD   256
#define NPROJ 12320
#define GATE_OFF 8192
#define B_OFF    12288
#define A_OFF    12304

// ---------------- fp32 GEMM: proj = hidden(4096x2048) @ W(2048x12320) ----------------
#define BM 128
#define BN 128
#define BK 16

__global__ __launch_bounds__(256) void gemm_f32_k(
    const float* __restrict__ A, const float* __restrict__ B, float* __restrict__ C,
    int M, int N, int K)
{
  __shared__ float As[BK][BM];
  __shared__ float Bs[BK][BN];
  const int tid = threadIdx.x;
  const int tx = tid & 15, ty = tid >> 4;
  const int m0 = blockIdx.y * BM;
  const int n0 = blockIdx.x * BN;
  float acc[8][8];
#pragma unroll
  for (int i = 0; i < 8; ++i)
#pragma unroll
    for (int j = 0; j < 8; ++j) acc[i][j] = 0.f;

  for (int k0 = 0; k0 < K; k0 += BK) {
#pragma unroll
    for (int l = 0; l < 2; ++l) {
      int s = tid + l * 256;          // 0..511 float4 slots of A tile (128x16)
      int row = s >> 2;
      int k4 = (s & 3) << 2;
      float4 av = *(const float4*)(A + (size_t)(m0 + row) * K + (k0 + k4));
      As[k4 + 0][row] = av.x; As[k4 + 1][row] = av.y;
      As[k4 + 2][row] = av.z; As[k4 + 3][row] = av.w;
    }
#pragma unroll
    for (int l = 0; l < 2; ++l) {
      int s = tid + l * 256;          // 0..511 float4 slots of B tile (16x128)
      int kr = s >> 5;
      int n4 = (s & 31) << 2;
      int n = n0 + n4;
      float4 bv = make_float4(0.f, 0.f, 0.f, 0.f);
      if (n < N) bv = *(const float4*)(B + (size_t)(k0 + kr) * N + n);
      *(float4*)&Bs[kr][n4] = bv;
    }
    __syncthreads();
#pragma unroll
    for (int kk = 0; kk < BK; ++kk) {
      float a[8], b[8];
      *(float4*)&a[0] = *(float4*)&As[kk][ty * 8];
      *(float4*)&a[4] = *(float4*)&As[kk][ty * 8 + 4];
      *(float4*)&b[0] = *(float4*)&Bs[kk][tx * 8];
      *(float4*)&b[4] = *(float4*)&Bs[kk][tx * 8 + 4];
#pragma unroll
      for (int i = 0; i < 8; ++i)
#pragma unroll
        for (int j = 0; j < 8; ++j) acc[i][j] = fmaf(a[i], b[j], acc[i][j]);
    }
    __syncthreads();
  }
#pragma unroll
  for (int i = 0; i < 8; ++i) {
    int m = m0 + ty * 8 + i;
#pragma unroll
    for (int j4 = 0; j4 < 8; j4 += 4) {
      int n = n0 + tx * 8 + j4;
      if (n < N) {
        float4 v = make_float4(acc[i][j4], acc[i][j4 + 1], acc[i][j4 + 2], acc[i][j4 + 3]);
        *(float4*)(C + (size_t)m * N + n) = v;
      }
    }
  }
}

// ------------- fused causal depthwise conv(4) + SiLU + l2norm(q,k) + q-scale -------------
// grid: (tchunk=8, cc=64, b=2), block 128. Each block: 128 channels x 256 timesteps.
__global__ __launch_bounds__(128) void conv_norm_k(
    const float* __restrict__ proj, const float* __restrict__ Wc,
    float* __restrict__ qn, float* __restrict__ kn, float* __restrict__ vn)
{
  const int b = blockIdx.z, cc = blockIdx.y, tc = blockIdx.x;
  const int tid = threadIdx.x;
  const int ch = cc * 128 + tid;            // 0..8191
  const float W0 = Wc[ch * 4 + 0], W1 = Wc[ch * 4 + 1], W2 = Wc[ch * 4 + 2], W3 = Wc[ch * 4 + 3];
  const int t0 = tc * 256;
  const float* P = proj + (size_t)b * L_SEQ * NPROJ + ch;

  float w0 = (t0 - 3 >= 0) ? P[(size_t)(t0 - 3) * NPROJ] : 0.f;
  float w1 = (t0 - 2 >= 0) ? P[(size_t)(t0 - 2) * NPROJ] : 0.f;
  float w2 = (t0 - 1 >= 0) ? P[(size_t)(t0 - 1) * NPROJ] : 0.f;

  const bool isq = (ch < 2048);
  const bool isk = (ch >= 2048 && ch < 4096);
  __shared__ float red[2][2];

  // store base pointers
  float* qdst = nullptr; float* kdst = nullptr; float* vdst = nullptr;
  if (isq) {
    int h = cc;               // 0..15
    qdst = qn + (((size_t)b * NH + h) * L_SEQ) * DH + tid;
  } else if (isk) {
    int h = cc - 16;
    kdst = kn + (((size_t)b * NH + h) * L_SEQ) * DH + tid;
  } else {
    int vc = ch - 4096;       // 0..4095
    int h = vc >> 8;
    int vcol = vc & 255;
    vdst = vn + (((size_t)b * NH + h) * L_SEQ) * HVD + vcol;
  }
  const float qscale = 0.08838834764831845f;  // 128^-0.5

  for (int t = t0; t < t0 + 256; ++t) {
    float x = P[(size_t)t * NPROJ];
    float y = w0 * W0 + w1 * W1 + w2 * W2 + x * W3;
    w0 = w1; w1 = w2; w2 = x;
    y = y / (1.f + expf(-y));   // silu
    if (isq || isk) {
      float ss = y * y;
#pragma unroll
      for (int off = 1; off < 64; off <<= 1) ss += __shfl_xor(ss, off);
      int wv = tid >> 6;
      if ((tid & 63) == 0) red[t & 1][wv] = ss;
      __syncthreads();
      float tot = red[t & 1][0] + red[t & 1][1];
      float nrm = 1.f / sqrtf(tot + 1e-6f);
      float val = y * nrm;
      if (isq) { qdst[(size_t)t * DH] = val * qscale; }
      else     { kdst[(size_t)t * DH] = val; }
    } else {
      vdst[(size_t)t * HVD] = y;
    }
  }
}

// ------------- beta = sigmoid(b), eg = exp(-exp(A_log)*softplus(A+dt_bias)) -------------
__global__ __launch_bounds__(256) void beta_g_k(
    const float* __restrict__ proj, const float* __restrict__ A_log,
    const float* __restrict__ dt_bias, float* __restrict__ beta, float* __restrict__ eg)
{
  int idx = blockIdx.x * 256 + threadIdx.x;   // (b*16+h)*2048 + t
  if (idx >= 2 * NH * L_SEQ) return;
  int t = idx & (L_SEQ - 1);
  int h = (idx >> 11) & (NH - 1);
  int b = idx >> 15;
  size_t row = (size_t)(b * L_SEQ + t) * NPROJ;
  float bv = proj[row + B_OFF + h];
  float av = proj[row + A_OFF + h];
  float be = 1.f / (1.f + expf(-bv));
  float xx = av + dt_bias[h];
  float sp = (xx > 20.f) ? xx : log1pf(expf(xx));
  float g = -expf(A_log[h]) * sp;
  beta[idx] = be;
  eg[idx] = expf(g);
}

// ------------- gated delta-rule scan -------------
// grid 512 = (b*16 + h)*16 + vchunk ; block 256 = 16 cols x 16 ksegs
#define TC 32
__global__ __launch_bounds__(256) void scan_k(
    const float* __restrict__ qn, const float* __restrict__ kn, const float* __restrict__ vn,
    const float* __restrict__ eg_arr, const float* __restrict__ beta_arr,
    const float* __restrict__ proj, float* __restrict__ out)
{
  const int blk = blockIdx.x;
  const int vchunk = blk & 15;
  const int h = (blk >> 4) & 15;
  const int b = blk >> 8;
  const int tid = threadIdx.x;
  const int col = tid >> 4;    // 0..15 (16 consecutive lanes per col share ksegs)
  const int kseg = tid & 15;   // 0..15, 8 k-entries each

  float S[8] = {0.f, 0.f, 0.f, 0.f, 0.f, 0.f, 0.f, 0.f};

  __shared__ float k_s[TC][128];
  __shared__ float q_s[TC][128];
  __shared__ float v_s[TC][16];
  __shared__ float o_s[TC][16];
  __shared__ float eg_s[TC];
  __shared__ float be_s[TC];

  const size_t bh = (size_t)b * NH + h;
  const float* kp = kn + bh * L_SEQ * DH;
  const float* qp = qn + bh * L_SEQ * DH;
  const float* vp = vn + bh * L_SEQ * HVD + vchunk * 16;
  const float* egp = eg_arr + bh * L_SEQ;
  const float* bep = beta_arr + bh * L_SEQ;

  for (int tchunk = 0; tchunk < L_SEQ / TC; ++tchunk) {
    const int t0 = tchunk * TC;
    __syncthreads();   // all consumers of previous chunk done
    // stage k,q: TC*128 floats each -> 4 float4 per thread per array
#pragma unroll
    for (int l = 0; l < 4; ++l) {
      int s = tid + l * 256;        // 0..1023 float4 slots
      int tt = s >> 5;
      int d4 = (s & 31) << 2;
      *(float4*)&k_s[tt][d4] = *(const float4*)(kp + (size_t)(t0 + tt) * DH + d4);
      *(float4*)&q_s[tt][d4] = *(const float4*)(qp + (size_t)(t0 + tt) * DH + d4);
    }
    if (tid < 128) {                 // v: TC*16 = 512 floats = 128 float4
      int tt = tid >> 2;
      int c4 = (tid & 3) << 2;
      *(float4*)&v_s[tt][c4] = *(const float4*)(vp + (size_t)(t0 + tt) * HVD + c4);
    } else if (tid < 160) {
      int tt = tid - 128;
      eg_s[tt] = egp[t0 + tt];
      be_s[tt] = bep[t0 + tt];
    }
    __syncthreads();

    for (int tt = 0; tt < TC; ++tt) {
      float kk[8], qq[8];
      *(float4*)&kk[0] = *(float4*)&k_s[tt][kseg * 8];
      *(float4*)&kk[4] = *(float4*)&k_s[tt][kseg * 8 + 4];
      const float eg = eg_s[tt];
      const float be = be_s[tt];
      const float vt = v_s[tt][col];
      float kS = 0.f;
#pragma unroll
      for (int j = 0; j < 8; ++j) kS = fmaf(kk[j], S[j], kS);
      kS += __shfl_xor(kS, 1); kS += __shfl_xor(kS, 2);
      kS += __shfl_xor(kS, 4); kS += __shfl_xor(kS, 8);
      const float delta = (vt - eg * kS) * be;
      *(float4*)&qq[0] = *(float4*)&q_s[tt][kseg * 8];
      *(float4*)&qq[4] = *(float4*)&q_s[tt][kseg * 8 + 4];
      float o = 0.f;
#pragma unroll
      for (int j = 0; j < 8; ++j) {
        S[j] = fmaf(S[j], eg, kk[j] * delta);
        o = fmaf(qq[j], S[j], o);
      }
      o += __shfl_xor(o, 1); o += __shfl_xor(o, 2);
      o += __shfl_xor(o, 4); o += __shfl_xor(o, 8);
      if (kseg == 0) o_s[tt][col] = o;
    }
    __syncthreads();
    // flush with output gate: 512 elems, 2 per thread
#pragma unroll
    for (int l = 0; l < 2; ++l) {
      int s = tid + l * 256;
      int tt = s >> 4;
      int c = s & 15;
      int t = t0 + tt;
      float gv = proj[(size_t)(b * L_SEQ + t) * NPROJ + GATE_OFF + h * HVD + vchunk * 16 + c];
      float sg = gv / (1.f + expf(-gv));
      out[((size_t)(b * L_SEQ + t) * NH + h) * HVD + vchunk * 16 + c] = o_s[tt][c] * sg;
    }
  }
}

extern "C" void kernel_launch(void* const* d_in, const int* in_sizes, int n_in,
                              void* d_out, int out_size, void* d_ws, size_t ws_size,
                              hipStream_t stream) {
  const float* hidden  = (const float*)d_in[0];   // (2,2048,2048)
  const float* W       = (const float*)d_in[1];   // (2048,12320)
  const float* Wc      = (const float*)d_in[2];   // (8192,4)
  const float* A_log   = (const float*)d_in[3];   // (16,)
  const float* dt_bias = (const float*)d_in[4];   // (16,)
  float* out = (float*)d_out;

  float* ws = (float*)d_ws;
  float* proj = ws;                                  // 50,462,720
  float* qn   = proj + (size_t)2 * L_SEQ * NPROJ;    //  8,388,608
  float* kn   = qn + (size_t)2 * NH * L_SEQ * DH;    //  8,388,608
  float* vn   = kn + (size_t)2 * NH * L_SEQ * DH;    // 16,777,216
  float* eg   = vn + (size_t)2 * NH * L_SEQ * HVD;   //     65,536
  float* beta = eg + (size_t)2 * NH * L_SEQ;         //     65,536

  // 1) projection GEMM
  dim3 g1((NPROJ + BN - 1) / BN, (2 * L_SEQ) / BM);  // (97, 32)
  gemm_f32_k<<<g1, 256, 0, stream>>>(hidden, W, proj, 2 * L_SEQ, NPROJ, DM);

  // 2) conv + silu + l2norm
  dim3 g2(8, 64, 2);
  conv_norm_k<<<g2, 128, 0, stream>>>(proj, Wc, qn, kn, vn);

  // 3) beta / eg
  beta_g_k<<<(2 * NH * L_SEQ + 255) / 256, 256, 0, stream>>>(proj, A_log, dt_bias, beta, eg);

  // 4) recurrence + output gating
  scan_k<<<512, 256, 0, stream>>>(qn, kn, vn, eg, beta, proj, out);
}

// Round 2
// 1792.382 us; speedup vs baseline: 2.1877x; 2.1877x over previous
//
#include <hip/hip_runtime.h>
#include <hip/hip_bf16.h>
#include <hip/hip_fp16.h>
#include <math.h>

#define L_SEQ 2048
#define DM    2048
#define NH    16
#define DH    128
#define HVD   256
#define NPROJ 12320
#define GATE_OFF 8192
#define B_OFF    12288
#define A_OFF    12304

#define NTILE_N 97          // ceil(12320/128)
#define KSTEPS  64          // 2048/32

typedef _Float16 v8h __attribute__((ext_vector_type(8)));
typedef float f32x4 __attribute__((ext_vector_type(4)));

__device__ inline void gload_lds16(const void* g, void* l) {
  __builtin_amdgcn_global_load_lds((const __attribute__((address_space(1))) void*)g,
                                   (__attribute__((address_space(3))) void*)l, 16, 0, 0);
}

// ---------------- pack A: hidden(4096x2048) f32 -> Ap[mtile][kstep][hi/lo][g][row][8] fp16, x16 ----
__global__ __launch_bounds__(256) void pack_A_k(const float* __restrict__ H, _Float16* __restrict__ Ap) {
  const int mtile = blockIdx.x >> 6, kstep = blockIdx.x & 63;
  const size_t base = (size_t)blockIdx.x * 2 * 4096;   // halfs
#pragma unroll
  for (int it = 0; it < 2; ++it) {
    int s = threadIdx.x + it * 256;     // 0..511
    int g = s >> 7, r = s & 127;
    const float* src = H + ((size_t)(mtile * 128 + r)) * 2048 + kstep * 32 + g * 8;
    float4 x0 = *(const float4*)src;
    float4 x1 = *(const float4*)(src + 4);
    float xs[8] = {x0.x, x0.y, x0.z, x0.w, x1.x, x1.y, x1.z, x1.w};
    v8h hi, lo;
#pragma unroll
    for (int j = 0; j < 8; ++j) {
      float v = xs[j] * 16.f;
      _Float16 h = (_Float16)v;
      hi[j] = h;
      lo[j] = (_Float16)(v - (float)h);
    }
    *(v8h*)(Ap + base + g * 1024 + r * 8) = hi;
    *(v8h*)(Ap + base + 4096 + g * 1024 + r * 8) = lo;
  }
}

// ---------------- pack B: W(2048x12320) f32 -> Bp[ntile][kstep][hi/lo][g][col][8] fp16, x1024 ----
__global__ __launch_bounds__(256) void pack_B_k(const float* __restrict__ W, _Float16* __restrict__ Bp) {
  const int ntile = blockIdx.x >> 6, kstep = blockIdx.x & 63;
  const size_t base = (size_t)blockIdx.x * 2 * 4096;   // halfs
#pragma unroll
  for (int it = 0; it < 2; ++it) {
    int s = threadIdx.x + it * 256;
    int g = s >> 7, col = s & 127;
    int n = ntile * 128 + col;
    v8h hi, lo;
#pragma unroll
    for (int j = 0; j < 8; ++j) {
      int k = kstep * 32 + g * 8 + j;
      float v = (n < NPROJ) ? W[(size_t)k * NPROJ + n] * 1024.f : 0.f;
      _Float16 h = (_Float16)v;
      hi[j] = h;
      lo[j] = (_Float16)(v - (float)h);
    }
    *(v8h*)(Bp + base + g * 1024 + col * 8) = hi;
    *(v8h*)(Bp + base + 4096 + g * 1024 + col * 8) = lo;
  }
}

// ---------------- split-fp16 MFMA GEMM: proj = (A x16)(W x1024)/16384 ----------------
__global__ __launch_bounds__(256) void gemm_mfma_k(const _Float16* __restrict__ Ap,
                                                   const _Float16* __restrict__ Bp,
                                                   float* __restrict__ C) {
  __shared__ _Float16 lds[16384];   // 32KB: Ahi[0,4096) Alo[4096,8192) Bhi[8192,12288) Blo[12288,16384)
  const int tid = threadIdx.x;
  const int mtile = blockIdx.x & 31;
  const int ntile = blockIdx.x >> 5;
  const int wid = tid >> 6, lane = tid & 63;
  const int wm = wid >> 1, wn = wid & 1;
  const int lrow = lane & 15, g = lane >> 4;

  f32x4 acc[4][4];
#pragma unroll
  for (int i = 0; i < 4; ++i)
#pragma unroll
    for (int j = 0; j < 4; ++j) acc[i][j] = (f32x4){0.f, 0.f, 0.f, 0.f};

  const int aoff = (wm * 64 + lrow) * 8 + g * 1024;      // halfs within tile
  const int boff = (wn * 64 + lrow) * 8 + g * 1024;

  for (int kstep = 0; kstep < KSTEPS; ++kstep) {
    const size_t Ab = ((size_t)(mtile * KSTEPS + kstep) * 2) * 4096;
    const size_t Bb = ((size_t)(ntile * KSTEPS + kstep) * 2) * 4096;
    __syncthreads();
#pragma unroll
    for (int r = 0; r < 4; ++r)
      gload_lds16(Ap + Ab + r * 2048 + tid * 8, &lds[r * 2048 + tid * 8]);
#pragma unroll
    for (int r = 0; r < 4; ++r)
      gload_lds16(Bp + Bb + r * 2048 + tid * 8, &lds[8192 + r * 2048 + tid * 8]);
    __syncthreads();

    v8h ah[4], al[4], bh[4], bl[4];
#pragma unroll
    for (int f = 0; f < 4; ++f) {
      ah[f] = *(const v8h*)&lds[aoff + f * 128];              // f*16 rows * 8 halfs
      al[f] = *(const v8h*)&lds[4096 + aoff + f * 128];
      bh[f] = *(const v8h*)&lds[8192 + boff + f * 128];
      bl[f] = *(const v8h*)&lds[12288 + boff + f * 128];
    }
#pragma unroll
    for (int fm = 0; fm < 4; ++fm)
#pragma unroll
      for (int fn = 0; fn < 4; ++fn) {
        acc[fm][fn] = __builtin_amdgcn_mfma_f32_16x16x32_f16(ah[fm], bh[fn], acc[fm][fn], 0, 0, 0);
        acc[fm][fn] = __builtin_amdgcn_mfma_f32_16x16x32_f16(ah[fm], bl[fn], acc[fm][fn], 0, 0, 0);
        acc[fm][fn] = __builtin_amdgcn_mfma_f32_16x16x32_f16(al[fm], bh[fn], acc[fm][fn], 0, 0, 0);
      }
  }

  const float sc = 1.f / 16384.f;
#pragma unroll
  for (int fm = 0; fm < 4; ++fm) {
    int row = mtile * 128 + wm * 64 + fm * 16 + g * 4;
#pragma unroll
    for (int fn = 0; fn < 4; ++fn) {
      int col = ntile * 128 + wn * 64 + fn * 16 + lrow;
      if (col < NPROJ) {
#pragma unroll
        for (int r = 0; r < 4; ++r)
          C[(size_t)(row + r) * NPROJ + col] = acc[fm][fn][r] * sc;
      }
    }
  }
}

// ------------- fused causal depthwise conv(4) + SiLU + l2norm(q,k) + q-scale -------------
__global__ __launch_bounds__(128) void conv_norm_k(
    const float* __restrict__ proj, const float* __restrict__ Wc,
    float* __restrict__ qn, float* __restrict__ kn, float* __restrict__ vn)
{
  const int b = blockIdx.z, cc = blockIdx.y, tc = blockIdx.x;
  const int tid = threadIdx.x;
  const int ch = cc * 128 + tid;            // 0..8191
  const float W0 = Wc[ch * 4 + 0], W1 = Wc[ch * 4 + 1], W2 = Wc[ch * 4 + 2], W3 = Wc[ch * 4 + 3];
  const int t0 = tc * 256;
  const float* P = proj + (size_t)b * L_SEQ * NPROJ + ch;

  float w0 = (t0 - 3 >= 0) ? P[(size_t)(t0 - 3) * NPROJ] : 0.f;
  float w1 = (t0 - 2 >= 0) ? P[(size_t)(t0 - 2) * NPROJ] : 0.f;
  float w2 = (t0 - 1 >= 0) ? P[(size_t)(t0 - 1) * NPROJ] : 0.f;

  const bool isq = (ch < 2048);
  const bool isk = (ch >= 2048 && ch < 4096);
  __shared__ float red[2][2];

  float* qdst = nullptr; float* kdst = nullptr; float* vdst = nullptr;
  if (isq) {
    int h = cc;
    qdst = qn + (((size_t)b * NH + h) * L_SEQ) * DH + tid;
  } else if (isk) {
    int h = cc - 16;
    kdst = kn + (((size_t)b * NH + h) * L_SEQ) * DH + tid;
  } else {
    int vc = ch - 4096;
    int h = vc >> 8;
    int vcol = vc & 255;
    vdst = vn + (((size_t)b * NH + h) * L_SEQ) * HVD + vcol;
  }
  const float qscale = 0.08838834764831845f;  // 128^-0.5

  for (int t = t0; t < t0 + 256; ++t) {
    float x = P[(size_t)t * NPROJ];
    float y = w0 * W0 + w1 * W1 + w2 * W2 + x * W3;
    w0 = w1; w1 = w2; w2 = x;
    y = y / (1.f + expf(-y));   // silu
    if (isq || isk) {
      float ss = y * y;
#pragma unroll
      for (int off = 1; off < 64; off <<= 1) ss += __shfl_xor(ss, off);
      int wv = tid >> 6;
      if ((tid & 63) == 0) red[t & 1][wv] = ss;
      __syncthreads();
      float tot = red[t & 1][0] + red[t & 1][1];
      float nrm = 1.f / sqrtf(tot + 1e-6f);
      float val = y * nrm;
      if (isq) { qdst[(size_t)t * DH] = val * qscale; }
      else     { kdst[(size_t)t * DH] = val; }
    } else {
      vdst[(size_t)t * HVD] = y;
    }
  }
}

// ------------- beta = sigmoid(b), eg = exp(g) -------------
__global__ __launch_bounds__(256) void beta_g_k(
    const float* __restrict__ proj, const float* __restrict__ A_log,
    const float* __restrict__ dt_bias, float* __restrict__ beta, float* __restrict__ eg)
{
  int idx = blockIdx.x * 256 + threadIdx.x;
  if (idx >= 2 * NH * L_SEQ) return;
  int t = idx & (L_SEQ - 1);
  int h = (idx >> 11) & (NH - 1);
  int b = idx >> 15;
  size_t row = (size_t)(b * L_SEQ + t) * NPROJ;
  float bv = proj[row + B_OFF + h];
  float av = proj[row + A_OFF + h];
  float be = 1.f / (1.f + expf(-bv));
  float xx = av + dt_bias[h];
  float sp = (xx > 20.f) ? xx : log1pf(expf(xx));
  float g = -expf(A_log[h]) * sp;
  beta[idx] = be;
  eg[idx] = expf(g);
}

// ------------- gated delta-rule scan -------------
#define TC 32
__global__ __launch_bounds__(256) void scan_k(
    const float* __restrict__ qn, const float* __restrict__ kn, const float* __restrict__ vn,
    const float* __restrict__ eg_arr, const float* __restrict__ beta_arr,
    const float* __restrict__ proj, float* __restrict__ out)
{
  const int blk = blockIdx.x;
  const int vchunk = blk & 15;
  const int h = (blk >> 4) & 15;
  const int b = blk >> 8;
  const int tid = threadIdx.x;
  const int col = tid >> 4;
  const int kseg = tid & 15;

  float S[8] = {0.f, 0.f, 0.f, 0.f, 0.f, 0.f, 0.f, 0.f};

  __shared__ float k_s[TC][128];
  __shared__ float q_s[TC][128];
  __shared__ float v_s[TC][16];
  __shared__ float o_s[TC][16];
  __shared__ float eg_s[TC];
  __shared__ float be_s[TC];

  const size_t bh = (size_t)b * NH + h;
  const float* kp = kn + bh * L_SEQ * DH;
  const float* qp = qn + bh * L_SEQ * DH;
  const float* vp = vn + bh * L_SEQ * HVD + vchunk * 16;
  const float* egp = eg_arr + bh * L_SEQ;
  const float* bep = beta_arr + bh * L_SEQ;

  for (int tchunk = 0; tchunk < L_SEQ / TC; ++tchunk) {
    const int t0 = tchunk * TC;
    __syncthreads();
#pragma unroll
    for (int l = 0; l < 4; ++l) {
      int s = tid + l * 256;
      int tt = s >> 5;
      int d4 = (s & 31) << 2;
      *(float4*)&k_s[tt][d4] = *(const float4*)(kp + (size_t)(t0 + tt) * DH + d4);
      *(float4*)&q_s[tt][d4] = *(const float4*)(qp + (size_t)(t0 + tt) * DH + d4);
    }
    if (tid < 128) {
      int tt = tid >> 2;
      int c4 = (tid & 3) << 2;
      *(float4*)&v_s[tt][c4] = *(const float4*)(vp + (size_t)(t0 + tt) * HVD + c4);
    } else if (tid < 160) {
      int tt = tid - 128;
      eg_s[tt] = egp[t0 + tt];
      be_s[tt] = bep[t0 + tt];
    }
    __syncthreads();

    for (int tt = 0; tt < TC; ++tt) {
      float kk[8], qq[8];
      *(float4*)&kk[0] = *(float4*)&k_s[tt][kseg * 8];
      *(float4*)&kk[4] = *(float4*)&k_s[tt][kseg * 8 + 4];
      const float eg = eg_s[tt];
      const float be = be_s[tt];
      const float vt = v_s[tt][col];
      float kS = 0.f;
#pragma unroll
      for (int j = 0; j < 8; ++j) kS = fmaf(kk[j], S[j], kS);
      kS += __shfl_xor(kS, 1); kS += __shfl_xor(kS, 2);
      kS += __shfl_xor(kS, 4); kS += __shfl_xor(kS, 8);
      const float delta = (vt - eg * kS) * be;
      *(float4*)&qq[0] = *(float4*)&q_s[tt][kseg * 8];
      *(float4*)&qq[4] = *(float4*)&q_s[tt][kseg * 8 + 4];
      float o = 0.f;
#pragma unroll
      for (int j = 0; j < 8; ++j) {
        S[j] = fmaf(S[j], eg, kk[j] * delta);
        o = fmaf(qq[j], S[j], o);
      }
      o += __shfl_xor(o, 1); o += __shfl_xor(o, 2);
      o += __shfl_xor(o, 4); o += __shfl_xor(o, 8);
      if (kseg == 0) o_s[tt][col] = o;
    }
    __syncthreads();
#pragma unroll
    for (int l = 0; l < 2; ++l) {
      int s = tid + l * 256;
      int tt = s >> 4;
      int c = s & 15;
      int t = t0 + tt;
      float gv = proj[(size_t)(b * L_SEQ + t) * NPROJ + GATE_OFF + h * HVD + vchunk * 16 + c];
      float sg = gv / (1.f + expf(-gv));
      out[((size_t)(b * L_SEQ + t) * NH + h) * HVD + vchunk * 16 + c] = o_s[tt][c] * sg;
    }
  }
}

extern "C" void kernel_launch(void* const* d_in, const int* in_sizes, int n_in,
                              void* d_out, int out_size, void* d_ws, size_t ws_size,
                              hipStream_t stream) {
  const float* hidden  = (const float*)d_in[0];
  const float* W       = (const float*)d_in[1];
  const float* Wc      = (const float*)d_in[2];
  const float* A_log   = (const float*)d_in[3];
  const float* dt_bias = (const float*)d_in[4];
  float* out = (float*)d_out;

  char* ws = (char*)d_ws;
  // packed region [0, 135.3MB) — dead after GEMM, aliased by qn/kn/vn/eg/beta
  _Float16* Ap = (_Float16*)ws;                                  // 2*4096*2048 halfs = 33.55MB
  _Float16* Bp = (_Float16*)(ws + (size_t)33554432);             // 2*12416*2048 halfs = 101.7MB
  float* proj = (float*)(ws + (size_t)33554432 + 101711872);     // 201.85MB
  // aliases over packed region:
  float* qn   = (float*)ws;                                      // 33.55MB
  float* kn   = qn + (size_t)2 * NH * L_SEQ * DH;                // 33.55MB
  float* vn   = kn + (size_t)2 * NH * L_SEQ * DH;                // 67.11MB
  float* eg   = vn + (size_t)2 * NH * L_SEQ * HVD;               // 0.26MB
  float* beta = eg + (size_t)2 * NH * L_SEQ;                     // 0.26MB

  // 1) pack A and B into hi/lo fp16 tile-native layout
  pack_A_k<<<32 * KSTEPS, 256, 0, stream>>>(hidden, Ap);
  pack_B_k<<<NTILE_N * KSTEPS, 256, 0, stream>>>(W, Bp);

  // 2) projection GEMM (split-fp16, 3-term MFMA)
  gemm_mfma_k<<<32 * NTILE_N, 256, 0, stream>>>(Ap, Bp, proj);

  // 3) conv + silu + l2norm
  dim3 g2(8, 64, 2);
  conv_norm_k<<<g2, 128, 0, stream>>>(proj, Wc, qn, kn, vn);

  // 4) beta / eg
  beta_g_k<<<(2 * NH * L_SEQ + 255) / 256, 256, 0, stream>>>(proj, A_log, dt_bias, beta, eg);

  // 5) recurrence + output gating
  scan_k<<<512, 256, 0, stream>>>(qn, kn, vn, eg, beta, proj, out);
}

// Round 3
// 1726.824 us; speedup vs baseline: 2.2708x; 1.0380x over previous
//
#include <hip/hip_runtime.h>
#include <hip/hip_bf16.h>
#include <hip/hip_fp16.h>
#include <math.h>

#define L_SEQ 2048
#define DM    2048
#define NH    16
#define DH    128
#define HVD   256
#define NPROJ 12320
#define GATE_OFF 8192
#define B_OFF    12288
#define A_OFF    12304

#define NTILE_N 97          // ceil(12320/128)
#define KSTEPS  64          // 2048/32

typedef _Float16 v8h __attribute__((ext_vector_type(8)));
typedef float f32x4 __attribute__((ext_vector_type(4)));

__device__ __forceinline__ void gload_lds16(const void* g, void* l) {
  __builtin_amdgcn_global_load_lds((const __attribute__((address_space(1))) void*)g,
                                   (__attribute__((address_space(3))) void*)l, 16, 0, 0);
}

// 16-lane full reduction via DPP row rotates (rows = 16 lanes on CDNA).
__device__ __forceinline__ float red16(float x) {
  x += __int_as_float(__builtin_amdgcn_update_dpp(0, __float_as_int(x), 0x121, 0xF, 0xF, false));
  x += __int_as_float(__builtin_amdgcn_update_dpp(0, __float_as_int(x), 0x122, 0xF, 0xF, false));
  x += __int_as_float(__builtin_amdgcn_update_dpp(0, __float_as_int(x), 0x124, 0xF, 0xF, false));
  x += __int_as_float(__builtin_amdgcn_update_dpp(0, __float_as_int(x), 0x128, 0xF, 0xF, false));
  return x;
}

// ---------------- pack A: hidden(4096x2048) f32 -> Ap[mtile][kstep][hi/lo][g][row][8] fp16, x16 ----
__global__ __launch_bounds__(256) void pack_A_k(const float* __restrict__ H, _Float16* __restrict__ Ap) {
  const int mtile = blockIdx.x >> 6, kstep = blockIdx.x & 63;
  const size_t base = (size_t)blockIdx.x * 2 * 4096;   // halfs
#pragma unroll
  for (int it = 0; it < 2; ++it) {
    int s = threadIdx.x + it * 256;     // 0..511
    int g = s >> 7, r = s & 127;
    const float* src = H + ((size_t)(mtile * 128 + r)) * 2048 + kstep * 32 + g * 8;
    float4 x0 = *(const float4*)src;
    float4 x1 = *(const float4*)(src + 4);
    float xs[8] = {x0.x, x0.y, x0.z, x0.w, x1.x, x1.y, x1.z, x1.w};
    v8h hi, lo;
#pragma unroll
    for (int j = 0; j < 8; ++j) {
      float v = xs[j] * 16.f;
      _Float16 h = (_Float16)v;
      hi[j] = h;
      lo[j] = (_Float16)(v - (float)h);
    }
    *(v8h*)(Ap + base + g * 1024 + r * 8) = hi;
    *(v8h*)(Ap + base + 4096 + g * 1024 + r * 8) = lo;
  }
}

// ---------------- pack B: W(2048x12320) f32 -> Bp[ntile][kstep][hi/lo][g][col][8] fp16, x1024 ----
__global__ __launch_bounds__(256) void pack_B_k(const float* __restrict__ W, _Float16* __restrict__ Bp) {
  const int ntile = blockIdx.x >> 6, kstep = blockIdx.x & 63;
  const size_t base = (size_t)blockIdx.x * 2 * 4096;   // halfs
#pragma unroll
  for (int it = 0; it < 2; ++it) {
    int s = threadIdx.x + it * 256;
    int g = s >> 7, col = s & 127;
    int n = ntile * 128 + col;
    v8h hi, lo;
#pragma unroll
    for (int j = 0; j < 8; ++j) {
      int k = kstep * 32 + g * 8 + j;
      float v = (n < NPROJ) ? W[(size_t)k * NPROJ + n] * 1024.f : 0.f;
      _Float16 h = (_Float16)v;
      hi[j] = h;
      lo[j] = (_Float16)(v - (float)h);
    }
    *(v8h*)(Bp + base + g * 1024 + col * 8) = hi;
    *(v8h*)(Bp + base + 4096 + g * 1024 + col * 8) = lo;
  }
}

// ---------------- split-fp16 MFMA GEMM: proj = (A x16)(W x1024)/16384 ----------------
__global__ __launch_bounds__(256) void gemm_mfma_k(const _Float16* __restrict__ Ap,
                                                   const _Float16* __restrict__ Bp,
                                                   float* __restrict__ C) {
  __shared__ _Float16 lds[16384];   // 32KB: Ahi Alo Bhi Blo
  const int tid = threadIdx.x;
  const int mtile = blockIdx.x & 31;
  const int ntile = blockIdx.x >> 5;
  const int wid = tid >> 6, lane = tid & 63;
  const int wm = wid >> 1, wn = wid & 1;
  const int lrow = lane & 15, g = lane >> 4;

  f32x4 acc[4][4];
#pragma unroll
  for (int i = 0; i < 4; ++i)
#pragma unroll
    for (int j = 0; j < 4; ++j) acc[i][j] = (f32x4){0.f, 0.f, 0.f, 0.f};

  const int aoff = (wm * 64 + lrow) * 8 + g * 1024;
  const int boff = (wn * 64 + lrow) * 8 + g * 1024;

  for (int kstep = 0; kstep < KSTEPS; ++kstep) {
    const size_t Ab = ((size_t)(mtile * KSTEPS + kstep) * 2) * 4096;
    const size_t Bb = ((size_t)(ntile * KSTEPS + kstep) * 2) * 4096;
    __syncthreads();
#pragma unroll
    for (int r = 0; r < 4; ++r)
      gload_lds16(Ap + Ab + r * 2048 + tid * 8, &lds[r * 2048 + tid * 8]);
#pragma unroll
    for (int r = 0; r < 4; ++r)
      gload_lds16(Bp + Bb + r * 2048 + tid * 8, &lds[8192 + r * 2048 + tid * 8]);
    __syncthreads();

    v8h ah[4], al[4], bh[4], bl[4];
#pragma unroll
    for (int f = 0; f < 4; ++f) {
      ah[f] = *(const v8h*)&lds[aoff + f * 128];
      al[f] = *(const v8h*)&lds[4096 + aoff + f * 128];
      bh[f] = *(const v8h*)&lds[8192 + boff + f * 128];
      bl[f] = *(const v8h*)&lds[12288 + boff + f * 128];
    }
#pragma unroll
    for (int fm = 0; fm < 4; ++fm)
#pragma unroll
      for (int fn = 0; fn < 4; ++fn) {
        acc[fm][fn] = __builtin_amdgcn_mfma_f32_16x16x32_f16(ah[fm], bh[fn], acc[fm][fn], 0, 0, 0);
        acc[fm][fn] = __builtin_amdgcn_mfma_f32_16x16x32_f16(ah[fm], bl[fn], acc[fm][fn], 0, 0, 0);
        acc[fm][fn] = __builtin_amdgcn_mfma_f32_16x16x32_f16(al[fm], bh[fn], acc[fm][fn], 0, 0, 0);
      }
  }

  const float sc = 1.f / 16384.f;
#pragma unroll
  for (int fm = 0; fm < 4; ++fm) {
    int row = mtile * 128 + wm * 64 + fm * 16 + g * 4;
#pragma unroll
    for (int fn = 0; fn < 4; ++fn) {
      int col = ntile * 128 + wn * 64 + fn * 16 + lrow;
      if (col < NPROJ) {
#pragma unroll
        for (int r = 0; r < 4; ++r)
          C[(size_t)(row + r) * NPROJ + col] = acc[fm][fn][r] * sc;
      }
    }
  }
}

// ------------- fused causal depthwise conv(4) + SiLU + l2norm(q,k) + q-scale -------------
__global__ __launch_bounds__(128) void conv_norm_k(
    const float* __restrict__ proj, const float* __restrict__ Wc,
    float* __restrict__ qn, float* __restrict__ kn, float* __restrict__ vn)
{
  const int b = blockIdx.z, cc = blockIdx.y, tc = blockIdx.x;
  const int tid = threadIdx.x;
  const int ch = cc * 128 + tid;
  const float W0 = Wc[ch * 4 + 0], W1 = Wc[ch * 4 + 1], W2 = Wc[ch * 4 + 2], W3 = Wc[ch * 4 + 3];
  const int t0 = tc * 256;
  const float* P = proj + (size_t)b * L_SEQ * NPROJ + ch;

  float w0 = (t0 - 3 >= 0) ? P[(size_t)(t0 - 3) * NPROJ] : 0.f;
  float w1 = (t0 - 2 >= 0) ? P[(size_t)(t0 - 2) * NPROJ] : 0.f;
  float w2 = (t0 - 1 >= 0) ? P[(size_t)(t0 - 1) * NPROJ] : 0.f;

  const bool isq = (ch < 2048);
  const bool isk = (ch >= 2048 && ch < 4096);
  __shared__ float red[2][2];

  float* qdst = nullptr; float* kdst = nullptr; float* vdst = nullptr;
  if (isq) {
    int h = cc;
    qdst = qn + (((size_t)b * NH + h) * L_SEQ) * DH + tid;
  } else if (isk) {
    int h = cc - 16;
    kdst = kn + (((size_t)b * NH + h) * L_SEQ) * DH + tid;
  } else {
    int vc = ch - 4096;
    int h = vc >> 8;
    int vcol = vc & 255;
    vdst = vn + (((size_t)b * NH + h) * L_SEQ) * HVD + vcol;
  }
  const float qscale = 0.08838834764831845f;

  for (int t = t0; t < t0 + 256; ++t) {
    float x = P[(size_t)t * NPROJ];
    float y = w0 * W0 + w1 * W1 + w2 * W2 + x * W3;
    w0 = w1; w1 = w2; w2 = x;
    y = y / (1.f + expf(-y));
    if (isq || isk) {
      float ss = y * y;
#pragma unroll
      for (int off = 1; off < 64; off <<= 1) ss += __shfl_xor(ss, off);
      int wv = tid >> 6;
      if ((tid & 63) == 0) red[t & 1][wv] = ss;
      __syncthreads();
      float tot = red[t & 1][0] + red[t & 1][1];
      float nrm = 1.f / sqrtf(tot + 1e-6f);
      float val = y * nrm;
      if (isq) { qdst[(size_t)t * DH] = val * qscale; }
      else     { kdst[(size_t)t * DH] = val; }
    } else {
      vdst[(size_t)t * HVD] = y;
    }
  }
}

// ------------- beta = sigmoid(b), eg = exp(g) -------------
__global__ __launch_bounds__(256) void beta_g_k(
    const float* __restrict__ proj, const float* __restrict__ A_log,
    const float* __restrict__ dt_bias, float* __restrict__ beta, float* __restrict__ eg)
{
  int idx = blockIdx.x * 256 + threadIdx.x;
  if (idx >= 2 * NH * L_SEQ) return;
  int t = idx & (L_SEQ - 1);
  int h = (idx >> 11) & (NH - 1);
  int b = idx >> 15;
  size_t row = (size_t)(b * L_SEQ + t) * NPROJ;
  float bv = proj[row + B_OFF + h];
  float av = proj[row + A_OFF + h];
  float be = 1.f / (1.f + expf(-bv));
  float xx = av + dt_bias[h];
  float sp = (xx > 20.f) ? xx : log1pf(expf(xx));
  float g = -expf(A_log[h]) * sp;
  beta[idx] = be;
  eg[idx] = expf(g);
}

// ------------- gated delta-rule scan (DPP + double-buffered gload_lds pipeline) -------------
// grid 512; swizzled: group g=(b*16+h) in blockIdx&31, vchunk = blockIdx>>5 (same-XCD per group)
#define TC 16
#define NCHUNK (L_SEQ / TC)
__global__ __launch_bounds__(256) void scan_k(
    const float* __restrict__ qn, const float* __restrict__ kn, const float* __restrict__ vn,
    const float* __restrict__ eg_arr, const float* __restrict__ beta_arr,
    const float* __restrict__ proj, float* __restrict__ out)
{
  const int j = blockIdx.x;
  const int grp = j & 31;           // b*16+h  (j%8 const per grp -> same XCD)
  const int vchunk = j >> 5;        // 0..15
  const int h = grp & 15;
  const int b = grp >> 4;
  const int tid = threadIdx.x;
  const int wid = tid >> 6, lane = tid & 63;
  const int col = tid >> 4;         // 0..15
  const int kseg = tid & 15;        // 0..15

  __shared__ float k_s[2][TC * 128];
  __shared__ float q_s[2][TC * 128];
  __shared__ float v_s[2][TC * 16];
  __shared__ float g_s[2][TC * 16];
  __shared__ float eg_s[L_SEQ];
  __shared__ float be_s[L_SEQ];

  const size_t bh = (size_t)b * NH + h;
  const float* kp = kn + bh * L_SEQ * DH;
  const float* qp = qn + bh * L_SEQ * DH;
  const float* vp = vn + bh * L_SEQ * HVD + vchunk * 16;
  const float* gp = proj + ((size_t)b * L_SEQ) * NPROJ + GATE_OFF + h * HVD + vchunk * 16;
  const float* egp = eg_arr + bh * L_SEQ;
  const float* bep = beta_arr + bh * L_SEQ;
  float* outp = out + (((size_t)b * L_SEQ) * NH + h) * HVD + vchunk * 16 + col;

  float S[8] = {0.f, 0.f, 0.f, 0.f, 0.f, 0.f, 0.f, 0.f};

  // prologue: eg/be full preload + chunk 0 stage
#pragma unroll
  for (int l = 0; l < 2; ++l) {
    int s = tid + l * 256;          // 0..511 float4 slots over 2048 floats
    gload_lds16(egp + s * 4, &eg_s[s * 4]);
    gload_lds16(bep + s * 4, &be_s[s * 4]);
  }
  {
#pragma unroll
    for (int l = 0; l < 2; ++l) {
      int s = tid + l * 256;        // 0..511: row=s>>5, u=s&31 -> kseg=u&15, j4=u>>4
      int row = s >> 5, u = s & 31;
      int srcoff = row * DH + (u & 15) * 8 + (u >> 4) * 4;
      gload_lds16(kp + srcoff, &k_s[0][s * 4]);
      gload_lds16(qp + srcoff, &q_s[0][s * 4]);
    }
    if (wid == 2) gload_lds16(vp + (size_t)(lane >> 2) * HVD + (lane & 3) * 4, &v_s[0][lane * 4]);
    if (wid == 3) gload_lds16(gp + (size_t)(lane >> 2) * NPROJ + (lane & 3) * 4, &g_s[0][lane * 4]);
  }

  for (int c = 0; c < NCHUNK; ++c) {
    __syncthreads();                // drains outstanding gloads (chunk c ready)
    const int p = c & 1;
    if (c + 1 < NCHUNK) {           // prefetch chunk c+1 into buf p^1
      const int t1 = (c + 1) * TC;
#pragma unroll
      for (int l = 0; l < 2; ++l) {
        int s = tid + l * 256;
        int row = s >> 5, u = s & 31;
        int srcoff = (t1 + row) * DH + (u & 15) * 8 + (u >> 4) * 4;
        gload_lds16(kp + srcoff, &k_s[p ^ 1][s * 4]);
        gload_lds16(qp + srcoff, &q_s[p ^ 1][s * 4]);
      }
      if (wid == 2) gload_lds16(vp + (size_t)(t1 + (lane >> 2)) * HVD + (lane & 3) * 4, &v_s[p ^ 1][lane * 4]);
      if (wid == 3) gload_lds16(gp + (size_t)(t1 + (lane >> 2)) * NPROJ + (lane & 3) * 4, &g_s[p ^ 1][lane * 4]);
    }
    const int t0 = c * TC;
#pragma unroll 4
    for (int tt = 0; tt < TC; ++tt) {
      const float* kr = &k_s[p][(tt * 32 + kseg) * 4];
      const float* qr = &q_s[p][(tt * 32 + kseg) * 4];
      float4 k0 = *(const float4*)kr;
      float4 k1 = *(const float4*)(kr + 64);
      float4 q0 = *(const float4*)qr;
      float4 q1 = *(const float4*)(qr + 64);
      const float egt = eg_s[t0 + tt];
      const float bet = be_s[t0 + tt];
      const float vt = v_s[p][tt * 16 + col];
      // kS = k . S  (pairwise fma tree, then 16-lane DPP reduce)
      float a0 = fmaf(k0.x, S[0], k0.y * S[1]);
      float a1 = fmaf(k0.z, S[2], k0.w * S[3]);
      float a2 = fmaf(k1.x, S[4], k1.y * S[5]);
      float a3 = fmaf(k1.z, S[6], k1.w * S[7]);
      float kS = red16((a0 + a1) + (a2 + a3));
      const float delta = fmaf(-egt, kS, vt) * bet;
      // S update + o
      S[0] = fmaf(S[0], egt, k0.x * delta);
      S[1] = fmaf(S[1], egt, k0.y * delta);
      S[2] = fmaf(S[2], egt, k0.z * delta);
      S[3] = fmaf(S[3], egt, k0.w * delta);
      S[4] = fmaf(S[4], egt, k1.x * delta);
      S[5] = fmaf(S[5], egt, k1.y * delta);
      S[6] = fmaf(S[6], egt, k1.z * delta);
      S[7] = fmaf(S[7], egt, k1.w * delta);
      float o0 = fmaf(q0.x, S[0], q0.y * S[1]);
      float o1 = fmaf(q0.z, S[2], q0.w * S[3]);
      float o2 = fmaf(q1.x, S[4], q1.y * S[5]);
      float o3 = fmaf(q1.z, S[6], q1.w * S[7]);
      float o = red16((o0 + o1) + (o2 + o3));
      if (kseg == 0) {
        float gv = g_s[p][tt * 16 + col];
        float sg = gv / (1.f + expf(-gv));
        outp[(size_t)(t0 + tt) * (NH * HVD)] = o * sg;
      }
    }
  }
}

extern "C" void kernel_launch(void* const* d_in, const int* in_sizes, int n_in,
                              void* d_out, int out_size, void* d_ws, size_t ws_size,
                              hipStream_t stream) {
  const float* hidden  = (const float*)d_in[0];
  const float* W       = (const float*)d_in[1];
  const float* Wc      = (const float*)d_in[2];
  const float* A_log   = (const float*)d_in[3];
  const float* dt_bias = (const float*)d_in[4];
  float* out = (float*)d_out;

  char* ws = (char*)d_ws;
  _Float16* Ap = (_Float16*)ws;
  _Float16* Bp = (_Float16*)(ws + (size_t)33554432);
  float* proj = (float*)(ws + (size_t)33554432 + 101711872);
  float* qn   = (float*)ws;
  float* kn   = qn + (size_t)2 * NH * L_SEQ * DH;
  float* vn   = kn + (size_t)2 * NH * L_SEQ * DH;
  float* eg   = vn + (size_t)2 * NH * L_SEQ * HVD;
  float* beta = eg + (size_t)2 * NH * L_SEQ;

  pack_A_k<<<32 * KSTEPS, 256, 0, stream>>>(hidden, Ap);
  pack_B_k<<<NTILE_N * KSTEPS, 256, 0, stream>>>(W, Bp);
  gemm_mfma_k<<<32 * NTILE_N, 256, 0, stream>>>(Ap, Bp, proj);

  dim3 g2(8, 64, 2);
  conv_norm_k<<<g2, 128, 0, stream>>>(proj, Wc, qn, kn, vn);
  beta_g_k<<<(2 * NH * L_SEQ + 255) / 256, 256, 0, stream>>>(proj, A_log, dt_bias, beta, eg);

  scan_k<<<512, 256, 0, stream>>>(qn, kn, vn, eg, beta, proj, out);
}

// Round 5
// 1357.570 us; speedup vs baseline: 2.8884x; 1.2720x over previous
//
#include <hip/hip_runtime.h>
#include <hip/hip_bf16.h>
#include <hip/hip_fp16.h>
#include <math.h>

#define L_SEQ 2048
#define DM    2048
#define NH    16
#define DH    128
#define HVD   256
#define NPROJ 12320
#define QKVW  8192
#define GW    4128

#define NTILE_N 97
#define KSTEPS  64

typedef _Float16 v8h __attribute__((ext_vector_type(8)));
typedef float f32x4 __attribute__((ext_vector_type(4)));

__device__ __forceinline__ void gload_lds16(const void* g, void* l) {
  __builtin_amdgcn_global_load_lds((const __attribute__((address_space(1))) void*)g,
                                   (__attribute__((address_space(3))) void*)l, 16, 0, 0);
}

__device__ __forceinline__ void splitw(float x, unsigned short& h, unsigned short& l) {
  _Float16 hh = (_Float16)x;
  _Float16 ll = (_Float16)(x - (float)hh);
  h = *(unsigned short*)&hh;
  l = *(unsigned short*)&ll;
}
__device__ __forceinline__ float h2f(unsigned short u) {
  return (float)(*(_Float16*)&u);
}

#define MFMA3(acc, ah, al, bh_, bl_)                                          \
  acc = __builtin_amdgcn_mfma_f32_16x16x32_f16(ah, bh_, acc, 0, 0, 0);        \
  acc = __builtin_amdgcn_mfma_f32_16x16x32_f16(ah, bl_, acc, 0, 0, 0);        \
  acc = __builtin_amdgcn_mfma_f32_16x16x32_f16(al, bh_, acc, 0, 0, 0);

// ---------------- pack A: hidden(4096x2048) f32 -> fp16 hi/lo, x16 ----------------
__global__ __launch_bounds__(256) void pack_A_k(const float* __restrict__ H, _Float16* __restrict__ Ap) {
  const int mtile = blockIdx.x >> 6, kstep = blockIdx.x & 63;
  const size_t base = (size_t)blockIdx.x * 2 * 4096;
#pragma unroll
  for (int it = 0; it < 2; ++it) {
    int s = threadIdx.x + it * 256;
    int g = s >> 7, r = s & 127;
    const float* src = H + ((size_t)(mtile * 128 + r)) * 2048 + kstep * 32 + g * 8;
    float4 x0 = *(const float4*)src;
    float4 x1 = *(const float4*)(src + 4);
    float xs[8] = {x0.x, x0.y, x0.z, x0.w, x1.x, x1.y, x1.z, x1.w};
    v8h hi, lo;
#pragma unroll
    for (int j = 0; j < 8; ++j) {
      float v = xs[j] * 16.f;
      _Float16 h = (_Float16)v;
      hi[j] = h;
      lo[j] = (_Float16)(v - (float)h);
    }
    *(v8h*)(Ap + base + g * 1024 + r * 8) = hi;
    *(v8h*)(Ap + base + 4096 + g * 1024 + r * 8) = lo;
  }
}

// ---------------- pack B: W(2048x12320) f32 -> fp16 hi/lo, x1024 ----------------
__global__ __launch_bounds__(256) void pack_B_k(const float* __restrict__ W, _Float16* __restrict__ Bp) {
  const int ntile = blockIdx.x >> 6, kstep = blockIdx.x & 63;
  const size_t base = (size_t)blockIdx.x * 2 * 4096;
#pragma unroll
  for (int it = 0; it < 2; ++it) {
    int s = threadIdx.x + it * 256;
    int g = s >> 7, col = s & 127;
    int n = ntile * 128 + col;
    v8h hi, lo;
#pragma unroll
    for (int j = 0; j < 8; ++j) {
      int k = kstep * 32 + g * 8 + j;
      float v = (n < NPROJ) ? W[(size_t)k * NPROJ + n] * 1024.f : 0.f;
      _Float16 h = (_Float16)v;
      hi[j] = h;
      lo[j] = (_Float16)(v - (float)h);
    }
    *(v8h*)(Bp + base + g * 1024 + col * 8) = hi;
    *(v8h*)(Bp + base + 4096 + g * 1024 + col * 8) = lo;
  }
}

// ---------------- split-fp16 MFMA GEMM: qkv cols -> Cq (stride 8192), gate/bA -> Cg (stride 4128) ----
__global__ __launch_bounds__(256) void gemm_mfma_k(const _Float16* __restrict__ Ap,
                                                   const _Float16* __restrict__ Bp,
                                                   float* __restrict__ Cq,
                                                   float* __restrict__ Cg) {
  __shared__ _Float16 lds[16384];
  const int tid = threadIdx.x;
  const int mtile = blockIdx.x & 31;
  const int ntile = blockIdx.x >> 5;
  const int wid = tid >> 6, lane = tid & 63;
  const int wm = wid >> 1, wn = wid & 1;
  const int lrow = lane & 15, g = lane >> 4;

  f32x4 acc[4][4];
#pragma unroll
  for (int i = 0; i < 4; ++i)
#pragma unroll
    for (int j = 0; j < 4; ++j) acc[i][j] = (f32x4){0.f, 0.f, 0.f, 0.f};

  const int aoff = (wm * 64 + lrow) * 8 + g * 1024;
  const int boff = (wn * 64 + lrow) * 8 + g * 1024;

  for (int kstep = 0; kstep < KSTEPS; ++kstep) {
    const size_t Ab = ((size_t)(mtile * KSTEPS + kstep) * 2) * 4096;
    const size_t Bb = ((size_t)(ntile * KSTEPS + kstep) * 2) * 4096;
    __syncthreads();
#pragma unroll
    for (int r = 0; r < 4; ++r)
      gload_lds16(Ap + Ab + r * 2048 + tid * 8, &lds[r * 2048 + tid * 8]);
#pragma unroll
    for (int r = 0; r < 4; ++r)
      gload_lds16(Bp + Bb + r * 2048 + tid * 8, &lds[8192 + r * 2048 + tid * 8]);
    __syncthreads();

    v8h ah[4], al[4], bh[4], bl[4];
#pragma unroll
    for (int f = 0; f < 4; ++f) {
      ah[f] = *(const v8h*)&lds[aoff + f * 128];
      al[f] = *(const v8h*)&lds[4096 + aoff + f * 128];
      bh[f] = *(const v8h*)&lds[8192 + boff + f * 128];
      bl[f] = *(const v8h*)&lds[12288 + boff + f * 128];
    }
#pragma unroll
    for (int fm = 0; fm < 4; ++fm)
#pragma unroll
      for (int fn = 0; fn < 4; ++fn) {
        acc[fm][fn] = __builtin_amdgcn_mfma_f32_16x16x32_f16(ah[fm], bh[fn], acc[fm][fn], 0, 0, 0);
        acc[fm][fn] = __builtin_amdgcn_mfma_f32_16x16x32_f16(ah[fm], bl[fn], acc[fm][fn], 0, 0, 0);
        acc[fm][fn] = __builtin_amdgcn_mfma_f32_16x16x32_f16(al[fm], bh[fn], acc[fm][fn], 0, 0, 0);
      }
  }

  const float sc = 1.f / 16384.f;
#pragma unroll
  for (int fm = 0; fm < 4; ++fm) {
    int row = mtile * 128 + wm * 64 + fm * 16 + g * 4;
#pragma unroll
    for (int fn = 0; fn < 4; ++fn) {
      int col = ntile * 128 + wn * 64 + fn * 16 + lrow;
      if (col < QKVW) {
#pragma unroll
        for (int r = 0; r < 4; ++r)
          Cq[(size_t)(row + r) * QKVW + col] = acc[fm][fn][r] * sc;
      } else if (col < NPROJ) {
        int lcol = col - QKVW;
#pragma unroll
        for (int r = 0; r < 4; ++r)
          Cg[(size_t)(row + r) * GW + lcol] = acc[fm][fn][r] * sc;
      }
    }
  }
}

// ------------- fused causal depthwise conv(4) + SiLU + l2norm(q,k) + q-scale -------------
__global__ __launch_bounds__(128) void conv_norm_k(
    const float* __restrict__ projQKV, const float* __restrict__ Wc,
    float* __restrict__ qn, float* __restrict__ kn, float* __restrict__ vn)
{
  const int b = blockIdx.z, cc = blockIdx.y, tc = blockIdx.x;
  const int tid = threadIdx.x;
  const int ch = cc * 128 + tid;
  const float W0 = Wc[ch * 4 + 0], W1 = Wc[ch * 4 + 1], W2 = Wc[ch * 4 + 2], W3 = Wc[ch * 4 + 3];
  const int t0 = tc * 256;
  const float* P = projQKV + (size_t)b * L_SEQ * QKVW + ch;

  float w0 = (t0 - 3 >= 0) ? P[(size_t)(t0 - 3) * QKVW] : 0.f;
  float w1 = (t0 - 2 >= 0) ? P[(size_t)(t0 - 2) * QKVW] : 0.f;
  float w2 = (t0 - 1 >= 0) ? P[(size_t)(t0 - 1) * QKVW] : 0.f;

  const bool isq = (ch < 2048);
  const bool isk = (ch >= 2048 && ch < 4096);
  __shared__ float red[2][2];

  float* qdst = nullptr; float* kdst = nullptr; float* vdst = nullptr;
  if (isq) {
    int h = cc;
    qdst = qn + (((size_t)b * NH + h) * L_SEQ) * DH + tid;
  } else if (isk) {
    int h = cc - 16;
    kdst = kn + (((size_t)b * NH + h) * L_SEQ) * DH + tid;
  } else {
    int vc = ch - 4096;
    int h = vc >> 8;
    int vcol = vc & 255;
    vdst = vn + (((size_t)b * NH + h) * L_SEQ) * HVD + vcol;
  }
  const float qscale = 0.08838834764831845f;

  for (int t = t0; t < t0 + 256; ++t) {
    float x = P[(size_t)t * QKVW];
    float y = w0 * W0 + w1 * W1 + w2 * W2 + x * W3;
    w0 = w1; w1 = w2; w2 = x;
    y = y / (1.f + expf(-y));
    if (isq || isk) {
      float ss = y * y;
#pragma unroll
      for (int off = 1; off < 64; off <<= 1) ss += __shfl_xor(ss, off);
      int wv = tid >> 6;
      if ((tid & 63) == 0) red[t & 1][wv] = ss;
      __syncthreads();
      float tot = red[t & 1][0] + red[t & 1][1];
      float nrm = 1.f / sqrtf(tot + 1e-6f);
      float val = y * nrm;
      if (isq) { qdst[(size_t)t * DH] = val * qscale; }
      else     { kdst[(size_t)t * DH] = val; }
    } else {
      vdst[(size_t)t * HVD] = y;
    }
  }
}

// ------------- beta = sigmoid(b), g = -exp(A_log)*softplus(A+dt_bias) -------------
__global__ __launch_bounds__(256) void beta_g_k(
    const float* __restrict__ projGate, const float* __restrict__ A_log,
    const float* __restrict__ dt_bias, float* __restrict__ beta, float* __restrict__ g_out)
{
  int idx = blockIdx.x * 256 + threadIdx.x;
  if (idx >= 2 * NH * L_SEQ) return;
  int t = idx & (L_SEQ - 1);
  int h = (idx >> 11) & (NH - 1);
  int b = idx >> 15;
  size_t row = (size_t)(b * L_SEQ + t) * GW;
  float bv = projGate[row + 4096 + h];
  float av = projGate[row + 4112 + h];
  float be = 1.f / (1.f + expf(-bv));
  float xx = av + dt_bias[h];
  float sp = (xx > 20.f) ? xx : log1pf(expf(xx));
  float g = -expf(A_log[h]) * sp;
  beta[idx] = be;
  g_out[idx] = g;
}

// ------------- Phase 1a: per-chunk T=(I+A)^-1, KT (kw-folded K^T), coef arrays -------------
// grid 1024 = bh*32 + chunk, block 256
__global__ __launch_bounds__(256) void p1a_k(
    const float* __restrict__ kn, const float* __restrict__ g_arr, const float* __restrict__ beta_arr,
    _Float16* __restrict__ Tg_h, _Float16* __restrict__ Tg_l,
    _Float16* __restrict__ KTg_h, _Float16* __restrict__ KTg_l,
    float* __restrict__ coefG)
{
  __shared__ _Float16 Kh[8192], Kl[8192];
  __shared__ float Am[4096], Tm[4096];
  __shared__ float lc[64], be[64], kw[64];
  const int cid = blockIdx.x, bh = cid >> 5, ch = cid & 31, t0 = ch * 64;
  const int tid = threadIdx.x, w = tid >> 6, lane = tid & 63, lr = lane & 15, g16 = lane >> 4;

  const float* kb = kn + ((size_t)bh * 2048 + t0) * 128;
#pragma unroll
  for (int l = 0; l < 8; ++l) {
    int s = tid + l * 256;
    int row = s >> 5, c = (s & 31) * 4;
    float4 v = *(const float4*)(kb + (size_t)row * 128 + c);
    ushort4 H, L;
    splitw(v.x * 1024.f, H.x, L.x); splitw(v.y * 1024.f, H.y, L.y);
    splitw(v.z * 1024.f, H.z, L.z); splitw(v.w * 1024.f, H.w, L.w);
    int ad = row * 128 + (c ^ ((row & 7) << 3));
    *(ushort4*)&Kh[ad] = H; *(ushort4*)&Kl[ad] = L;
  }
#pragma unroll
  for (int l = 0; l < 16; ++l) { int s2 = tid + l * 256; Tm[s2] = ((s2 >> 6) == (s2 & 63)) ? 1.f : 0.f; }
  if (tid < 64) {
    float x = g_arr[(size_t)bh * 2048 + t0 + tid];
#pragma unroll
    for (int off = 1; off < 64; off <<= 1) { float y = __shfl_up(x, off); if (tid >= off) x += y; }
    lc[tid] = x;
    float x63 = __shfl(x, 63);
    float b_ = beta_arr[(size_t)bh * 2048 + t0 + tid];
    be[tid] = b_;
    kw[tid] = expf(x63 - x);
    float ca = expf(x);
    coefG[(size_t)cid * 192 + tid] = ca;
    coefG[(size_t)cid * 192 + 64 + tid] = b_;
    coefG[(size_t)cid * 192 + 128 + tid] = b_ * ca;
  }
  __syncthreads();
  // G = K K^T -> A
  const float ds20 = 1.f / 1048576.f;
  for (int nt = 0; nt < 4; ++nt) {
    f32x4 acc = (f32x4){0.f, 0.f, 0.f, 0.f};
    int nrow = nt * 16 + lr;
    int arow = w * 16 + lr;
#pragma unroll
    for (int ks = 0; ks < 4; ++ks) {
      int c = ks * 32 + g16 * 8;
      v8h ah = *(const v8h*)&Kh[arow * 128 + (c ^ ((arow & 7) << 3))];
      v8h al = *(const v8h*)&Kl[arow * 128 + (c ^ ((arow & 7) << 3))];
      v8h bhh = *(const v8h*)&Kh[nrow * 128 + (c ^ ((nrow & 7) << 3))];
      v8h bll = *(const v8h*)&Kl[nrow * 128 + (c ^ ((nrow & 7) << 3))];
      MFMA3(acc, ah, al, bhh, bll);
    }
    int s_ = nt * 16 + lr;
#pragma unroll
    for (int r = 0; r < 4; ++r) {
      int t = w * 16 + g16 * 4 + r;
      float av = (s_ < t) ? acc[r] * ds20 * be[t] * expf(lc[t] - lc[s_]) : 0.f;
      Am[t * 64 + s_] = av;
    }
  }
  __syncthreads();
  // KT global (kw-folded, sigma 1024, pre-swizzled)
  for (int s = tid; s < 8192; s += 256) {
    int feat = s >> 6, t = s & 63;
    int ki = t * 128 + (feat ^ ((t & 7) << 3));
    float kvv = ((float)Kh[ki] + (float)Kl[ki]) * kw[t];
    unsigned short hh, ll; splitw(kvv, hh, ll);
    size_t go = (size_t)cid * 8192 + feat * 64 + (t ^ ((feat & 7) << 3));
    *(unsigned short*)&KTg_h[go] = hh;
    *(unsigned short*)&KTg_l[go] = ll;
  }
  // T = (I+A)^-1 forward substitution (wave 0, lane=column)
  if (w == 0) {
    int j = lane;
    for (int t = 1; t < 64; ++t) {
      float sum = 0.f;
      for (int s = 0; s < t; ++s) sum = fmaf(Am[t * 64 + s], Tm[s * 64 + j], sum);
      Tm[t * 64 + j] = ((j == t) ? 1.f : 0.f) - sum;
    }
  }
  __syncthreads();
  // T global (sigma 256, pre-swizzled)
#pragma unroll
  for (int l = 0; l < 16; ++l) {
    int s2 = tid + l * 256;
    int t = s2 >> 6, sc_ = s2 & 63;
    unsigned short hh, ll; splitw(Tm[s2] * 256.f, hh, ll);
    size_t go = (size_t)cid * 4096 + t * 64 + (sc_ ^ ((t & 7) << 3));
    *(unsigned short*)&Tg_h[go] = hh;
    *(unsigned short*)&Tg_l[go] = ll;
  }
}

// ------------- Phase 1b: Hq[t][s] = exp(lc_t-lc_s) * (q_t . k_s), s<=t  (sigma 16384) -------------
__global__ __launch_bounds__(256) void p1b_k(
    const float* __restrict__ kn, const float* __restrict__ qn, const float* __restrict__ g_arr,
    _Float16* __restrict__ Hg_h, _Float16* __restrict__ Hg_l)
{
  __shared__ _Float16 Kh[8192], Kl[8192], Qh[8192], Ql[8192];
  __shared__ float lc[64];
  const int cid = blockIdx.x, bh = cid >> 5, ch = cid & 31, t0 = ch * 64;
  const int tid = threadIdx.x, w = tid >> 6, lane = tid & 63, lr = lane & 15, g16 = lane >> 4;

  const float* kb = kn + ((size_t)bh * 2048 + t0) * 128;
  const float* qb = qn + ((size_t)bh * 2048 + t0) * 128;
#pragma unroll
  for (int l = 0; l < 8; ++l) {
    int s = tid + l * 256;
    int row = s >> 5, c = (s & 31) * 4;
    int ad = row * 128 + (c ^ ((row & 7) << 3));
    float4 v = *(const float4*)(kb + (size_t)row * 128 + c);
    ushort4 H, L;
    splitw(v.x * 1024.f, H.x, L.x); splitw(v.y * 1024.f, H.y, L.y);
    splitw(v.z * 1024.f, H.z, L.z); splitw(v.w * 1024.f, H.w, L.w);
    *(ushort4*)&Kh[ad] = H; *(ushort4*)&Kl[ad] = L;
    float4 q = *(const float4*)(qb + (size_t)row * 128 + c);
    splitw(q.x * 1024.f, H.x, L.x); splitw(q.y * 1024.f, H.y, L.y);
    splitw(q.z * 1024.f, H.z, L.z); splitw(q.w * 1024.f, H.w, L.w);
    *(ushort4*)&Qh[ad] = H; *(ushort4*)&Ql[ad] = L;
  }
  if (tid < 64) {
    float x = g_arr[(size_t)bh * 2048 + t0 + tid];
#pragma unroll
    for (int off = 1; off < 64; off <<= 1) { float y = __shfl_up(x, off); if (tid >= off) x += y; }
    lc[tid] = x;
  }
  __syncthreads();
  const float ds20 = 1.f / 1048576.f;
  for (int nt = 0; nt < 4; ++nt) {
    f32x4 acc = (f32x4){0.f, 0.f, 0.f, 0.f};
    int nrow = nt * 16 + lr;
    int arow = w * 16 + lr;
#pragma unroll
    for (int ks = 0; ks < 4; ++ks) {
      int c = ks * 32 + g16 * 8;
      v8h ah = *(const v8h*)&Qh[arow * 128 + (c ^ ((arow & 7) << 3))];
      v8h al = *(const v8h*)&Ql[arow * 128 + (c ^ ((arow & 7) << 3))];
      v8h bhh = *(const v8h*)&Kh[nrow * 128 + (c ^ ((nrow & 7) << 3))];
      v8h bll = *(const v8h*)&Kl[nrow * 128 + (c ^ ((nrow & 7) << 3))];
      MFMA3(acc, ah, al, bhh, bll);
    }
    int s_ = nt * 16 + lr;
#pragma unroll
    for (int r = 0; r < 4; ++r) {
      int t = w * 16 + g16 * 4 + r;
      float hv = (s_ <= t) ? acc[r] * ds20 * expf(lc[t] - lc[s_]) : 0.f;
      unsigned short hh, ll; splitw(hv * 16384.f, hh, ll);
      size_t go = (size_t)cid * 4096 + t * 64 + (s_ ^ ((t & 7) << 3));
      *(unsigned short*)&Hg_h[go] = hh;
      *(unsigned short*)&Hg_l[go] = ll;
    }
  }
}

// ------------- Phase 2: sequential chunk scan, MFMA everywhere -------------
// grid 128: blk = vb*32 + bh  (4 vb-blocks of a bh land on same XCD)
__global__ __launch_bounds__(256) void p2_k(
    const float* __restrict__ qn, const float* __restrict__ kn, const float* __restrict__ vn,
    const float* __restrict__ projGate,
    const _Float16* __restrict__ Tg_h, const _Float16* __restrict__ Tg_l,
    const _Float16* __restrict__ Hg_h, const _Float16* __restrict__ Hg_l,
    const _Float16* __restrict__ KTg_h, const _Float16* __restrict__ KTg_l,
    const float* __restrict__ coefG, float* __restrict__ out)
{
  __shared__ _Float16 St_h[8192], St_l[8192];
  __shared__ _Float16 KQ0[8192], KQ1[8192];
  __shared__ _Float16 KTs_h[8192], KTs_l[8192];
  __shared__ _Float16 Ts_h[4096], Ts_l[4096];
  __shared__ _Float16 Hs_h[4096], Hs_l[4096];
  __shared__ float cf[192];

  const int blk = blockIdx.x;
  const int vb = blk >> 5, bh = blk & 31;
  const int b = bh >> 4, h = bh & 15, v0 = vb * 64;
  const int tid = threadIdx.x, w = tid >> 6, lane = tid & 63, lr = lane & 15, g16 = lane >> 4;

  _Float16* BT_h = &KQ0[0];
  _Float16* BT_l = &KQ0[4096];
  _Float16* UT_h = &KQ1[0];
  _Float16* UT_l = &KQ1[4096];

#pragma unroll
  for (int l = 0; l < 16; ++l) { ((unsigned int*)St_h)[tid + l * 256] = 0u; }
#pragma unroll
  for (int l = 0; l < 16; ++l) { ((unsigned int*)St_l)[tid + l * 256] = 0u; }

  const float* qbase = qn + ((size_t)bh * 2048) * 128;
  const float* kbase = kn + ((size_t)bh * 2048) * 128;
  const float* gp = projGate + ((size_t)b * 2048) * GW + h * 256 + v0;
  const float i2_16 = 1.f / 65536.f;
  const float i2_20 = 1.f / 1048576.f;
  const float uscale = 1.f / 256.f;      // raw (T*256 . B*64)=16384*U -> store x64
  const float sscale = 64.f / 65536.f;   // raw (KT*1024 . UT*64)=65536*S -> store x64

  for (int ch = 0; ch < 32; ++ch) {
    const int cid = bh * 32 + ch, t0 = ch * 64;
    // ---- stage: gload T/Hq/KT/coef; VALU-split Q ----
    {
      const _Float16* th = Tg_h + (size_t)cid * 4096;
      const _Float16* tl = Tg_l + (size_t)cid * 4096;
      const _Float16* hh = Hg_h + (size_t)cid * 4096;
      const _Float16* hl = Hg_l + (size_t)cid * 4096;
      const _Float16* kth = KTg_h + (size_t)cid * 8192;
      const _Float16* ktl = KTg_l + (size_t)cid * 8192;
#pragma unroll
      for (int l = 0; l < 2; ++l) {
        int i = tid + l * 256;
        gload_lds16(th + i * 8, &Ts_h[i * 8]);
        gload_lds16(tl + i * 8, &Ts_l[i * 8]);
        gload_lds16(hh + i * 8, &Hs_h[i * 8]);
        gload_lds16(hl + i * 8, &Hs_l[i * 8]);
      }
#pragma unroll
      for (int l = 0; l < 4; ++l) {
        int i = tid + l * 256;
        gload_lds16(kth + i * 8, &KTs_h[i * 8]);
        gload_lds16(ktl + i * 8, &KTs_l[i * 8]);
      }
      if (tid < 48) gload_lds16(coefG + (size_t)cid * 192 + tid * 4, &cf[tid * 4]);
#pragma unroll
      for (int l = 0; l < 8; ++l) {
        int s = tid + l * 256;
        int row = s >> 5, c = (s & 31) * 4;
        float4 v = *(const float4*)(qbase + (size_t)(t0 + row) * 128 + c);
        ushort4 H, L;
        splitw(v.x * 1024.f, H.x, L.x); splitw(v.y * 1024.f, H.y, L.y);
        splitw(v.z * 1024.f, H.z, L.z); splitw(v.w * 1024.f, H.w, L.w);
        int ad = row * 128 + (c ^ ((row & 7) << 3));
        *(ushort4*)&KQ0[ad] = H; *(ushort4*)&KQ1[ad] = L;
      }
    }
    __syncthreads();   // (b)
    const float cc = cf[63];
    // ---- QS0 -> Oacc ----
    f32x4 Oacc[4];
    {
      const int arow = w * 16 + lr, swa = (arow & 7) << 3;
      for (int nt = 0; nt < 4; ++nt) {
        f32x4 acc = (f32x4){0.f, 0.f, 0.f, 0.f};
        const int n = nt * 16 + lr, swn = (n & 7) << 3;
#pragma unroll
        for (int ks = 0; ks < 4; ++ks) {
          int c = ks * 32 + g16 * 8;
          v8h ah = *(const v8h*)&KQ0[arow * 128 + (c ^ swa)];
          v8h al = *(const v8h*)&KQ1[arow * 128 + (c ^ swa)];
          v8h bhh = *(const v8h*)&St_h[n * 128 + (c ^ swn)];
          v8h bll = *(const v8h*)&St_l[n * 128 + (c ^ swn)];
          MFMA3(acc, ah, al, bhh, bll);
        }
        Oacc[nt] = acc;
      }
      float4 cav = *(float4*)&cf[w * 16 + g16 * 4];
#pragma unroll
      for (int nt = 0; nt < 4; ++nt) {
        Oacc[nt][0] *= cav.x * 16.f; Oacc[nt][1] *= cav.y * 16.f;
        Oacc[nt][2] *= cav.z * 16.f; Oacc[nt][3] *= cav.w * 16.f;
      }
    }
    __syncthreads();   // (d) Q consumed
    // ---- stage K ----
#pragma unroll
    for (int l = 0; l < 8; ++l) {
      int s = tid + l * 256;
      int row = s >> 5, c = (s & 31) * 4;
      float4 v = *(const float4*)(kbase + (size_t)(t0 + row) * 128 + c);
      ushort4 H, L;
      splitw(v.x * 1024.f, H.x, L.x); splitw(v.y * 1024.f, H.y, L.y);
      splitw(v.z * 1024.f, H.z, L.z); splitw(v.w * 1024.f, H.w, L.w);
      int ad = row * 128 + (c ^ ((row & 7) << 3));
      *(ushort4*)&KQ0[ad] = H; *(ushort4*)&KQ1[ad] = L;
    }
    __syncthreads();   // (e)
    // ---- KS0 -> B (packed regs) ----
    ushort4 pBh[4], pBl[4];
    {
      const int arow = w * 16 + lr, swa = (arow & 7) << 3;
      float4 cb1v = *(float4*)&cf[64 + w * 16 + g16 * 4];
      float4 cb2v = *(float4*)&cf[128 + w * 16 + g16 * 4];
      for (int nt = 0; nt < 4; ++nt) {
        f32x4 acc = (f32x4){0.f, 0.f, 0.f, 0.f};
        const int n = nt * 16 + lr, swn = (n & 7) << 3;
#pragma unroll
        for (int ks = 0; ks < 4; ++ks) {
          int c = ks * 32 + g16 * 8;
          v8h ah = *(const v8h*)&KQ0[arow * 128 + (c ^ swa)];
          v8h al = *(const v8h*)&KQ1[arow * 128 + (c ^ swa)];
          v8h bhh = *(const v8h*)&St_h[n * 128 + (c ^ swn)];
          v8h bll = *(const v8h*)&St_l[n * 128 + (c ^ swn)];
          MFMA3(acc, ah, al, bhh, bll);
        }
        float cb1a[4] = {cb1v.x, cb1v.y, cb1v.z, cb1v.w};
        float cb2a[4] = {cb2v.x, cb2v.y, cb2v.z, cb2v.w};
        unsigned short* ph = (unsigned short*)&pBh[nt];
        unsigned short* pl = (unsigned short*)&pBl[nt];
#pragma unroll
        for (int r = 0; r < 4; ++r) {
          int t = w * 16 + g16 * 4 + r;
          float kv = acc[r] * i2_16;
          float Vv = vn[((size_t)bh * 2048 + t0 + t) * 256 + v0 + n];
          float Bv = cb1a[r] * Vv - cb2a[r] * kv;
          splitw(Bv * 64.f, ph[r], pl[r]);
        }
      }
    }
    __syncthreads();   // (f) K dead
    {
      const int tb = w * 16 + g16 * 4;
      for (int nt = 0; nt < 4; ++nt) {
        const int n = nt * 16 + lr, swn = (n & 7) << 3;
        int ad = n * 64 + (tb ^ swn);
        *(ushort4*)&BT_h[ad] = pBh[nt];
        *(ushort4*)&BT_l[ad] = pBl[nt];
      }
    }
    __syncthreads();   // (g) BT ready
    // ---- U = T @ B -> UT ----
    {
      const int arow = w * 16 + lr, swa = (arow & 7) << 3;
      const int tb = w * 16 + g16 * 4;
      for (int nt = 0; nt < 4; ++nt) {
        f32x4 acc = (f32x4){0.f, 0.f, 0.f, 0.f};
        const int n = nt * 16 + lr, swn = (n & 7) << 3;
#pragma unroll
        for (int ks = 0; ks < 2; ++ks) {
          int c = ks * 32 + g16 * 8;
          v8h ah = *(const v8h*)&Ts_h[arow * 64 + (c ^ swa)];
          v8h al = *(const v8h*)&Ts_l[arow * 64 + (c ^ swa)];
          v8h bhh = *(const v8h*)&BT_h[n * 64 + (c ^ swn)];
          v8h bll = *(const v8h*)&BT_l[n * 64 + (c ^ swn)];
          MFMA3(acc, ah, al, bhh, bll);
        }
        ushort4 H, L;
        unsigned short* ph = (unsigned short*)&H;
        unsigned short* pl = (unsigned short*)&L;
#pragma unroll
        for (int r = 0; r < 4; ++r) splitw(acc[r] * uscale, ph[r], pl[r]);
        int ad = n * 64 + (tb ^ swn);
        *(ushort4*)&UT_h[ad] = H;
        *(ushort4*)&UT_l[ad] = L;
      }
    }
    __syncthreads();   // (h) UT ready
    // ---- O += Hq @ UT ; write out ----
    {
      const int arow = w * 16 + lr, swa = (arow & 7) << 3;
      for (int nt = 0; nt < 4; ++nt) {
        const int n = nt * 16 + lr, swn = (n & 7) << 3;
#pragma unroll
        for (int ks = 0; ks < 2; ++ks) {
          int c = ks * 32 + g16 * 8;
          v8h ah = *(const v8h*)&Hs_h[arow * 64 + (c ^ swa)];
          v8h al = *(const v8h*)&Hs_l[arow * 64 + (c ^ swa)];
          v8h bhh = *(const v8h*)&UT_h[n * 64 + (c ^ swn)];
          v8h bll = *(const v8h*)&UT_l[n * 64 + (c ^ swn)];
          MFMA3(Oacc[nt], ah, al, bhh, bll);
        }
      }
      for (int nt = 0; nt < 4; ++nt) {
        const int n = nt * 16 + lr;
#pragma unroll
        for (int r = 0; r < 4; ++r) {
          int t = t0 + w * 16 + g16 * 4 + r;
          float Ov = Oacc[nt][r] * i2_20;
          float gv = gp[(size_t)t * GW + n];
          out[((size_t)b * 2048 + t) * 4096 + h * 256 + v0 + n] = Ov * (gv / (1.f + expf(-gv)));
        }
      }
    }
    // ---- S' = cc*S + KT @ UT ----
    {
      const float cc1024 = cc * 1024.f;
#pragma unroll
      for (int m2 = w * 2; m2 < w * 2 + 2; ++m2) {
        const int arow = m2 * 16 + lr, swa = (arow & 7) << 3;
        const int fb = m2 * 16 + g16 * 4;
        for (int nt = 0; nt < 4; ++nt) {
          const int n = nt * 16 + lr, swn = (n & 7) << 3;
          int sad = n * 128 + (fb ^ swn);
          ushort4 sh4 = *(ushort4*)&St_h[sad];
          ushort4 sl4 = *(ushort4*)&St_l[sad];
          f32x4 acc;
          acc[0] = cc1024 * (h2f(sh4.x) + h2f(sl4.x));
          acc[1] = cc1024 * (h2f(sh4.y) + h2f(sl4.y));
          acc[2] = cc1024 * (h2f(sh4.z) + h2f(sl4.z));
          acc[3] = cc1024 * (h2f(sh4.w) + h2f(sl4.w));
#pragma unroll
          for (int ks = 0; ks < 2; ++ks) {
            int c = ks * 32 + g16 * 8;
            v8h ah = *(const v8h*)&KTs_h[arow * 64 + (c ^ swa)];
            v8h al = *(const v8h*)&KTs_l[arow * 64 + (c ^ swa)];
            v8h bhh = *(const v8h*)&UT_h[n * 64 + (c ^ swn)];
            v8h bll = *(const v8h*)&UT_l[n * 64 + (c ^ swn)];
            MFMA3(acc, ah, al, bhh, bll);
          }
          ushort4 H, L;
          unsigned short* ph = (unsigned short*)&H;
          unsigned short* pl = (unsigned short*)&L;
#pragma unroll
          for (int r = 0; r < 4; ++r) splitw(acc[r] * sscale, ph[r], pl[r]);
          *(ushort4*)&St_h[sad] = H;
          *(ushort4*)&St_l[sad] = L;
        }
      }
    }
    __syncthreads();   // (i)
  }
}

extern "C" void kernel_launch(void* const* d_in, const int* in_sizes, int n_in,
                              void* d_out, int out_size, void* d_ws, size_t ws_size,
                              hipStream_t stream) {
  const float* hidden  = (const float*)d_in[0];
  const float* W       = (const float*)d_in[1];
  const float* Wc      = (const float*)d_in[2];
  const float* A_log   = (const float*)d_in[3];
  const float* dt_bias = (const float*)d_in[4];
  float* out = (float*)d_out;

  char* ws = (char*)d_ws;
  // [0, 135.27MB): Ap/Bp -> aliased by qn/kn/vn/g/beta after GEMM
  _Float16* Ap = (_Float16*)ws;
  _Float16* Bp = (_Float16*)(ws + (size_t)33554432);
  float* qn    = (float*)ws;
  float* kn    = qn + (size_t)8388608;
  float* vn    = kn + (size_t)8388608;
  float* g_arr = vn + (size_t)16777216;
  float* beta  = g_arr + (size_t)65536;
  // [135.27MB, 269.48MB): projQKV (cols 0..8191) -> aliased by chunk tables after conv
  float* projQKV = (float*)(ws + (size_t)135266304);
  char*  tb0 = ws + (size_t)135266304;
  _Float16* Tg_h  = (_Float16*)tb0;
  _Float16* Tg_l  = (_Float16*)(tb0 + (size_t)8388608);
  _Float16* Hg_h  = (_Float16*)(tb0 + (size_t)16777216);
  _Float16* Hg_l  = (_Float16*)(tb0 + (size_t)25165824);
  _Float16* KTg_h = (_Float16*)(tb0 + (size_t)33554432);
  _Float16* KTg_l = (_Float16*)(tb0 + (size_t)50331648);
  float*    coefG = (float*)   (tb0 + (size_t)67108864);
  // [269.48MB, 337.12MB): projGate (cols 8192..12319), live until p2
  float* projGate = (float*)(ws + (size_t)269484032);

  pack_A_k<<<32 * KSTEPS, 256, 0, stream>>>(hidden, Ap);
  pack_B_k<<<NTILE_N * KSTEPS, 256, 0, stream>>>(W, Bp);
  gemm_mfma_k<<<32 * NTILE_N, 256, 0, stream>>>(Ap, Bp, projQKV, projGate);

  dim3 g2(8, 64, 2);
  conv_norm_k<<<g2, 128, 0, stream>>>(projQKV, Wc, qn, kn, vn);
  beta_g_k<<<(2 * NH * L_SEQ + 255) / 256, 256, 0, stream>>>(projGate, A_log, dt_bias, beta, g_arr);

  p1a_k<<<1024, 256, 0, stream>>>(kn, g_arr, beta, Tg_h, Tg_l, KTg_h, KTg_l, coefG);
  p1b_k<<<1024, 256, 0, stream>>>(kn, qn, g_arr, Hg_h, Hg_l);
  p2_k<<<128, 256, 0, stream>>>(qn, kn, vn, projGate, Tg_h, Tg_l, Hg_h, Hg_l, KTg_h, KTg_l, coefG, out);
}

// Round 6
// 1350.487 us; speedup vs baseline: 2.9035x; 1.0052x over previous
//
#include <hip/hip_runtime.h>
#include <hip/hip_bf16.h>
#include <hip/hip_fp16.h>
#include <math.h>

#define L_SEQ 2048
#define DM    2048
#define NH    16
#define DH    128
#define HVD   256
#define NPROJ 12320
#define QKVW  8192
#define GW    4128

#define NTILE_N 97
#define KSTEPS  64

typedef _Float16 v8h __attribute__((ext_vector_type(8)));
typedef float f32x4 __attribute__((ext_vector_type(4)));

__device__ __forceinline__ void gload_lds16(const void* g, void* l) {
  __builtin_amdgcn_global_load_lds((const __attribute__((address_space(1))) void*)g,
                                   (__attribute__((address_space(3))) void*)l, 16, 0, 0);
}

__device__ __forceinline__ void splitw(float x, unsigned short& h, unsigned short& l) {
  _Float16 hh = (_Float16)x;
  _Float16 ll = (_Float16)(x - (float)hh);
  h = *(unsigned short*)&hh;
  l = *(unsigned short*)&ll;
}
__device__ __forceinline__ float h2f(unsigned short u) {
  return (float)(*(_Float16*)&u);
}

#define MFMA3(acc, ah, al, bh_, bl_)                                          \
  acc = __builtin_amdgcn_mfma_f32_16x16x32_f16(ah, bh_, acc, 0, 0, 0);        \
  acc = __builtin_amdgcn_mfma_f32_16x16x32_f16(ah, bl_, acc, 0, 0, 0);        \
  acc = __builtin_amdgcn_mfma_f32_16x16x32_f16(al, bh_, acc, 0, 0, 0);

// ---------------- pack A: hidden(4096x2048) f32 -> fp16 hi/lo, x16 ----------------
__global__ __launch_bounds__(256) void pack_A_k(const float* __restrict__ H, _Float16* __restrict__ Ap) {
  const int mtile = blockIdx.x >> 6, kstep = blockIdx.x & 63;
  const size_t base = (size_t)blockIdx.x * 2 * 4096;
#pragma unroll
  for (int it = 0; it < 2; ++it) {
    int s = threadIdx.x + it * 256;
    int g = s >> 7, r = s & 127;
    const float* src = H + ((size_t)(mtile * 128 + r)) * 2048 + kstep * 32 + g * 8;
    float4 x0 = *(const float4*)src;
    float4 x1 = *(const float4*)(src + 4);
    float xs[8] = {x0.x, x0.y, x0.z, x0.w, x1.x, x1.y, x1.z, x1.w};
    v8h hi, lo;
#pragma unroll
    for (int j = 0; j < 8; ++j) {
      float v = xs[j] * 16.f;
      _Float16 h = (_Float16)v;
      hi[j] = h;
      lo[j] = (_Float16)(v - (float)h);
    }
    *(v8h*)(Ap + base + g * 1024 + r * 8) = hi;
    *(v8h*)(Ap + base + 4096 + g * 1024 + r * 8) = lo;
  }
}

// ---------------- pack B: W(2048x12320) f32 -> fp16 hi/lo, x1024 ----------------
__global__ __launch_bounds__(256) void pack_B_k(const float* __restrict__ W, _Float16* __restrict__ Bp) {
  const int ntile = blockIdx.x >> 6, kstep = blockIdx.x & 63;
  const size_t base = (size_t)blockIdx.x * 2 * 4096;
#pragma unroll
  for (int it = 0; it < 2; ++it) {
    int s = threadIdx.x + it * 256;
    int g = s >> 7, col = s & 127;
    int n = ntile * 128 + col;
    v8h hi, lo;
#pragma unroll
    for (int j = 0; j < 8; ++j) {
      int k = kstep * 32 + g * 8 + j;
      float v = (n < NPROJ) ? W[(size_t)k * NPROJ + n] * 1024.f : 0.f;
      _Float16 h = (_Float16)v;
      hi[j] = h;
      lo[j] = (_Float16)(v - (float)h);
    }
    *(v8h*)(Bp + base + g * 1024 + col * 8) = hi;
    *(v8h*)(Bp + base + 4096 + g * 1024 + col * 8) = lo;
  }
}

// ---------------- split-fp16 MFMA GEMM, 2-phase double-buffered + XCD swizzle ----------------
__global__ __launch_bounds__(256) void gemm_mfma_k(const _Float16* __restrict__ Ap,
                                                   const _Float16* __restrict__ Bp,
                                                   float* __restrict__ Cq,
                                                   float* __restrict__ Cg) {
  __shared__ _Float16 lds[2][16384];   // 64KB: per buf: Ahi Alo Bhi Blo
  const int tid = threadIdx.x;
  // bijective XCD swizzle: nwg = 3104 = 8*388; XCD x gets contiguous logical chunk
  const int bid = blockIdx.x;
  const int swz = (bid & 7) * 388 + (bid >> 3);
  const int mtile = swz & 31;
  const int ntile = swz >> 5;
  const int wid = tid >> 6, lane = tid & 63;
  const int wm = wid >> 1, wn = wid & 1;
  const int lrow = lane & 15, g = lane >> 4;

  f32x4 acc[4][4];
#pragma unroll
  for (int i = 0; i < 4; ++i)
#pragma unroll
    for (int j = 0; j < 4; ++j) acc[i][j] = (f32x4){0.f, 0.f, 0.f, 0.f};

  const int aoff = (wm * 64 + lrow) * 8 + g * 1024;
  const int boff = (wn * 64 + lrow) * 8 + g * 1024;

  const _Float16* Asrc = Ap + ((size_t)(mtile * KSTEPS) * 2) * 4096 + tid * 8;
  const _Float16* Bsrc = Bp + ((size_t)(ntile * KSTEPS) * 2) * 4096 + tid * 8;

  // prologue: stage kstep 0 into buf 0
#pragma unroll
  for (int r = 0; r < 4; ++r) {
    gload_lds16(Asrc + r * 2048, &lds[0][r * 2048 + tid * 8]);
    gload_lds16(Bsrc + r * 2048, &lds[0][8192 + r * 2048 + tid * 8]);
  }
  __syncthreads();

  for (int kstep = 0; kstep < KSTEPS; ++kstep) {
    const int p = kstep & 1;
    if (kstep + 1 < KSTEPS) {     // prefetch next K-step into buf p^1 (in flight during MFMA)
      const _Float16* An = Asrc + (size_t)(kstep + 1) * 8192;
      const _Float16* Bn = Bsrc + (size_t)(kstep + 1) * 8192;
#pragma unroll
      for (int r = 0; r < 4; ++r) {
        gload_lds16(An + r * 2048, &lds[p ^ 1][r * 2048 + tid * 8]);
        gload_lds16(Bn + r * 2048, &lds[p ^ 1][8192 + r * 2048 + tid * 8]);
      }
    }
    v8h ah[4], al[4], bh[4], bl[4];
#pragma unroll
    for (int f = 0; f < 4; ++f) {
      ah[f] = *(const v8h*)&lds[p][aoff + f * 128];
      al[f] = *(const v8h*)&lds[p][4096 + aoff + f * 128];
      bh[f] = *(const v8h*)&lds[p][8192 + boff + f * 128];
      bl[f] = *(const v8h*)&lds[p][12288 + boff + f * 128];
    }
#pragma unroll
    for (int fm = 0; fm < 4; ++fm)
#pragma unroll
      for (int fn = 0; fn < 4; ++fn) {
        acc[fm][fn] = __builtin_amdgcn_mfma_f32_16x16x32_f16(ah[fm], bh[fn], acc[fm][fn], 0, 0, 0);
        acc[fm][fn] = __builtin_amdgcn_mfma_f32_16x16x32_f16(ah[fm], bl[fn], acc[fm][fn], 0, 0, 0);
        acc[fm][fn] = __builtin_amdgcn_mfma_f32_16x16x32_f16(al[fm], bh[fn], acc[fm][fn], 0, 0, 0);
      }
    __syncthreads();   // drains prefetch (covered by MFMA phase) + protects buf reuse
  }

  const float sc = 1.f / 16384.f;
#pragma unroll
  for (int fm = 0; fm < 4; ++fm) {
    int row = mtile * 128 + wm * 64 + fm * 16 + g * 4;
#pragma unroll
    for (int fn = 0; fn < 4; ++fn) {
      int col = ntile * 128 + wn * 64 + fn * 16 + lrow;
      if (col < QKVW) {
#pragma unroll
        for (int r = 0; r < 4; ++r)
          Cq[(size_t)(row + r) * QKVW + col] = acc[fm][fn][r] * sc;
      } else if (col < NPROJ) {
        int lcol = col - QKVW;
#pragma unroll
        for (int r = 0; r < 4; ++r)
          Cg[(size_t)(row + r) * GW + lcol] = acc[fm][fn][r] * sc;
      }
    }
  }
}

// ------------- fused causal depthwise conv(4) + SiLU + l2norm(q,k) + q-scale -------------
__global__ __launch_bounds__(128) void conv_norm_k(
    const float* __restrict__ projQKV, const float* __restrict__ Wc,
    float* __restrict__ qn, float* __restrict__ kn, float* __restrict__ vn)
{
  const int b = blockIdx.z, cc = blockIdx.y, tc = blockIdx.x;
  const int tid = threadIdx.x;
  const int ch = cc * 128 + tid;
  const float W0 = Wc[ch * 4 + 0], W1 = Wc[ch * 4 + 1], W2 = Wc[ch * 4 + 2], W3 = Wc[ch * 4 + 3];
  const int t0 = tc * 256;
  const float* P = projQKV + (size_t)b * L_SEQ * QKVW + ch;

  float w0 = (t0 - 3 >= 0) ? P[(size_t)(t0 - 3) * QKVW] : 0.f;
  float w1 = (t0 - 2 >= 0) ? P[(size_t)(t0 - 2) * QKVW] : 0.f;
  float w2 = (t0 - 1 >= 0) ? P[(size_t)(t0 - 1) * QKVW] : 0.f;

  const bool isq = (ch < 2048);
  const bool isk = (ch >= 2048 && ch < 4096);
  __shared__ float red[2][2];

  float* qdst = nullptr; float* kdst = nullptr; float* vdst = nullptr;
  if (isq) {
    int h = cc;
    qdst = qn + (((size_t)b * NH + h) * L_SEQ) * DH + tid;
  } else if (isk) {
    int h = cc - 16;
    kdst = kn + (((size_t)b * NH + h) * L_SEQ) * DH + tid;
  } else {
    int vc = ch - 4096;
    int h = vc >> 8;
    int vcol = vc & 255;
    vdst = vn + (((size_t)b * NH + h) * L_SEQ) * HVD + vcol;
  }
  const float qscale = 0.08838834764831845f;

  for (int t = t0; t < t0 + 256; ++t) {
    float x = P[(size_t)t * QKVW];
    float y = w0 * W0 + w1 * W1 + w2 * W2 + x * W3;
    w0 = w1; w1 = w2; w2 = x;
    y = y / (1.f + expf(-y));
    if (isq || isk) {
      float ss = y * y;
#pragma unroll
      for (int off = 1; off < 64; off <<= 1) ss += __shfl_xor(ss, off);
      int wv = tid >> 6;
      if ((tid & 63) == 0) red[t & 1][wv] = ss;
      __syncthreads();
      float tot = red[t & 1][0] + red[t & 1][1];
      float nrm = 1.f / sqrtf(tot + 1e-6f);
      float val = y * nrm;
      if (isq) { qdst[(size_t)t * DH] = val * qscale; }
      else     { kdst[(size_t)t * DH] = val; }
    } else {
      vdst[(size_t)t * HVD] = y;
    }
  }
}

// ------------- beta = sigmoid(b), g = -exp(A_log)*softplus(A+dt_bias) -------------
__global__ __launch_bounds__(256) void beta_g_k(
    const float* __restrict__ projGate, const float* __restrict__ A_log,
    const float* __restrict__ dt_bias, float* __restrict__ beta, float* __restrict__ g_out)
{
  int idx = blockIdx.x * 256 + threadIdx.x;
  if (idx >= 2 * NH * L_SEQ) return;
  int t = idx & (L_SEQ - 1);
  int h = (idx >> 11) & (NH - 1);
  int b = idx >> 15;
  size_t row = (size_t)(b * L_SEQ + t) * GW;
  float bv = projGate[row + 4096 + h];
  float av = projGate[row + 4112 + h];
  float be = 1.f / (1.f + expf(-bv));
  float xx = av + dt_bias[h];
  float sp = (xx > 20.f) ? xx : log1pf(expf(xx));
  float g = -expf(A_log[h]) * sp;
  beta[idx] = be;
  g_out[idx] = g;
}

// ------------- Phase 1a: per-chunk T=(I+A)^-1, KT (kw-folded K^T), coef arrays -------------
__global__ __launch_bounds__(256) void p1a_k(
    const float* __restrict__ kn, const float* __restrict__ g_arr, const float* __restrict__ beta_arr,
    _Float16* __restrict__ Tg_h, _Float16* __restrict__ Tg_l,
    _Float16* __restrict__ KTg_h, _Float16* __restrict__ KTg_l,
    float* __restrict__ coefG)
{
  __shared__ _Float16 Kh[8192], Kl[8192];
  __shared__ float Am[4096], Tm[4096];
  __shared__ float lc[64], be[64], kw[64];
  const int cid = blockIdx.x, bh = cid >> 5, ch = cid & 31, t0 = ch * 64;
  const int tid = threadIdx.x, w = tid >> 6, lane = tid & 63, lr = lane & 15, g16 = lane >> 4;

  const float* kb = kn + ((size_t)bh * 2048 + t0) * 128;
#pragma unroll
  for (int l = 0; l < 8; ++l) {
    int s = tid + l * 256;
    int row = s >> 5, c = (s & 31) * 4;
    float4 v = *(const float4*)(kb + (size_t)row * 128 + c);
    ushort4 H, L;
    splitw(v.x * 1024.f, H.x, L.x); splitw(v.y * 1024.f, H.y, L.y);
    splitw(v.z * 1024.f, H.z, L.z); splitw(v.w * 1024.f, H.w, L.w);
    int ad = row * 128 + (c ^ ((row & 7) << 3));
    *(ushort4*)&Kh[ad] = H; *(ushort4*)&Kl[ad] = L;
  }
#pragma unroll
  for (int l = 0; l < 16; ++l) { int s2 = tid + l * 256; Tm[s2] = ((s2 >> 6) == (s2 & 63)) ? 1.f : 0.f; }
  if (tid < 64) {
    float x = g_arr[(size_t)bh * 2048 + t0 + tid];
#pragma unroll
    for (int off = 1; off < 64; off <<= 1) { float y = __shfl_up(x, off); if (tid >= off) x += y; }
    lc[tid] = x;
    float x63 = __shfl(x, 63);
    float b_ = beta_arr[(size_t)bh * 2048 + t0 + tid];
    be[tid] = b_;
    kw[tid] = expf(x63 - x);
    float ca = expf(x);
    coefG[(size_t)cid * 192 + tid] = ca;
    coefG[(size_t)cid * 192 + 64 + tid] = b_;
    coefG[(size_t)cid * 192 + 128 + tid] = b_ * ca;
  }
  __syncthreads();
  const float ds20 = 1.f / 1048576.f;
  for (int nt = 0; nt < 4; ++nt) {
    f32x4 acc = (f32x4){0.f, 0.f, 0.f, 0.f};
    int nrow = nt * 16 + lr;
    int arow = w * 16 + lr;
#pragma unroll
    for (int ks = 0; ks < 4; ++ks) {
      int c = ks * 32 + g16 * 8;
      v8h ah = *(const v8h*)&Kh[arow * 128 + (c ^ ((arow & 7) << 3))];
      v8h al = *(const v8h*)&Kl[arow * 128 + (c ^ ((arow & 7) << 3))];
      v8h bhh = *(const v8h*)&Kh[nrow * 128 + (c ^ ((nrow & 7) << 3))];
      v8h bll = *(const v8h*)&Kl[nrow * 128 + (c ^ ((nrow & 7) << 3))];
      MFMA3(acc, ah, al, bhh, bll);
    }
    int s_ = nt * 16 + lr;
#pragma unroll
    for (int r = 0; r < 4; ++r) {
      int t = w * 16 + g16 * 4 + r;
      float av = (s_ < t) ? acc[r] * ds20 * be[t] * expf(lc[t] - lc[s_]) : 0.f;
      Am[t * 64 + s_] = av;
    }
  }
  __syncthreads();
  for (int s = tid; s < 8192; s += 256) {
    int feat = s >> 6, t = s & 63;
    int ki = t * 128 + (feat ^ ((t & 7) << 3));
    float kvv = ((float)Kh[ki] + (float)Kl[ki]) * kw[t];
    unsigned short hh, ll; splitw(kvv, hh, ll);
    size_t go = (size_t)cid * 8192 + feat * 64 + (t ^ ((feat & 7) << 3));
    *(unsigned short*)&KTg_h[go] = hh;
    *(unsigned short*)&KTg_l[go] = ll;
  }
  if (w == 0) {
    int j = lane;
    for (int t = 1; t < 64; ++t) {
      float sum = 0.f;
      for (int s = 0; s < t; ++s) sum = fmaf(Am[t * 64 + s], Tm[s * 64 + j], sum);
      Tm[t * 64 + j] = ((j == t) ? 1.f : 0.f) - sum;
    }
  }
  __syncthreads();
#pragma unroll
  for (int l = 0; l < 16; ++l) {
    int s2 = tid + l * 256;
    int t = s2 >> 6, sc_ = s2 & 63;
    unsigned short hh, ll; splitw(Tm[s2] * 256.f, hh, ll);
    size_t go = (size_t)cid * 4096 + t * 64 + (sc_ ^ ((t & 7) << 3));
    *(unsigned short*)&Tg_h[go] = hh;
    *(unsigned short*)&Tg_l[go] = ll;
  }
}

// ------------- Phase 1b: Hq[t][s] = exp(lc_t-lc_s) * (q_t . k_s), s<=t  (sigma 16384) -------------
__global__ __launch_bounds__(256) void p1b_k(
    const float* __restrict__ kn, const float* __restrict__ qn, const float* __restrict__ g_arr,
    _Float16* __restrict__ Hg_h, _Float16* __restrict__ Hg_l)
{
  __shared__ _Float16 Kh[8192], Kl[8192], Qh[8192], Ql[8192];
  __shared__ float lc[64];
  const int cid = blockIdx.x, bh = cid >> 5, ch = cid & 31, t0 = ch * 64;
  const int tid = threadIdx.x, w = tid >> 6, lane = tid & 63, lr = lane & 15, g16 = lane >> 4;

  const float* kb = kn + ((size_t)bh * 2048 + t0) * 128;
  const float* qb = qn + ((size_t)bh * 2048 + t0) * 128;
#pragma unroll
  for (int l = 0; l < 8; ++l) {
    int s = tid + l * 256;
    int row = s >> 5, c = (s & 31) * 4;
    int ad = row * 128 + (c ^ ((row & 7) << 3));
    float4 v = *(const float4*)(kb + (size_t)row * 128 + c);
    ushort4 H, L;
    splitw(v.x * 1024.f, H.x, L.x); splitw(v.y * 1024.f, H.y, L.y);
    splitw(v.z * 1024.f, H.z, L.z); splitw(v.w * 1024.f, H.w, L.w);
    *(ushort4*)&Kh[ad] = H; *(ushort4*)&Kl[ad] = L;
    float4 q = *(const float4*)(qb + (size_t)row * 128 + c);
    splitw(q.x * 1024.f, H.x, L.x); splitw(q.y * 1024.f, H.y, L.y);
    splitw(q.z * 1024.f, H.z, L.z); splitw(q.w * 1024.f, H.w, L.w);
    *(ushort4*)&Qh[ad] = H; *(ushort4*)&Ql[ad] = L;
  }
  if (tid < 64) {
    float x = g_arr[(size_t)bh * 2048 + t0 + tid];
#pragma unroll
    for (int off = 1; off < 64; off <<= 1) { float y = __shfl_up(x, off); if (tid >= off) x += y; }
    lc[tid] = x;
  }
  __syncthreads();
  const float ds20 = 1.f / 1048576.f;
  for (int nt = 0; nt < 4; ++nt) {
    f32x4 acc = (f32x4){0.f, 0.f, 0.f, 0.f};
    int nrow = nt * 16 + lr;
    int arow = w * 16 + lr;
#pragma unroll
    for (int ks = 0; ks < 4; ++ks) {
      int c = ks * 32 + g16 * 8;
      v8h ah = *(const v8h*)&Qh[arow * 128 + (c ^ ((arow & 7) << 3))];
      v8h al = *(const v8h*)&Ql[arow * 128 + (c ^ ((arow & 7) << 3))];
      v8h bhh = *(const v8h*)&Kh[nrow * 128 + (c ^ ((nrow & 7) << 3))];
      v8h bll = *(const v8h*)&Kl[nrow * 128 + (c ^ ((nrow & 7) << 3))];
      MFMA3(acc, ah, al, bhh, bll);
    }
    int s_ = nt * 16 + lr;
#pragma unroll
    for (int r = 0; r < 4; ++r) {
      int t = w * 16 + g16 * 4 + r;
      float hv = (s_ <= t) ? acc[r] * ds20 * expf(lc[t] - lc[s_]) : 0.f;
      unsigned short hh, ll; splitw(hv * 16384.f, hh, ll);
      size_t go = (size_t)cid * 4096 + t * 64 + (s_ ^ ((t & 7) << 3));
      *(unsigned short*)&Hg_h[go] = hh;
      *(unsigned short*)&Hg_l[go] = ll;
    }
  }
}

// ------------- Phase 2: sequential chunk scan, MFMA everywhere -------------
__global__ __launch_bounds__(256) void p2_k(
    const float* __restrict__ qn, const float* __restrict__ kn, const float* __restrict__ vn,
    const float* __restrict__ projGate,
    const _Float16* __restrict__ Tg_h, const _Float16* __restrict__ Tg_l,
    const _Float16* __restrict__ Hg_h, const _Float16* __restrict__ Hg_l,
    const _Float16* __restrict__ KTg_h, const _Float16* __restrict__ KTg_l,
    const float* __restrict__ coefG, float* __restrict__ out)
{
  __shared__ _Float16 St_h[8192], St_l[8192];
  __shared__ _Float16 KQ0[8192], KQ1[8192];
  __shared__ _Float16 KTs_h[8192], KTs_l[8192];
  __shared__ _Float16 Ts_h[4096], Ts_l[4096];
  __shared__ _Float16 Hs_h[4096], Hs_l[4096];
  __shared__ float cf[192];

  const int blk = blockIdx.x;
  const int vb = blk >> 5, bh = blk & 31;
  const int b = bh >> 4, h = bh & 15, v0 = vb * 64;
  const int tid = threadIdx.x, w = tid >> 6, lane = tid & 63, lr = lane & 15, g16 = lane >> 4;

  _Float16* BT_h = &KQ0[0];
  _Float16* BT_l = &KQ0[4096];
  _Float16* UT_h = &KQ1[0];
  _Float16* UT_l = &KQ1[4096];

#pragma unroll
  for (int l = 0; l < 16; ++l) { ((unsigned int*)St_h)[tid + l * 256] = 0u; }
#pragma unroll
  for (int l = 0; l < 16; ++l) { ((unsigned int*)St_l)[tid + l * 256] = 0u; }

  const float* qbase = qn + ((size_t)bh * 2048) * 128;
  const float* kbase = kn + ((size_t)bh * 2048) * 128;
  const float* gp = projGate + ((size_t)b * 2048) * GW + h * 256 + v0;
  const float i2_16 = 1.f / 65536.f;
  const float i2_20 = 1.f / 1048576.f;
  const float uscale = 1.f / 256.f;
  const float sscale = 64.f / 65536.f;

  for (int ch = 0; ch < 32; ++ch) {
    const int cid = bh * 32 + ch, t0 = ch * 64;
    {
      const _Float16* th = Tg_h + (size_t)cid * 4096;
      const _Float16* tl = Tg_l + (size_t)cid * 4096;
      const _Float16* hh = Hg_h + (size_t)cid * 4096;
      const _Float16* hl = Hg_l + (size_t)cid * 4096;
      const _Float16* kth = KTg_h + (size_t)cid * 8192;
      const _Float16* ktl = KTg_l + (size_t)cid * 8192;
#pragma unroll
      for (int l = 0; l < 2; ++l) {
        int i = tid + l * 256;
        gload_lds16(th + i * 8, &Ts_h[i * 8]);
        gload_lds16(tl + i * 8, &Ts_l[i * 8]);
        gload_lds16(hh + i * 8, &Hs_h[i * 8]);
        gload_lds16(hl + i * 8, &Hs_l[i * 8]);
      }
#pragma unroll
      for (int l = 0; l < 4; ++l) {
        int i = tid + l * 256;
        gload_lds16(kth + i * 8, &KTs_h[i * 8]);
        gload_lds16(ktl + i * 8, &KTs_l[i * 8]);
      }
      if (tid < 48) gload_lds16(coefG + (size_t)cid * 192 + tid * 4, &cf[tid * 4]);
#pragma unroll
      for (int l = 0; l < 8; ++l) {
        int s = tid + l * 256;
        int row = s >> 5, c = (s & 31) * 4;
        float4 v = *(const float4*)(qbase + (size_t)(t0 + row) * 128 + c);
        ushort4 H, L;
        splitw(v.x * 1024.f, H.x, L.x); splitw(v.y * 1024.f, H.y, L.y);
        splitw(v.z * 1024.f, H.z, L.z); splitw(v.w * 1024.f, H.w, L.w);
        int ad = row * 128 + (c ^ ((row & 7) << 3));
        *(ushort4*)&KQ0[ad] = H; *(ushort4*)&KQ1[ad] = L;
      }
    }
    __syncthreads();
    const float cc = cf[63];
    f32x4 Oacc[4];
    {
      const int arow = w * 16 + lr, swa = (arow & 7) << 3;
      for (int nt = 0; nt < 4; ++nt) {
        f32x4 acc = (f32x4){0.f, 0.f, 0.f, 0.f};
        const int n = nt * 16 + lr, swn = (n & 7) << 3;
#pragma unroll
        for (int ks = 0; ks < 4; ++ks) {
          int c = ks * 32 + g16 * 8;
          v8h ah = *(const v8h*)&KQ0[arow * 128 + (c ^ swa)];
          v8h al = *(const v8h*)&KQ1[arow * 128 + (c ^ swa)];
          v8h bhh = *(const v8h*)&St_h[n * 128 + (c ^ swn)];
          v8h bll = *(const v8h*)&St_l[n * 128 + (c ^ swn)];
          MFMA3(acc, ah, al, bhh, bll);
        }
        Oacc[nt] = acc;
      }
      float4 cav = *(float4*)&cf[w * 16 + g16 * 4];
#pragma unroll
      for (int nt = 0; nt < 4; ++nt) {
        Oacc[nt][0] *= cav.x * 16.f; Oacc[nt][1] *= cav.y * 16.f;
        Oacc[nt][2] *= cav.z * 16.f; Oacc[nt][3] *= cav.w * 16.f;
      }
    }
    __syncthreads();
#pragma unroll
    for (int l = 0; l < 8; ++l) {
      int s = tid + l * 256;
      int row = s >> 5, c = (s & 31) * 4;
      float4 v = *(const float4*)(kbase + (size_t)(t0 + row) * 128 + c);
      ushort4 H, L;
      splitw(v.x * 1024.f, H.x, L.x); splitw(v.y * 1024.f, H.y, L.y);
      splitw(v.z * 1024.f, H.z, L.z); splitw(v.w * 1024.f, H.w, L.w);
      int ad = row * 128 + (c ^ ((row & 7) << 3));
      *(ushort4*)&KQ0[ad] = H; *(ushort4*)&KQ1[ad] = L;
    }
    __syncthreads();
    ushort4 pBh[4], pBl[4];
    {
      const int arow = w * 16 + lr, swa = (arow & 7) << 3;
      float4 cb1v = *(float4*)&cf[64 + w * 16 + g16 * 4];
      float4 cb2v = *(float4*)&cf[128 + w * 16 + g16 * 4];
      for (int nt = 0; nt < 4; ++nt) {
        f32x4 acc = (f32x4){0.f, 0.f, 0.f, 0.f};
        const int n = nt * 16 + lr, swn = (n & 7) << 3;
#pragma unroll
        for (int ks = 0; ks < 4; ++ks) {
          int c = ks * 32 + g16 * 8;
          v8h ah = *(const v8h*)&KQ0[arow * 128 + (c ^ swa)];
          v8h al = *(const v8h*)&KQ1[arow * 128 + (c ^ swa)];
          v8h bhh = *(const v8h*)&St_h[n * 128 + (c ^ swn)];
          v8h bll = *(const v8h*)&St_l[n * 128 + (c ^ swn)];
          MFMA3(acc, ah, al, bhh, bll);
        }
        float cb1a[4] = {cb1v.x, cb1v.y, cb1v.z, cb1v.w};
        float cb2a[4] = {cb2v.x, cb2v.y, cb2v.z, cb2v.w};
        unsigned short* ph = (unsigned short*)&pBh[nt];
        unsigned short* pl = (unsigned short*)&pBl[nt];
#pragma unroll
        for (int r = 0; r < 4; ++r) {
          int t = w * 16 + g16 * 4 + r;
          float kv = acc[r] * i2_16;
          float Vv = vn[((size_t)bh * 2048 + t0 + t) * 256 + v0 + n];
          float Bv = cb1a[r] * Vv - cb2a[r] * kv;
          splitw(Bv * 64.f, ph[r], pl[r]);
        }
      }
    }
    __syncthreads();
    {
      const int tb = w * 16 + g16 * 4;
      for (int nt = 0; nt < 4; ++nt) {
        const int n = nt * 16 + lr, swn = (n & 7) << 3;
        int ad = n * 64 + (tb ^ swn);
        *(ushort4*)&BT_h[ad] = pBh[nt];
        *(ushort4*)&BT_l[ad] = pBl[nt];
      }
    }
    __syncthreads();
    {
      const int arow = w * 16 + lr, swa = (arow & 7) << 3;
      const int tb = w * 16 + g16 * 4;
      for (int nt = 0; nt < 4; ++nt) {
        f32x4 acc = (f32x4){0.f, 0.f, 0.f, 0.f};
        const int n = nt * 16 + lr, swn = (n & 7) << 3;
#pragma unroll
        for (int ks = 0; ks < 2; ++ks) {
          int c = ks * 32 + g16 * 8;
          v8h ah = *(const v8h*)&Ts_h[arow * 64 + (c ^ swa)];
          v8h al = *(const v8h*)&Ts_l[arow * 64 + (c ^ swa)];
          v8h bhh = *(const v8h*)&BT_h[n * 64 + (c ^ swn)];
          v8h bll = *(const v8h*)&BT_l[n * 64 + (c ^ swn)];
          MFMA3(acc, ah, al, bhh, bll);
        }
        ushort4 H, L;
        unsigned short* ph = (unsigned short*)&H;
        unsigned short* pl = (unsigned short*)&L;
#pragma unroll
        for (int r = 0; r < 4; ++r) splitw(acc[r] * uscale, ph[r], pl[r]);
        int ad = n * 64 + (tb ^ swn);
        *(ushort4*)&UT_h[ad] = H;
        *(ushort4*)&UT_l[ad] = L;
      }
    }
    __syncthreads();
    {
      const int arow = w * 16 + lr, swa = (arow & 7) << 3;
      for (int nt = 0; nt < 4; ++nt) {
        const int n = nt * 16 + lr, swn = (n & 7) << 3;
#pragma unroll
        for (int ks = 0; ks < 2; ++ks) {
          int c = ks * 32 + g16 * 8;
          v8h ah = *(const v8h*)&Hs_h[arow * 64 + (c ^ swa)];
          v8h al = *(const v8h*)&Hs_l[arow * 64 + (c ^ swa)];
          v8h bhh = *(const v8h*)&UT_h[n * 64 + (c ^ swn)];
          v8h bll = *(const v8h*)&UT_l[n * 64 + (c ^ swn)];
          MFMA3(Oacc[nt], ah, al, bhh, bll);
        }
      }
      for (int nt = 0; nt < 4; ++nt) {
        const int n = nt * 16 + lr;
#pragma unroll
        for (int r = 0; r < 4; ++r) {
          int t = t0 + w * 16 + g16 * 4 + r;
          float Ov = Oacc[nt][r] * i2_20;
          float gv = gp[(size_t)t * GW + n];
          out[((size_t)b * 2048 + t) * 4096 + h * 256 + v0 + n] = Ov * (gv / (1.f + expf(-gv)));
        }
      }
    }
    {
      const float cc1024 = cc * 1024.f;
#pragma unroll
      for (int m2 = w * 2; m2 < w * 2 + 2; ++m2) {
        const int arow = m2 * 16 + lr, swa = (arow & 7) << 3;
        const int fb = m2 * 16 + g16 * 4;
        for (int nt = 0; nt < 4; ++nt) {
          const int n = nt * 16 + lr, swn = (n & 7) << 3;
          int sad = n * 128 + (fb ^ swn);
          ushort4 sh4 = *(ushort4*)&St_h[sad];
          ushort4 sl4 = *(ushort4*)&St_l[sad];
          f32x4 acc;
          acc[0] = cc1024 * (h2f(sh4.x) + h2f(sl4.x));
          acc[1] = cc1024 * (h2f(sh4.y) + h2f(sl4.y));
          acc[2] = cc1024 * (h2f(sh4.z) + h2f(sl4.z));
          acc[3] = cc1024 * (h2f(sh4.w) + h2f(sl4.w));
#pragma unroll
          for (int ks = 0; ks < 2; ++ks) {
            int c = ks * 32 + g16 * 8;
            v8h ah = *(const v8h*)&KTs_h[arow * 64 + (c ^ swa)];
            v8h al = *(const v8h*)&KTs_l[arow * 64 + (c ^ swa)];
            v8h bhh = *(const v8h*)&UT_h[n * 64 + (c ^ swn)];
            v8h bll = *(const v8h*)&UT_l[n * 64 + (c ^ swn)];
            MFMA3(acc, ah, al, bhh, bll);
          }
          ushort4 H, L;
          unsigned short* ph = (unsigned short*)&H;
          unsigned short* pl = (unsigned short*)&L;
#pragma unroll
          for (int r = 0; r < 4; ++r) splitw(acc[r] * sscale, ph[r], pl[r]);
          *(ushort4*)&St_h[sad] = H;
          *(ushort4*)&St_l[sad] = L;
        }
      }
    }
    __syncthreads();
  }
}

extern "C" void kernel_launch(void* const* d_in, const int* in_sizes, int n_in,
                              void* d_out, int out_size, void* d_ws, size_t ws_size,
                              hipStream_t stream) {
  const float* hidden  = (const float*)d_in[0];
  const float* W       = (const float*)d_in[1];
  const float* Wc      = (const float*)d_in[2];
  const float* A_log   = (const float*)d_in[3];
  const float* dt_bias = (const float*)d_in[4];
  float* out = (float*)d_out;

  char* ws = (char*)d_ws;
  _Float16* Ap = (_Float16*)ws;
  _Float16* Bp = (_Float16*)(ws + (size_t)33554432);
  float* qn    = (float*)ws;
  float* kn    = qn + (size_t)8388608;
  float* vn    = kn + (size_t)8388608;
  float* g_arr = vn + (size_t)16777216;
  float* beta  = g_arr + (size_t)65536;
  float* projQKV = (float*)(ws + (size_t)135266304);
  char*  tb0 = ws + (size_t)135266304;
  _Float16* Tg_h  = (_Float16*)tb0;
  _Float16* Tg_l  = (_Float16*)(tb0 + (size_t)8388608);
  _Float16* Hg_h  = (_Float16*)(tb0 + (size_t)16777216);
  _Float16* Hg_l  = (_Float16*)(tb0 + (size_t)25165824);
  _Float16* KTg_h = (_Float16*)(tb0 + (size_t)33554432);
  _Float16* KTg_l = (_Float16*)(tb0 + (size_t)50331648);
  float*    coefG = (float*)   (tb0 + (size_t)67108864);
  float* projGate = (float*)(ws + (size_t)269484032);

  pack_A_k<<<32 * KSTEPS, 256, 0, stream>>>(hidden, Ap);
  pack_B_k<<<NTILE_N * KSTEPS, 256, 0, stream>>>(W, Bp);
  gemm_mfma_k<<<32 * NTILE_N, 256, 0, stream>>>(Ap, Bp, projQKV, projGate);

  dim3 g2(8, 64, 2);
  conv_norm_k<<<g2, 128, 0, stream>>>(projQKV, Wc, qn, kn, vn);
  beta_g_k<<<(2 * NH * L_SEQ + 255) / 256, 256, 0, stream>>>(projGate, A_log, dt_bias, beta, g_arr);

  p1a_k<<<1024, 256, 0, stream>>>(kn, g_arr, beta, Tg_h, Tg_l, KTg_h, KTg_l, coefG);
  p1b_k<<<1024, 256, 0, stream>>>(kn, qn, g_arr, Hg_h, Hg_l);
  p2_k<<<128, 256, 0, stream>>>(qn, kn, vn, projGate, Tg_h, Tg_l, Hg_h, Hg_l, KTg_h, KTg_l, coefG, out);
}

// Round 7
// 1307.685 us; speedup vs baseline: 2.9986x; 1.0327x over previous
//
#include <hip/hip_runtime.h>
#include <hip/hip_bf16.h>
#include <hip/hip_fp16.h>
#include <math.h>

#define L_SEQ 2048
#define DM    2048
#define NH    16
#define DH    128
#define HVD   256
#define NPROJ 12320
#define QKVW  8192
#define GW    4128

#define NTILE_N 97
#define KSTEPS  64

typedef _Float16 v8h __attribute__((ext_vector_type(8)));
typedef float f32x4 __attribute__((ext_vector_type(4)));

__device__ __forceinline__ void gload_lds16(const void* g, void* l) {
  __builtin_amdgcn_global_load_lds((const __attribute__((address_space(1))) void*)g,
                                   (__attribute__((address_space(3))) void*)l, 16, 0, 0);
}

__device__ __forceinline__ void splitw(float x, unsigned short& h, unsigned short& l) {
  _Float16 hh = (_Float16)x;
  _Float16 ll = (_Float16)(x - (float)hh);
  h = *(unsigned short*)&hh;
  l = *(unsigned short*)&ll;
}
__device__ __forceinline__ float h2f(unsigned short u) {
  return (float)(*(_Float16*)&u);
}

#define MFMA3(acc, ah, al, bh_, bl_)                                          \
  acc = __builtin_amdgcn_mfma_f32_16x16x32_f16(ah, bh_, acc, 0, 0, 0);        \
  acc = __builtin_amdgcn_mfma_f32_16x16x32_f16(ah, bl_, acc, 0, 0, 0);        \
  acc = __builtin_amdgcn_mfma_f32_16x16x32_f16(al, bh_, acc, 0, 0, 0);

// ---------------- pack A: hidden(4096x2048) f32 -> fp16 hi/lo, x16 ----------------
__global__ __launch_bounds__(256) void pack_A_k(const float* __restrict__ H, _Float16* __restrict__ Ap) {
  const int mtile = blockIdx.x >> 6, kstep = blockIdx.x & 63;
  const size_t base = (size_t)blockIdx.x * 2 * 4096;
#pragma unroll
  for (int it = 0; it < 2; ++it) {
    int s = threadIdx.x + it * 256;
    int g = s >> 7, r = s & 127;
    const float* src = H + ((size_t)(mtile * 128 + r)) * 2048 + kstep * 32 + g * 8;
    float4 x0 = *(const float4*)src;
    float4 x1 = *(const float4*)(src + 4);
    float xs[8] = {x0.x, x0.y, x0.z, x0.w, x1.x, x1.y, x1.z, x1.w};
    v8h hi, lo;
#pragma unroll
    for (int j = 0; j < 8; ++j) {
      float v = xs[j] * 16.f;
      _Float16 h = (_Float16)v;
      hi[j] = h;
      lo[j] = (_Float16)(v - (float)h);
    }
    *(v8h*)(Ap + base + g * 1024 + r * 8) = hi;
    *(v8h*)(Ap + base + 4096 + g * 1024 + r * 8) = lo;
  }
}

// ---------------- pack B: W(2048x12320) f32 -> fp16 hi/lo, x1024 ----------------
__global__ __launch_bounds__(256) void pack_B_k(const float* __restrict__ W, _Float16* __restrict__ Bp) {
  const int ntile = blockIdx.x >> 6, kstep = blockIdx.x & 63;
  const size_t base = (size_t)blockIdx.x * 2 * 4096;
#pragma unroll
  for (int it = 0; it < 2; ++it) {
    int s = threadIdx.x + it * 256;
    int g = s >> 7, col = s & 127;
    int n = ntile * 128 + col;
    v8h hi, lo;
#pragma unroll
    for (int j = 0; j < 8; ++j) {
      int k = kstep * 32 + g * 8 + j;
      float v = (n < NPROJ) ? W[(size_t)k * NPROJ + n] * 1024.f : 0.f;
      _Float16 h = (_Float16)v;
      hi[j] = h;
      lo[j] = (_Float16)(v - (float)h);
    }
    *(v8h*)(Bp + base + g * 1024 + col * 8) = hi;
    *(v8h*)(Bp + base + 4096 + g * 1024 + col * 8) = lo;
  }
}

// ---------------- split-fp16 MFMA GEMM, 2-phase double-buffered, identity block mapping ----------------
// Identity mapping is XCD-optimal here: round-robin dispatch gives each XCD a fixed
// 4-mtile set (4MB A working set = L2 size) with B streamed once via L3 (measured 515MB FETCH).
__global__ __launch_bounds__(256) void gemm_mfma_k(const _Float16* __restrict__ Ap,
                                                   const _Float16* __restrict__ Bp,
                                                   float* __restrict__ Cq,
                                                   float* __restrict__ Cg) {
  __shared__ _Float16 lds[2][16384];   // 64KB: per buf: Ahi Alo Bhi Blo
  const int tid = threadIdx.x;
  const int mtile = blockIdx.x & 31;
  const int ntile = blockIdx.x >> 5;
  const int wid = tid >> 6, lane = tid & 63;
  const int wm = wid >> 1, wn = wid & 1;
  const int lrow = lane & 15, g = lane >> 4;

  f32x4 acc[4][4];
#pragma unroll
  for (int i = 0; i < 4; ++i)
#pragma unroll
    for (int j = 0; j < 4; ++j) acc[i][j] = (f32x4){0.f, 0.f, 0.f, 0.f};

  const int aoff = (wm * 64 + lrow) * 8 + g * 1024;
  const int boff = (wn * 64 + lrow) * 8 + g * 1024;

  const _Float16* Asrc = Ap + ((size_t)(mtile * KSTEPS) * 2) * 4096 + tid * 8;
  const _Float16* Bsrc = Bp + ((size_t)(ntile * KSTEPS) * 2) * 4096 + tid * 8;

  // prologue: stage kstep 0 into buf 0
#pragma unroll
  for (int r = 0; r < 4; ++r) {
    gload_lds16(Asrc + r * 2048, &lds[0][r * 2048 + tid * 8]);
    gload_lds16(Bsrc + r * 2048, &lds[0][8192 + r * 2048 + tid * 8]);
  }
  __syncthreads();

  for (int kstep = 0; kstep < KSTEPS; ++kstep) {
    const int p = kstep & 1;
    if (kstep + 1 < KSTEPS) {     // prefetch next K-step into buf p^1 (in flight during MFMA)
      const _Float16* An = Asrc + (size_t)(kstep + 1) * 8192;
      const _Float16* Bn = Bsrc + (size_t)(kstep + 1) * 8192;
#pragma unroll
      for (int r = 0; r < 4; ++r) {
        gload_lds16(An + r * 2048, &lds[p ^ 1][r * 2048 + tid * 8]);
        gload_lds16(Bn + r * 2048, &lds[p ^ 1][8192 + r * 2048 + tid * 8]);
      }
    }
    v8h ah[4], al[4], bh[4], bl[4];
#pragma unroll
    for (int f = 0; f < 4; ++f) {
      ah[f] = *(const v8h*)&lds[p][aoff + f * 128];
      al[f] = *(const v8h*)&lds[p][4096 + aoff + f * 128];
      bh[f] = *(const v8h*)&lds[p][8192 + boff + f * 128];
      bl[f] = *(const v8h*)&lds[p][12288 + boff + f * 128];
    }
#pragma unroll
    for (int fm = 0; fm < 4; ++fm)
#pragma unroll
      for (int fn = 0; fn < 4; ++fn) {
        acc[fm][fn] = __builtin_amdgcn_mfma_f32_16x16x32_f16(ah[fm], bh[fn], acc[fm][fn], 0, 0, 0);
        acc[fm][fn] = __builtin_amdgcn_mfma_f32_16x16x32_f16(ah[fm], bl[fn], acc[fm][fn], 0, 0, 0);
        acc[fm][fn] = __builtin_amdgcn_mfma_f32_16x16x32_f16(al[fm], bh[fn], acc[fm][fn], 0, 0, 0);
      }
    __syncthreads();   // drains prefetch (covered by MFMA phase) + protects buf reuse
  }

  const float sc = 1.f / 16384.f;
#pragma unroll
  for (int fm = 0; fm < 4; ++fm) {
    int row = mtile * 128 + wm * 64 + fm * 16 + g * 4;
#pragma unroll
    for (int fn = 0; fn < 4; ++fn) {
      int col = ntile * 128 + wn * 64 + fn * 16 + lrow;
      if (col < QKVW) {
#pragma unroll
        for (int r = 0; r < 4; ++r)
          Cq[(size_t)(row + r) * QKVW + col] = acc[fm][fn][r] * sc;
      } else if (col < NPROJ) {
        int lcol = col - QKVW;
#pragma unroll
        for (int r = 0; r < 4; ++r)
          Cg[(size_t)(row + r) * GW + lcol] = acc[fm][fn][r] * sc;
      }
    }
  }
}

// ------------- fused causal depthwise conv(4) + SiLU + l2norm(q,k) + q-scale -------------
__global__ __launch_bounds__(128) void conv_norm_k(
    const float* __restrict__ projQKV, const float* __restrict__ Wc,
    float* __restrict__ qn, float* __restrict__ kn, float* __restrict__ vn)
{
  const int b = blockIdx.z, cc = blockIdx.y, tc = blockIdx.x;
  const int tid = threadIdx.x;
  const int ch = cc * 128 + tid;
  const float W0 = Wc[ch * 4 + 0], W1 = Wc[ch * 4 + 1], W2 = Wc[ch * 4 + 2], W3 = Wc[ch * 4 + 3];
  const int t0 = tc * 256;
  const float* P = projQKV + (size_t)b * L_SEQ * QKVW + ch;

  float w0 = (t0 - 3 >= 0) ? P[(size_t)(t0 - 3) * QKVW] : 0.f;
  float w1 = (t0 - 2 >= 0) ? P[(size_t)(t0 - 2) * QKVW] : 0.f;
  float w2 = (t0 - 1 >= 0) ? P[(size_t)(t0 - 1) * QKVW] : 0.f;

  const bool isq = (ch < 2048);
  const bool isk = (ch >= 2048 && ch < 4096);
  __shared__ float red[2][2];

  float* qdst = nullptr; float* kdst = nullptr; float* vdst = nullptr;
  if (isq) {
    int h = cc;
    qdst = qn + (((size_t)b * NH + h) * L_SEQ) * DH + tid;
  } else if (isk) {
    int h = cc - 16;
    kdst = kn + (((size_t)b * NH + h) * L_SEQ) * DH + tid;
  } else {
    int vc = ch - 4096;
    int h = vc >> 8;
    int vcol = vc & 255;
    vdst = vn + (((size_t)b * NH + h) * L_SEQ) * HVD + vcol;
  }
  const float qscale = 0.08838834764831845f;

  for (int t = t0; t < t0 + 256; ++t) {
    float x = P[(size_t)t * QKVW];
    float y = w0 * W0 + w1 * W1 + w2 * W2 + x * W3;
    w0 = w1; w1 = w2; w2 = x;
    y = y / (1.f + expf(-y));
    if (isq || isk) {
      float ss = y * y;
#pragma unroll
      for (int off = 1; off < 64; off <<= 1) ss += __shfl_xor(ss, off);
      int wv = tid >> 6;
      if ((tid & 63) == 0) red[t & 1][wv] = ss;
      __syncthreads();
      float tot = red[t & 1][0] + red[t & 1][1];
      float nrm = 1.f / sqrtf(tot + 1e-6f);
      float val = y * nrm;
      if (isq) { qdst[(size_t)t * DH] = val * qscale; }
      else     { kdst[(size_t)t * DH] = val; }
    } else {
      vdst[(size_t)t * HVD] = y;
    }
  }
}

// ------------- beta = sigmoid(b), g = -exp(A_log)*softplus(A+dt_bias) -------------
__global__ __launch_bounds__(256) void beta_g_k(
    const float* __restrict__ projGate, const float* __restrict__ A_log,
    const float* __restrict__ dt_bias, float* __restrict__ beta, float* __restrict__ g_out)
{
  int idx = blockIdx.x * 256 + threadIdx.x;
  if (idx >= 2 * NH * L_SEQ) return;
  int t = idx & (L_SEQ - 1);
  int h = (idx >> 11) & (NH - 1);
  int b = idx >> 15;
  size_t row = (size_t)(b * L_SEQ + t) * GW;
  float bv = projGate[row + 4096 + h];
  float av = projGate[row + 4112 + h];
  float be = 1.f / (1.f + expf(-bv));
  float xx = av + dt_bias[h];
  float sp = (xx > 20.f) ? xx : log1pf(expf(xx));
  float g = -expf(A_log[h]) * sp;
  beta[idx] = be;
  g_out[idx] = g;
}

// ------------- Phase 1a: per-chunk T=(I+A)^-1, KT (kw-folded K^T), coef arrays -------------
__global__ __launch_bounds__(256) void p1a_k(
    const float* __restrict__ kn, const float* __restrict__ g_arr, const float* __restrict__ beta_arr,
    _Float16* __restrict__ Tg_h, _Float16* __restrict__ Tg_l,
    _Float16* __restrict__ KTg_h, _Float16* __restrict__ KTg_l,
    float* __restrict__ coefG)
{
  __shared__ _Float16 Kh[8192], Kl[8192];
  __shared__ float Am[4096], Tm[4096];
  __shared__ float lc[64], be[64], kw[64];
  const int cid = blockIdx.x, bh = cid >> 5, ch = cid & 31, t0 = ch * 64;
  const int tid = threadIdx.x, w = tid >> 6, lane = tid & 63, lr = lane & 15, g16 = lane >> 4;

  const float* kb = kn + ((size_t)bh * 2048 + t0) * 128;
#pragma unroll
  for (int l = 0; l < 8; ++l) {
    int s = tid + l * 256;
    int row = s >> 5, c = (s & 31) * 4;
    float4 v = *(const float4*)(kb + (size_t)row * 128 + c);
    ushort4 H, L;
    splitw(v.x * 1024.f, H.x, L.x); splitw(v.y * 1024.f, H.y, L.y);
    splitw(v.z * 1024.f, H.z, L.z); splitw(v.w * 1024.f, H.w, L.w);
    int ad = row * 128 + (c ^ ((row & 7) << 3));
    *(ushort4*)&Kh[ad] = H; *(ushort4*)&Kl[ad] = L;
  }
#pragma unroll
  for (int l = 0; l < 16; ++l) { int s2 = tid + l * 256; Tm[s2] = ((s2 >> 6) == (s2 & 63)) ? 1.f : 0.f; }
  if (tid < 64) {
    float x = g_arr[(size_t)bh * 2048 + t0 + tid];
#pragma unroll
    for (int off = 1; off < 64; off <<= 1) { float y = __shfl_up(x, off); if (tid >= off) x += y; }
    lc[tid] = x;
    float x63 = __shfl(x, 63);
    float b_ = beta_arr[(size_t)bh * 2048 + t0 + tid];
    be[tid] = b_;
    kw[tid] = expf(x63 - x);
    float ca = expf(x);
    coefG[(size_t)cid * 192 + tid] = ca;
    coefG[(size_t)cid * 192 + 64 + tid] = b_;
    coefG[(size_t)cid * 192 + 128 + tid] = b_ * ca;
  }
  __syncthreads();
  const float ds20 = 1.f / 1048576.f;
  for (int nt = 0; nt < 4; ++nt) {
    f32x4 acc = (f32x4){0.f, 0.f, 0.f, 0.f};
    int nrow = nt * 16 + lr;
    int arow = w * 16 + lr;
#pragma unroll
    for (int ks = 0; ks < 4; ++ks) {
      int c = ks * 32 + g16 * 8;
      v8h ah = *(const v8h*)&Kh[arow * 128 + (c ^ ((arow & 7) << 3))];
      v8h al = *(const v8h*)&Kl[arow * 128 + (c ^ ((arow & 7) << 3))];
      v8h bhh = *(const v8h*)&Kh[nrow * 128 + (c ^ ((nrow & 7) << 3))];
      v8h bll = *(const v8h*)&Kl[nrow * 128 + (c ^ ((nrow & 7) << 3))];
      MFMA3(acc, ah, al, bhh, bll);
    }
    int s_ = nt * 16 + lr;
#pragma unroll
    for (int r = 0; r < 4; ++r) {
      int t = w * 16 + g16 * 4 + r;
      float av = (s_ < t) ? acc[r] * ds20 * be[t] * expf(lc[t] - lc[s_]) : 0.f;
      Am[t * 64 + s_] = av;
    }
  }
  __syncthreads();
  for (int s = tid; s < 8192; s += 256) {
    int feat = s >> 6, t = s & 63;
    int ki = t * 128 + (feat ^ ((t & 7) << 3));
    float kvv = ((float)Kh[ki] + (float)Kl[ki]) * kw[t];
    unsigned short hh, ll; splitw(kvv, hh, ll);
    size_t go = (size_t)cid * 8192 + feat * 64 + (t ^ ((feat & 7) << 3));
    *(unsigned short*)&KTg_h[go] = hh;
    *(unsigned short*)&KTg_l[go] = ll;
  }
  if (w == 0) {
    int j = lane;
    for (int t = 1; t < 64; ++t) {
      float sum = 0.f;
      for (int s = 0; s < t; ++s) sum = fmaf(Am[t * 64 + s], Tm[s * 64 + j], sum);
      Tm[t * 64 + j] = ((j == t) ? 1.f : 0.f) - sum;
    }
  }
  __syncthreads();
#pragma unroll
  for (int l = 0; l < 16; ++l) {
    int s2 = tid + l * 256;
    int t = s2 >> 6, sc_ = s2 & 63;
    unsigned short hh, ll; splitw(Tm[s2] * 256.f, hh, ll);
    size_t go = (size_t)cid * 4096 + t * 64 + (sc_ ^ ((t & 7) << 3));
    *(unsigned short*)&Tg_h[go] = hh;
    *(unsigned short*)&Tg_l[go] = ll;
  }
}

// ------------- Phase 1b: Hq[t][s] = exp(lc_t-lc_s) * (q_t . k_s), s<=t  (sigma 16384) -------------
__global__ __launch_bounds__(256) void p1b_k(
    const float* __restrict__ kn, const float* __restrict__ qn, const float* __restrict__ g_arr,
    _Float16* __restrict__ Hg_h, _Float16* __restrict__ Hg_l)
{
  __shared__ _Float16 Kh[8192], Kl[8192], Qh[8192], Ql[8192];
  __shared__ float lc[64];
  const int cid = blockIdx.x, bh = cid >> 5, ch = cid & 31, t0 = ch * 64;
  const int tid = threadIdx.x, w = tid >> 6, lane = tid & 63, lr = lane & 15, g16 = lane >> 4;

  const float* kb = kn + ((size_t)bh * 2048 + t0) * 128;
  const float* qb = qn + ((size_t)bh * 2048 + t0) * 128;
#pragma unroll
  for (int l = 0; l < 8; ++l) {
    int s = tid + l * 256;
    int row = s >> 5, c = (s & 31) * 4;
    int ad = row * 128 + (c ^ ((row & 7) << 3));
    float4 v = *(const float4*)(kb + (size_t)row * 128 + c);
    ushort4 H, L;
    splitw(v.x * 1024.f, H.x, L.x); splitw(v.y * 1024.f, H.y, L.y);
    splitw(v.z * 1024.f, H.z, L.z); splitw(v.w * 1024.f, H.w, L.w);
    *(ushort4*)&Kh[ad] = H; *(ushort4*)&Kl[ad] = L;
    float4 q = *(const float4*)(qb + (size_t)row * 128 + c);
    splitw(q.x * 1024.f, H.x, L.x); splitw(q.y * 1024.f, H.y, L.y);
    splitw(q.z * 1024.f, H.z, L.z); splitw(q.w * 1024.f, H.w, L.w);
    *(ushort4*)&Qh[ad] = H; *(ushort4*)&Ql[ad] = L;
  }
  if (tid < 64) {
    float x = g_arr[(size_t)bh * 2048 + t0 + tid];
#pragma unroll
    for (int off = 1; off < 64; off <<= 1) { float y = __shfl_up(x, off); if (tid >= off) x += y; }
    lc[tid] = x;
  }
  __syncthreads();
  const float ds20 = 1.f / 1048576.f;
  for (int nt = 0; nt < 4; ++nt) {
    f32x4 acc = (f32x4){0.f, 0.f, 0.f, 0.f};
    int nrow = nt * 16 + lr;
    int arow = w * 16 + lr;
#pragma unroll
    for (int ks = 0; ks < 4; ++ks) {
      int c = ks * 32 + g16 * 8;
      v8h ah = *(const v8h*)&Qh[arow * 128 + (c ^ ((arow & 7) << 3))];
      v8h al = *(const v8h*)&Ql[arow * 128 + (c ^ ((arow & 7) << 3))];
      v8h bhh = *(const v8h*)&Kh[nrow * 128 + (c ^ ((nrow & 7) << 3))];
      v8h bll = *(const v8h*)&Kl[nrow * 128 + (c ^ ((nrow & 7) << 3))];
      MFMA3(acc, ah, al, bhh, bll);
    }
    int s_ = nt * 16 + lr;
#pragma unroll
    for (int r = 0; r < 4; ++r) {
      int t = w * 16 + g16 * 4 + r;
      float hv = (s_ <= t) ? acc[r] * ds20 * expf(lc[t] - lc[s_]) : 0.f;
      unsigned short hh, ll; splitw(hv * 16384.f, hh, ll);
      size_t go = (size_t)cid * 4096 + t * 64 + (s_ ^ ((t & 7) << 3));
      *(unsigned short*)&Hg_h[go] = hh;
      *(unsigned short*)&Hg_l[go] = ll;
    }
  }
}

// ------------- Phase 2: sequential chunk scan, MFMA everywhere -------------
__global__ __launch_bounds__(256) void p2_k(
    const float* __restrict__ qn, const float* __restrict__ kn, const float* __restrict__ vn,
    const float* __restrict__ projGate,
    const _Float16* __restrict__ Tg_h, const _Float16* __restrict__ Tg_l,
    const _Float16* __restrict__ Hg_h, const _Float16* __restrict__ Hg_l,
    const _Float16* __restrict__ KTg_h, const _Float16* __restrict__ KTg_l,
    const float* __restrict__ coefG, float* __restrict__ out)
{
  __shared__ _Float16 St_h[8192], St_l[8192];
  __shared__ _Float16 KQ0[8192], KQ1[8192];
  __shared__ _Float16 KTs_h[8192], KTs_l[8192];
  __shared__ _Float16 Ts_h[4096], Ts_l[4096];
  __shared__ _Float16 Hs_h[4096], Hs_l[4096];
  __shared__ float cf[192];

  const int blk = blockIdx.x;
  const int vb = blk >> 5, bh = blk & 31;
  const int b = bh >> 4, h = bh & 15, v0 = vb * 64;
  const int tid = threadIdx.x, w = tid >> 6, lane = tid & 63, lr = lane & 15, g16 = lane >> 4;

  _Float16* BT_h = &KQ0[0];
  _Float16* BT_l = &KQ0[4096];
  _Float16* UT_h = &KQ1[0];
  _Float16* UT_l = &KQ1[4096];

#pragma unroll
  for (int l = 0; l < 16; ++l) { ((unsigned int*)St_h)[tid + l * 256] = 0u; }
#pragma unroll
  for (int l = 0; l < 16; ++l) { ((unsigned int*)St_l)[tid + l * 256] = 0u; }

  const float* qbase = qn + ((size_t)bh * 2048) * 128;
  const float* kbase = kn + ((size_t)bh * 2048) * 128;
  const float* gp = projGate + ((size_t)b * 2048) * GW + h * 256 + v0;
  const float i2_16 = 1.f / 65536.f;
  const float i2_20 = 1.f / 1048576.f;
  const float uscale = 1.f / 256.f;
  const float sscale = 64.f / 65536.f;

  for (int ch = 0; ch < 32; ++ch) {
    const int cid = bh * 32 + ch, t0 = ch * 64;
    {
      const _Float16* th = Tg_h + (size_t)cid * 4096;
      const _Float16* tl = Tg_l + (size_t)cid * 4096;
      const _Float16* hh = Hg_h + (size_t)cid * 4096;
      const _Float16* hl = Hg_l + (size_t)cid * 4096;
      const _Float16* kth = KTg_h + (size_t)cid * 8192;
      const _Float16* ktl = KTg_l + (size_t)cid * 8192;
#pragma unroll
      for (int l = 0; l < 2; ++l) {
        int i = tid + l * 256;
        gload_lds16(th + i * 8, &Ts_h[i * 8]);
        gload_lds16(tl + i * 8, &Ts_l[i * 8]);
        gload_lds16(hh + i * 8, &Hs_h[i * 8]);
        gload_lds16(hl + i * 8, &Hs_l[i * 8]);
      }
#pragma unroll
      for (int l = 0; l < 4; ++l) {
        int i = tid + l * 256;
        gload_lds16(kth + i * 8, &KTs_h[i * 8]);
        gload_lds16(ktl + i * 8, &KTs_l[i * 8]);
      }
      if (tid < 48) gload_lds16(coefG + (size_t)cid * 192 + tid * 4, &cf[tid * 4]);
#pragma unroll
      for (int l = 0; l < 8; ++l) {
        int s = tid + l * 256;
        int row = s >> 5, c = (s & 31) * 4;
        float4 v = *(const float4*)(qbase + (size_t)(t0 + row) * 128 + c);
        ushort4 H, L;
        splitw(v.x * 1024.f, H.x, L.x); splitw(v.y * 1024.f, H.y, L.y);
        splitw(v.z * 1024.f, H.z, L.z); splitw(v.w * 1024.f, H.w, L.w);
        int ad = row * 128 + (c ^ ((row & 7) << 3));
        *(ushort4*)&KQ0[ad] = H; *(ushort4*)&KQ1[ad] = L;
      }
    }
    __syncthreads();
    const float cc = cf[63];
    f32x4 Oacc[4];
    {
      const int arow = w * 16 + lr, swa = (arow & 7) << 3;
      for (int nt = 0; nt < 4; ++nt) {
        f32x4 acc = (f32x4){0.f, 0.f, 0.f, 0.f};
        const int n = nt * 16 + lr, swn = (n & 7) << 3;
#pragma unroll
        for (int ks = 0; ks < 4; ++ks) {
          int c = ks * 32 + g16 * 8;
          v8h ah = *(const v8h*)&KQ0[arow * 128 + (c ^ swa)];
          v8h al = *(const v8h*)&KQ1[arow * 128 + (c ^ swa)];
          v8h bhh = *(const v8h*)&St_h[n * 128 + (c ^ swn)];
          v8h bll = *(const v8h*)&St_l[n * 128 + (c ^ swn)];
          MFMA3(acc, ah, al, bhh, bll);
        }
        Oacc[nt] = acc;
      }
      float4 cav = *(float4*)&cf[w * 16 + g16 * 4];
#pragma unroll
      for (int nt = 0; nt < 4; ++nt) {
        Oacc[nt][0] *= cav.x * 16.f; Oacc[nt][1] *= cav.y * 16.f;
        Oacc[nt][2] *= cav.z * 16.f; Oacc[nt][3] *= cav.w * 16.f;
      }
    }
    __syncthreads();
#pragma unroll
    for (int l = 0; l < 8; ++l) {
      int s = tid + l * 256;
      int row = s >> 5, c = (s & 31) * 4;
      float4 v = *(const float4*)(kbase + (size_t)(t0 + row) * 128 + c);
      ushort4 H, L;
      splitw(v.x * 1024.f, H.x, L.x); splitw(v.y * 1024.f, H.y, L.y);
      splitw(v.z * 1024.f, H.z, L.z); splitw(v.w * 1024.f, H.w, L.w);
      int ad = row * 128 + (c ^ ((row & 7) << 3));
      *(ushort4*)&KQ0[ad] = H; *(ushort4*)&KQ1[ad] = L;
    }
    __syncthreads();
    ushort4 pBh[4], pBl[4];
    {
      const int arow = w * 16 + lr, swa = (arow & 7) << 3;
      float4 cb1v = *(float4*)&cf[64 + w * 16 + g16 * 4];
      float4 cb2v = *(float4*)&cf[128 + w * 16 + g16 * 4];
      for (int nt = 0; nt < 4; ++nt) {
        f32x4 acc = (f32x4){0.f, 0.f, 0.f, 0.f};
        const int n = nt * 16 + lr, swn = (n & 7) << 3;
#pragma unroll
        for (int ks = 0; ks < 4; ++ks) {
          int c = ks * 32 + g16 * 8;
          v8h ah = *(const v8h*)&KQ0[arow * 128 + (c ^ swa)];
          v8h al = *(const v8h*)&KQ1[arow * 128 + (c ^ swa)];
          v8h bhh = *(const v8h*)&St_h[n * 128 + (c ^ swn)];
          v8h bll = *(const v8h*)&St_l[n * 128 + (c ^ swn)];
          MFMA3(acc, ah, al, bhh, bll);
        }
        float cb1a[4] = {cb1v.x, cb1v.y, cb1v.z, cb1v.w};
        float cb2a[4] = {cb2v.x, cb2v.y, cb2v.z, cb2v.w};
        unsigned short* ph = (unsigned short*)&pBh[nt];
        unsigned short* pl = (unsigned short*)&pBl[nt];
#pragma unroll
        for (int r = 0; r < 4; ++r) {
          int t = w * 16 + g16 * 4 + r;
          float kv = acc[r] * i2_16;
          float Vv = vn[((size_t)bh * 2048 + t0 + t) * 256 + v0 + n];
          float Bv = cb1a[r] * Vv - cb2a[r] * kv;
          splitw(Bv * 64.f, ph[r], pl[r]);
        }
      }
    }
    __syncthreads();
    {
      const int tb = w * 16 + g16 * 4;
      for (int nt = 0; nt < 4; ++nt) {
        const int n = nt * 16 + lr, swn = (n & 7) << 3;
        int ad = n * 64 + (tb ^ swn);
        *(ushort4*)&BT_h[ad] = pBh[nt];
        *(ushort4*)&BT_l[ad] = pBl[nt];
      }
    }
    __syncthreads();
    {
      const int arow = w * 16 + lr, swa = (arow & 7) << 3;
      const int tb = w * 16 + g16 * 4;
      for (int nt = 0; nt < 4; ++nt) {
        f32x4 acc = (f32x4){0.f, 0.f, 0.f, 0.f};
        const int n = nt * 16 + lr, swn = (n & 7) << 3;
#pragma unroll
        for (int ks = 0; ks < 2; ++ks) {
          int c = ks * 32 + g16 * 8;
          v8h ah = *(const v8h*)&Ts_h[arow * 64 + (c ^ swa)];
          v8h al = *(const v8h*)&Ts_l[arow * 64 + (c ^ swa)];
          v8h bhh = *(const v8h*)&BT_h[n * 64 + (c ^ swn)];
          v8h bll = *(const v8h*)&BT_l[n * 64 + (c ^ swn)];
          MFMA3(acc, ah, al, bhh, bll);
        }
        ushort4 H, L;
        unsigned short* ph = (unsigned short*)&H;
        unsigned short* pl = (unsigned short*)&L;
#pragma unroll
        for (int r = 0; r < 4; ++r) splitw(acc[r] * uscale, ph[r], pl[r]);
        int ad = n * 64 + (tb ^ swn);
        *(ushort4*)&UT_h[ad] = H;
        *(ushort4*)&UT_l[ad] = L;
      }
    }
    __syncthreads();
    {
      const int arow = w * 16 + lr, swa = (arow & 7) << 3;
      for (int nt = 0; nt < 4; ++nt) {
        const int n = nt * 16 + lr, swn = (n & 7) << 3;
#pragma unroll
        for (int ks = 0; ks < 2; ++ks) {
          int c = ks * 32 + g16 * 8;
          v8h ah = *(const v8h*)&Hs_h[arow * 64 + (c ^ swa)];
          v8h al = *(const v8h*)&Hs_l[arow * 64 + (c ^ swa)];
          v8h bhh = *(const v8h*)&UT_h[n * 64 + (c ^ swn)];
          v8h bll = *(const v8h*)&UT_l[n * 64 + (c ^ swn)];
          MFMA3(Oacc[nt], ah, al, bhh, bll);
        }
      }
      for (int nt = 0; nt < 4; ++nt) {
        const int n = nt * 16 + lr;
#pragma unroll
        for (int r = 0; r < 4; ++r) {
          int t = t0 + w * 16 + g16 * 4 + r;
          float Ov = Oacc[nt][r] * i2_20;
          float gv = gp[(size_t)t * GW + n];
          out[((size_t)b * 2048 + t) * 4096 + h * 256 + v0 + n] = Ov * (gv / (1.f + expf(-gv)));
        }
      }
    }
    {
      const float cc1024 = cc * 1024.f;
#pragma unroll
      for (int m2 = w * 2; m2 < w * 2 + 2; ++m2) {
        const int arow = m2 * 16 + lr, swa = (arow & 7) << 3;
        const int fb = m2 * 16 + g16 * 4;
        for (int nt = 0; nt < 4; ++nt) {
          const int n = nt * 16 + lr, swn = (n & 7) << 3;
          int sad = n * 128 + (fb ^ swn);
          ushort4 sh4 = *(ushort4*)&St_h[sad];
          ushort4 sl4 = *(ushort4*)&St_l[sad];
          f32x4 acc;
          acc[0] = cc1024 * (h2f(sh4.x) + h2f(sl4.x));
          acc[1] = cc1024 * (h2f(sh4.y) + h2f(sl4.y));
          acc[2] = cc1024 * (h2f(sh4.z) + h2f(sl4.z));
          acc[3] = cc1024 * (h2f(sh4.w) + h2f(sl4.w));
#pragma unroll
          for (int ks = 0; ks < 2; ++ks) {
            int c = ks * 32 + g16 * 8;
            v8h ah = *(const v8h*)&KTs_h[arow * 64 + (c ^ swa)];
            v8h al = *(const v8h*)&KTs_l[arow * 64 + (c ^ swa)];
            v8h bhh = *(const v8h*)&UT_h[n * 64 + (c ^ swn)];
            v8h bll = *(const v8h*)&UT_l[n * 64 + (c ^ swn)];
            MFMA3(acc, ah, al, bhh, bll);
          }
          ushort4 H, L;
          unsigned short* ph = (unsigned short*)&H;
          unsigned short* pl = (unsigned short*)&L;
#pragma unroll
          for (int r = 0; r < 4; ++r) splitw(acc[r] * sscale, ph[r], pl[r]);
          *(ushort4*)&St_h[sad] = H;
          *(ushort4*)&St_l[sad] = L;
        }
      }
    }
    __syncthreads();
  }
}

extern "C" void kernel_launch(void* const* d_in, const int* in_sizes, int n_in,
                              void* d_out, int out_size, void* d_ws, size_t ws_size,
                              hipStream_t stream) {
  const float* hidden  = (const float*)d_in[0];
  const float* W       = (const float*)d_in[1];
  const float* Wc      = (const float*)d_in[2];
  const float* A_log   = (const float*)d_in[3];
  const float* dt_bias = (const float*)d_in[4];
  float* out = (float*)d_out;

  char* ws = (char*)d_ws;
  _Float16* Ap = (_Float16*)ws;
  _Float16* Bp = (_Float16*)(ws + (size_t)33554432);
  float* qn    = (float*)ws;
  float* kn    = qn + (size_t)8388608;
  float* vn    = kn + (size_t)8388608;
  float* g_arr = vn + (size_t)16777216;
  float* beta  = g_arr + (size_t)65536;
  float* projQKV = (float*)(ws + (size_t)135266304);
  char*  tb0 = ws + (size_t)135266304;
  _Float16* Tg_h  = (_Float16*)tb0;
  _Float16* Tg_l  = (_Float16*)(tb0 + (size_t)8388608);
  _Float16* Hg_h  = (_Float16*)(tb0 + (size_t)16777216);
  _Float16* Hg_l  = (_Float16*)(tb0 + (size_t)25165824);
  _Float16* KTg_h = (_Float16*)(tb0 + (size_t)33554432);
  _Float16* KTg_l = (_Float16*)(tb0 + (size_t)50331648);
  float*    coefG = (float*)   (tb0 + (size_t)67108864);
  float* projGate = (float*)(ws + (size_t)269484032);

  pack_A_k<<<32 * KSTEPS, 256, 0, stream>>>(hidden, Ap);
  pack_B_k<<<NTILE_N * KSTEPS, 256, 0, stream>>>(W, Bp);
  gemm_mfma_k<<<32 * NTILE_N, 256, 0, stream>>>(Ap, Bp, projQKV, projGate);

  dim3 g2(8, 64, 2);
  conv_norm_k<<<g2, 128, 0, stream>>>(projQKV, Wc, qn, kn, vn);
  beta_g_k<<<(2 * NH * L_SEQ + 255) / 256, 256, 0, stream>>>(projGate, A_log, dt_bias, beta, g_arr);

  p1a_k<<<1024, 256, 0, stream>>>(kn, g_arr, beta, Tg_h, Tg_l, KTg_h, KTg_l, coefG);
  p1b_k<<<1024, 256, 0, stream>>>(kn, qn, g_arr, Hg_h, Hg_l);
  p2_k<<<128, 256, 0, stream>>>(qn, kn, vn, projGate, Tg_h, Tg_l, Hg_h, Hg_l, KTg_h, KTg_l, coefG, out);
}

// Round 8
// 1175.429 us; speedup vs baseline: 3.3360x; 1.1125x over previous
//
#include <hip/hip_runtime.h>
#include <hip/hip_bf16.h>
#include <hip/hip_fp16.h>
#include <math.h>

#define L_SEQ 2048
#define DM    2048
#define NH    16
#define DH    128
#define HVD   256
#define NPROJ 12320
#define QKVW  8192
#define GW    4128

#define NTILE_N 97
#define KSTEPS  64

typedef _Float16 v8h __attribute__((ext_vector_type(8)));
typedef float f32x4 __attribute__((ext_vector_type(4)));

__device__ __forceinline__ void gload_lds16(const void* g, void* l) {
  __builtin_amdgcn_global_load_lds((const __attribute__((address_space(1))) void*)g,
                                   (__attribute__((address_space(3))) void*)l, 16, 0, 0);
}

__device__ __forceinline__ void splitw(float x, unsigned short& h, unsigned short& l) {
  _Float16 hh = (_Float16)x;
  _Float16 ll = (_Float16)(x - (float)hh);
  h = *(unsigned short*)&hh;
  l = *(unsigned short*)&ll;
}
__device__ __forceinline__ float h2f(unsigned short u) {
  return (float)(*(_Float16*)&u);
}

#define MFMA3(acc, ah, al, bh_, bl_)                                          \
  acc = __builtin_amdgcn_mfma_f32_16x16x32_f16(ah, bh_, acc, 0, 0, 0);        \
  acc = __builtin_amdgcn_mfma_f32_16x16x32_f16(ah, bl_, acc, 0, 0, 0);        \
  acc = __builtin_amdgcn_mfma_f32_16x16x32_f16(al, bh_, acc, 0, 0, 0);

// ---------------- pack A: hidden(4096x2048) f32 -> fp16 hi/lo, x16 ----------------
__global__ __launch_bounds__(256) void pack_A_k(const float* __restrict__ H, _Float16* __restrict__ Ap) {
  const int mtile = blockIdx.x >> 6, kstep = blockIdx.x & 63;
  const size_t base = (size_t)blockIdx.x * 2 * 4096;
#pragma unroll
  for (int it = 0; it < 2; ++it) {
    int s = threadIdx.x + it * 256;
    int g = s >> 7, r = s & 127;
    const float* src = H + ((size_t)(mtile * 128 + r)) * 2048 + kstep * 32 + g * 8;
    float4 x0 = *(const float4*)src;
    float4 x1 = *(const float4*)(src + 4);
    float xs[8] = {x0.x, x0.y, x0.z, x0.w, x1.x, x1.y, x1.z, x1.w};
    v8h hi, lo;
#pragma unroll
    for (int j = 0; j < 8; ++j) {
      float v = xs[j] * 16.f;
      _Float16 h = (_Float16)v;
      hi[j] = h;
      lo[j] = (_Float16)(v - (float)h);
    }
    *(v8h*)(Ap + base + g * 1024 + r * 8) = hi;
    *(v8h*)(Ap + base + 4096 + g * 1024 + r * 8) = lo;
  }
}

// ---------------- pack B: W(2048x12320) f32 -> fp16 hi/lo, x1024 ----------------
__global__ __launch_bounds__(256) void pack_B_k(const float* __restrict__ W, _Float16* __restrict__ Bp) {
  const int ntile = blockIdx.x >> 6, kstep = blockIdx.x & 63;
  const size_t base = (size_t)blockIdx.x * 2 * 4096;
#pragma unroll
  for (int it = 0; it < 2; ++it) {
    int s = threadIdx.x + it * 256;
    int g = s >> 7, col = s & 127;
    int n = ntile * 128 + col;
    v8h hi, lo;
#pragma unroll
    for (int j = 0; j < 8; ++j) {
      int k = kstep * 32 + g * 8 + j;
      float v = (n < NPROJ) ? W[(size_t)k * NPROJ + n] * 1024.f : 0.f;
      _Float16 h = (_Float16)v;
      hi[j] = h;
      lo[j] = (_Float16)(v - (float)h);
    }
    *(v8h*)(Bp + base + g * 1024 + col * 8) = hi;
    *(v8h*)(Bp + base + 4096 + g * 1024 + col * 8) = lo;
  }
}

// ---------------- split-fp16 MFMA GEMM: counted-vmcnt 2-buffer pipeline ----------------
// Identity block mapping (XCD-optimal: fixed 4-mtile set per XCD = 4MB = L2).
// T4: loads for step k+1 stay IN FLIGHT across both barriers; vmcnt(8) waits only step k.
__global__ __launch_bounds__(256) void gemm_mfma_k(const _Float16* __restrict__ Ap,
                                                   const _Float16* __restrict__ Bp,
                                                   float* __restrict__ Cq,
                                                   float* __restrict__ Cg) {
  __shared__ _Float16 lds[2][16384];   // 64KB: per buf: Ahi Alo Bhi Blo
  const int tid = threadIdx.x;
  const int mtile = blockIdx.x & 31;
  const int ntile = blockIdx.x >> 5;
  const int wid = tid >> 6, lane = tid & 63;
  const int wm = wid >> 1, wn = wid & 1;
  const int lrow = lane & 15, g = lane >> 4;

  f32x4 acc[4][4];
#pragma unroll
  for (int i = 0; i < 4; ++i)
#pragma unroll
    for (int j = 0; j < 4; ++j) acc[i][j] = (f32x4){0.f, 0.f, 0.f, 0.f};

  const int aoff = (wm * 64 + lrow) * 8 + g * 1024;
  const int boff = (wn * 64 + lrow) * 8 + g * 1024;

  const _Float16* Asrc = Ap + ((size_t)(mtile * KSTEPS) * 2) * 4096 + tid * 8;
  const _Float16* Bsrc = Bp + ((size_t)(ntile * KSTEPS) * 2) * 4096 + tid * 8;

#define STAGE(KS, BUF)                                                         \
  {                                                                            \
    const _Float16* An_ = Asrc + (size_t)(KS) * 8192;                          \
    const _Float16* Bn_ = Bsrc + (size_t)(KS) * 8192;                          \
    _Pragma("unroll")                                                          \
    for (int r = 0; r < 4; ++r) {                                              \
      gload_lds16(An_ + r * 2048, &lds[BUF][r * 2048 + tid * 8]);              \
      gload_lds16(Bn_ + r * 2048, &lds[BUF][8192 + r * 2048 + tid * 8]);       \
    }                                                                          \
  }

  // prologue: two K-steps in flight
  STAGE(0, 0);
  STAGE(1, 1);

  for (int kstep = 0; kstep < KSTEPS; ++kstep) {
    const int p = kstep & 1;
    if (kstep + 1 < KSTEPS) {
      asm volatile("s_waitcnt vmcnt(8)" ::: "memory");   // step k's 8 loads done; k+1's stay in flight
    } else {
      asm volatile("s_waitcnt vmcnt(0)" ::: "memory");   // last step: drain
    }
    __builtin_amdgcn_sched_barrier(0);
    __builtin_amdgcn_s_barrier();                         // all waves' step-k data in LDS
    __builtin_amdgcn_sched_barrier(0);

    v8h ah[4], al[4], bh[4], bl[4];
#pragma unroll
    for (int f = 0; f < 4; ++f) {
      ah[f] = *(const v8h*)&lds[p][aoff + f * 128];
      al[f] = *(const v8h*)&lds[p][4096 + aoff + f * 128];
      bh[f] = *(const v8h*)&lds[p][8192 + boff + f * 128];
      bl[f] = *(const v8h*)&lds[p][12288 + boff + f * 128];
    }
#pragma unroll
    for (int fm = 0; fm < 4; ++fm)
#pragma unroll
      for (int fn = 0; fn < 4; ++fn) {
        acc[fm][fn] = __builtin_amdgcn_mfma_f32_16x16x32_f16(ah[fm], bh[fn], acc[fm][fn], 0, 0, 0);
        acc[fm][fn] = __builtin_amdgcn_mfma_f32_16x16x32_f16(ah[fm], bl[fn], acc[fm][fn], 0, 0, 0);
        acc[fm][fn] = __builtin_amdgcn_mfma_f32_16x16x32_f16(al[fm], bh[fn], acc[fm][fn], 0, 0, 0);
      }
    __builtin_amdgcn_sched_barrier(0);
    __builtin_amdgcn_s_barrier();                         // all waves done reading buf p
    __builtin_amdgcn_sched_barrier(0);
    if (kstep + 2 < KSTEPS) STAGE(kstep + 2, p);          // refill freed buffer
  }
#undef STAGE

  const float sc = 1.f / 16384.f;
#pragma unroll
  for (int fm = 0; fm < 4; ++fm) {
    int row = mtile * 128 + wm * 64 + fm * 16 + g * 4;
#pragma unroll
    for (int fn = 0; fn < 4; ++fn) {
      int col = ntile * 128 + wn * 64 + fn * 16 + lrow;
      if (col < QKVW) {
#pragma unroll
        for (int r = 0; r < 4; ++r)
          Cq[(size_t)(row + r) * QKVW + col] = acc[fm][fn][r] * sc;
      } else if (col < NPROJ) {
        int lcol = col - QKVW;
#pragma unroll
        for (int r = 0; r < 4; ++r)
          Cg[(size_t)(row + r) * GW + lcol] = acc[fm][fn][r] * sc;
      }
    }
  }
}

// ------------- conv+silu+l2norm for q/k: one wave per (head, t-chunk), no barriers -------------
// grid (32 tc, 32 hg, 2 b), block 64. Lane owns 2 channels; full-wave shfl reduce.
__global__ __launch_bounds__(64) void conv_qk_k(
    const float* __restrict__ projQKV, const float* __restrict__ Wc,
    float* __restrict__ qn, float* __restrict__ kn)
{
  const int b = blockIdx.z, hg = blockIdx.y, tc = blockIdx.x;
  const int lane = threadIdx.x;
  const int ch = hg * 128 + lane * 2;          // 0..4095 (q then k)
  float4 Wa = *(const float4*)(Wc + (size_t)ch * 4);
  float4 Wb = *(const float4*)(Wc + (size_t)ch * 4 + 4);
  const int t0 = tc * 64;
  const float* P = projQKV + (size_t)b * L_SEQ * QKVW + ch;
  float2 w0 = make_float2(0.f, 0.f), w1 = w0, w2 = w0;
  if (t0 >= 3) w0 = *(const float2*)(P + (size_t)(t0 - 3) * QKVW);
  if (t0 >= 2) w1 = *(const float2*)(P + (size_t)(t0 - 2) * QKVW);
  if (t0 >= 1) w2 = *(const float2*)(P + (size_t)(t0 - 1) * QKVW);
  const bool isq = hg < 16;
  const int h = isq ? hg : hg - 16;
  float* dst = (isq ? qn : kn) + (((size_t)b * NH + h) * L_SEQ) * DH + lane * 2;
  const float sc = isq ? 0.08838834764831845f : 1.f;
  for (int t = t0; t < t0 + 64; ++t) {
    float2 x = *(const float2*)(P + (size_t)t * QKVW);
    float y0 = w0.x * Wa.x + w1.x * Wa.y + w2.x * Wa.z + x.x * Wa.w;
    float y1 = w0.y * Wb.x + w1.y * Wb.y + w2.y * Wb.z + x.y * Wb.w;
    w0 = w1; w1 = w2; w2 = x;
    y0 = y0 / (1.f + expf(-y0));
    y1 = y1 / (1.f + expf(-y1));
    float ss = y0 * y0 + y1 * y1;
#pragma unroll
    for (int off = 1; off < 64; off <<= 1) ss += __shfl_xor(ss, off);
    float nrm = sc / sqrtf(ss + 1e-6f);
    *(float2*)(dst + (size_t)t * DH) = make_float2(y0 * nrm, y1 * nrm);
  }
}

// ------------- conv+silu for v: elementwise, float4 per thread -------------
// grid (32 tc, 4 cg, 2 b), block 256.
__global__ __launch_bounds__(256) void conv_v_k(
    const float* __restrict__ projQKV, const float* __restrict__ Wc,
    float* __restrict__ vn)
{
  const int b = blockIdx.z, cg = blockIdx.y, tc = blockIdx.x;
  const int vc = (cg * 256 + threadIdx.x) * 4;     // 0..4092
  const int ch = 4096 + vc;
  float4 Wv0 = *(const float4*)(Wc + (size_t)ch * 4);
  float4 Wv1 = *(const float4*)(Wc + (size_t)ch * 4 + 4);
  float4 Wv2 = *(const float4*)(Wc + (size_t)ch * 4 + 8);
  float4 Wv3 = *(const float4*)(Wc + (size_t)ch * 4 + 12);
  const int t0 = tc * 64;
  const float* P = projQKV + (size_t)b * L_SEQ * QKVW + ch;
  float4 w0 = make_float4(0.f, 0.f, 0.f, 0.f), w1 = w0, w2 = w0;
  if (t0 >= 3) w0 = *(const float4*)(P + (size_t)(t0 - 3) * QKVW);
  if (t0 >= 2) w1 = *(const float4*)(P + (size_t)(t0 - 2) * QKVW);
  if (t0 >= 1) w2 = *(const float4*)(P + (size_t)(t0 - 1) * QKVW);
  const int h = vc >> 8, vcol = vc & 255;
  float* dst = vn + (((size_t)b * NH + h) * L_SEQ) * HVD + vcol;
  for (int t = t0; t < t0 + 64; ++t) {
    float4 x = *(const float4*)(P + (size_t)t * QKVW);
    float4 y;
    y.x = w0.x * Wv0.x + w1.x * Wv0.y + w2.x * Wv0.z + x.x * Wv0.w;
    y.y = w0.y * Wv1.x + w1.y * Wv1.y + w2.y * Wv1.z + x.y * Wv1.w;
    y.z = w0.z * Wv2.x + w1.z * Wv2.y + w2.z * Wv2.z + x.z * Wv2.w;
    y.w = w0.w * Wv3.x + w1.w * Wv3.y + w2.w * Wv3.z + x.w * Wv3.w;
    w0 = w1; w1 = w2; w2 = x;
    y.x = y.x / (1.f + expf(-y.x));
    y.y = y.y / (1.f + expf(-y.y));
    y.z = y.z / (1.f + expf(-y.z));
    y.w = y.w / (1.f + expf(-y.w));
    *(float4*)(dst + (size_t)t * HVD) = y;
  }
}

// ------------- beta = sigmoid(b), g = -exp(A_log)*softplus(A+dt_bias) -------------
__global__ __launch_bounds__(256) void beta_g_k(
    const float* __restrict__ projGate, const float* __restrict__ A_log,
    const float* __restrict__ dt_bias, float* __restrict__ beta, float* __restrict__ g_out)
{
  int idx = blockIdx.x * 256 + threadIdx.x;
  if (idx >= 2 * NH * L_SEQ) return;
  int t = idx & (L_SEQ - 1);
  int h = (idx >> 11) & (NH - 1);
  int b = idx >> 15;
  size_t row = (size_t)(b * L_SEQ + t) * GW;
  float bv = projGate[row + 4096 + h];
  float av = projGate[row + 4112 + h];
  float be = 1.f / (1.f + expf(-bv));
  float xx = av + dt_bias[h];
  float sp = (xx > 20.f) ? xx : log1pf(expf(xx));
  float g = -expf(A_log[h]) * sp;
  beta[idx] = be;
  g_out[idx] = g;
}

// ------------- Phase 1a: per-chunk T=(I+A)^-1, KT (kw-folded K^T), coef arrays -------------
__global__ __launch_bounds__(256) void p1a_k(
    const float* __restrict__ kn, const float* __restrict__ g_arr, const float* __restrict__ beta_arr,
    _Float16* __restrict__ Tg_h, _Float16* __restrict__ Tg_l,
    _Float16* __restrict__ KTg_h, _Float16* __restrict__ KTg_l,
    float* __restrict__ coefG)
{
  __shared__ _Float16 Kh[8192], Kl[8192];
  __shared__ float Am[4096], Tm[4096];
  __shared__ float lc[64], be[64], kw[64];
  const int cid = blockIdx.x, bh = cid >> 5, ch = cid & 31, t0 = ch * 64;
  const int tid = threadIdx.x, w = tid >> 6, lane = tid & 63, lr = lane & 15, g16 = lane >> 4;

  const float* kb = kn + ((size_t)bh * 2048 + t0) * 128;
#pragma unroll
  for (int l = 0; l < 8; ++l) {
    int s = tid + l * 256;
    int row = s >> 5, c = (s & 31) * 4;
    float4 v = *(const float4*)(kb + (size_t)row * 128 + c);
    ushort4 H, L;
    splitw(v.x * 1024.f, H.x, L.x); splitw(v.y * 1024.f, H.y, L.y);
    splitw(v.z * 1024.f, H.z, L.z); splitw(v.w * 1024.f, H.w, L.w);
    int ad = row * 128 + (c ^ ((row & 7) << 3));
    *(ushort4*)&Kh[ad] = H; *(ushort4*)&Kl[ad] = L;
  }
#pragma unroll
  for (int l = 0; l < 16; ++l) { int s2 = tid + l * 256; Tm[s2] = ((s2 >> 6) == (s2 & 63)) ? 1.f : 0.f; }
  if (tid < 64) {
    float x = g_arr[(size_t)bh * 2048 + t0 + tid];
#pragma unroll
    for (int off = 1; off < 64; off <<= 1) { float y = __shfl_up(x, off); if (tid >= off) x += y; }
    lc[tid] = x;
    float x63 = __shfl(x, 63);
    float b_ = beta_arr[(size_t)bh * 2048 + t0 + tid];
    be[tid] = b_;
    kw[tid] = expf(x63 - x);
    float ca = expf(x);
    coefG[(size_t)cid * 192 + tid] = ca;
    coefG[(size_t)cid * 192 + 64 + tid] = b_;
    coefG[(size_t)cid * 192 + 128 + tid] = b_ * ca;
  }
  __syncthreads();
  const float ds20 = 1.f / 1048576.f;
  for (int nt = 0; nt < 4; ++nt) {
    f32x4 acc = (f32x4){0.f, 0.f, 0.f, 0.f};
    int nrow = nt * 16 + lr;
    int arow = w * 16 + lr;
#pragma unroll
    for (int ks = 0; ks < 4; ++ks) {
      int c = ks * 32 + g16 * 8;
      v8h ah = *(const v8h*)&Kh[arow * 128 + (c ^ ((arow & 7) << 3))];
      v8h al = *(const v8h*)&Kl[arow * 128 + (c ^ ((arow & 7) << 3))];
      v8h bhh = *(const v8h*)&Kh[nrow * 128 + (c ^ ((nrow & 7) << 3))];
      v8h bll = *(const v8h*)&Kl[nrow * 128 + (c ^ ((nrow & 7) << 3))];
      MFMA3(acc, ah, al, bhh, bll);
    }
    int s_ = nt * 16 + lr;
#pragma unroll
    for (int r = 0; r < 4; ++r) {
      int t = w * 16 + g16 * 4 + r;
      float av = (s_ < t) ? acc[r] * ds20 * be[t] * expf(lc[t] - lc[s_]) : 0.f;
      Am[t * 64 + s_] = av;
    }
  }
  __syncthreads();
  for (int s = tid; s < 8192; s += 256) {
    int feat = s >> 6, t = s & 63;
    int ki = t * 128 + (feat ^ ((t & 7) << 3));
    float kvv = ((float)Kh[ki] + (float)Kl[ki]) * kw[t];
    unsigned short hh, ll; splitw(kvv, hh, ll);
    size_t go = (size_t)cid * 8192 + feat * 64 + (t ^ ((feat & 7) << 3));
    *(unsigned short*)&KTg_h[go] = hh;
    *(unsigned short*)&KTg_l[go] = ll;
  }
  if (w == 0) {
    int j = lane;
    for (int t = 1; t < 64; ++t) {
      float sum = 0.f;
      for (int s = 0; s < t; ++s) sum = fmaf(Am[t * 64 + s], Tm[s * 64 + j], sum);
      Tm[t * 64 + j] = ((j == t) ? 1.f : 0.f) - sum;
    }
  }
  __syncthreads();
#pragma unroll
  for (int l = 0; l < 16; ++l) {
    int s2 = tid + l * 256;
    int t = s2 >> 6, sc_ = s2 & 63;
    unsigned short hh, ll; splitw(Tm[s2] * 256.f, hh, ll);
    size_t go = (size_t)cid * 4096 + t * 64 + (sc_ ^ ((t & 7) << 3));
    *(unsigned short*)&Tg_h[go] = hh;
    *(unsigned short*)&Tg_l[go] = ll;
  }
}

// ------------- Phase 1b: Hq[t][s] = exp(lc_t-lc_s) * (q_t . k_s), s<=t  (sigma 16384) -------------
__global__ __launch_bounds__(256) void p1b_k(
    const float* __restrict__ kn, const float* __restrict__ qn, const float* __restrict__ g_arr,
    _Float16* __restrict__ Hg_h, _Float16* __restrict__ Hg_l)
{
  __shared__ _Float16 Kh[8192], Kl[8192], Qh[8192], Ql[8192];
  __shared__ float lc[64];
  const int cid = blockIdx.x, bh = cid >> 5, ch = cid & 31, t0 = ch * 64;
  const int tid = threadIdx.x, w = tid >> 6, lane = tid & 63, lr = lane & 15, g16 = lane >> 4;

  const float* kb = kn + ((size_t)bh * 2048 + t0) * 128;
  const float* qb = qn + ((size_t)bh * 2048 + t0) * 128;
#pragma unroll
  for (int l = 0; l < 8; ++l) {
    int s = tid + l * 256;
    int row = s >> 5, c = (s & 31) * 4;
    int ad = row * 128 + (c ^ ((row & 7) << 3));
    float4 v = *(const float4*)(kb + (size_t)row * 128 + c);
    ushort4 H, L;
    splitw(v.x * 1024.f, H.x, L.x); splitw(v.y * 1024.f, H.y, L.y);
    splitw(v.z * 1024.f, H.z, L.z); splitw(v.w * 1024.f, H.w, L.w);
    *(ushort4*)&Kh[ad] = H; *(ushort4*)&Kl[ad] = L;
    float4 q = *(const float4*)(qb + (size_t)row * 128 + c);
    splitw(q.x * 1024.f, H.x, L.x); splitw(q.y * 1024.f, H.y, L.y);
    splitw(q.z * 1024.f, H.z, L.z); splitw(q.w * 1024.f, H.w, L.w);
    *(ushort4*)&Qh[ad] = H; *(ushort4*)&Ql[ad] = L;
  }
  if (tid < 64) {
    float x = g_arr[(size_t)bh * 2048 + t0 + tid];
#pragma unroll
    for (int off = 1; off < 64; off <<= 1) { float y = __shfl_up(x, off); if (tid >= off) x += y; }
    lc[tid] = x;
  }
  __syncthreads();
  const float ds20 = 1.f / 1048576.f;
  for (int nt = 0; nt < 4; ++nt) {
    f32x4 acc = (f32x4){0.f, 0.f, 0.f, 0.f};
    int nrow = nt * 16 + lr;
    int arow = w * 16 + lr;
#pragma unroll
    for (int ks = 0; ks < 4; ++ks) {
      int c = ks * 32 + g16 * 8;
      v8h ah = *(const v8h*)&Qh[arow * 128 + (c ^ ((arow & 7) << 3))];
      v8h al = *(const v8h*)&Ql[arow * 128 + (c ^ ((arow & 7) << 3))];
      v8h bhh = *(const v8h*)&Kh[nrow * 128 + (c ^ ((nrow & 7) << 3))];
      v8h bll = *(const v8h*)&Kl[nrow * 128 + (c ^ ((nrow & 7) << 3))];
      MFMA3(acc, ah, al, bhh, bll);
    }
    int s_ = nt * 16 + lr;
#pragma unroll
    for (int r = 0; r < 4; ++r) {
      int t = w * 16 + g16 * 4 + r;
      float hv = (s_ <= t) ? acc[r] * ds20 * expf(lc[t] - lc[s_]) : 0.f;
      unsigned short hh, ll; splitw(hv * 16384.f, hh, ll);
      size_t go = (size_t)cid * 4096 + t * 64 + (s_ ^ ((t & 7) << 3));
      *(unsigned short*)&Hg_h[go] = hh;
      *(unsigned short*)&Hg_l[go] = ll;
    }
  }
}

// ------------- Phase 2: sequential chunk scan, MFMA everywhere -------------
__global__ __launch_bounds__(256) void p2_k(
    const float* __restrict__ qn, const float* __restrict__ kn, const float* __restrict__ vn,
    const float* __restrict__ projGate,
    const _Float16* __restrict__ Tg_h, const _Float16* __restrict__ Tg_l,
    const _Float16* __restrict__ Hg_h, const _Float16* __restrict__ Hg_l,
    const _Float16* __restrict__ KTg_h, const _Float16* __restrict__ KTg_l,
    const float* __restrict__ coefG, float* __restrict__ out)
{
  __shared__ _Float16 St_h[8192], St_l[8192];
  __shared__ _Float16 KQ0[8192], KQ1[8192];
  __shared__ _Float16 KTs_h[8192], KTs_l[8192];
  __shared__ _Float16 Ts_h[4096], Ts_l[4096];
  __shared__ _Float16 Hs_h[4096], Hs_l[4096];
  __shared__ float cf[192];

  const int blk = blockIdx.x;
  const int vb = blk >> 5, bh = blk & 31;
  const int b = bh >> 4, h = bh & 15, v0 = vb * 64;
  const int tid = threadIdx.x, w = tid >> 6, lane = tid & 63, lr = lane & 15, g16 = lane >> 4;

  _Float16* BT_h = &KQ0[0];
  _Float16* BT_l = &KQ0[4096];
  _Float16* UT_h = &KQ1[0];
  _Float16* UT_l = &KQ1[4096];

#pragma unroll
  for (int l = 0; l < 16; ++l) { ((unsigned int*)St_h)[tid + l * 256] = 0u; }
#pragma unroll
  for (int l = 0; l < 16; ++l) { ((unsigned int*)St_l)[tid + l * 256] = 0u; }

  const float* qbase = qn + ((size_t)bh * 2048) * 128;
  const float* kbase = kn + ((size_t)bh * 2048) * 128;
  const float* gp = projGate + ((size_t)b * 2048) * GW + h * 256 + v0;
  const float i2_16 = 1.f / 65536.f;
  const float i2_20 = 1.f / 1048576.f;
  const float uscale = 1.f / 256.f;
  const float sscale = 64.f / 65536.f;

  for (int ch = 0; ch < 32; ++ch) {
    const int cid = bh * 32 + ch, t0 = ch * 64;
    {
      const _Float16* th = Tg_h + (size_t)cid * 4096;
      const _Float16* tl = Tg_l + (size_t)cid * 4096;
      const _Float16* hh = Hg_h + (size_t)cid * 4096;
      const _Float16* hl = Hg_l + (size_t)cid * 4096;
      const _Float16* kth = KTg_h + (size_t)cid * 8192;
      const _Float16* ktl = KTg_l + (size_t)cid * 8192;
#pragma unroll
      for (int l = 0; l < 2; ++l) {
        int i = tid + l * 256;
        gload_lds16(th + i * 8, &Ts_h[i * 8]);
        gload_lds16(tl + i * 8, &Ts_l[i * 8]);
        gload_lds16(hh + i * 8, &Hs_h[i * 8]);
        gload_lds16(hl + i * 8, &Hs_l[i * 8]);
      }
#pragma unroll
      for (int l = 0; l < 4; ++l) {
        int i = tid + l * 256;
        gload_lds16(kth + i * 8, &KTs_h[i * 8]);
        gload_lds16(ktl + i * 8, &KTs_l[i * 8]);
      }
      if (tid < 48) gload_lds16(coefG + (size_t)cid * 192 + tid * 4, &cf[tid * 4]);
#pragma unroll
      for (int l = 0; l < 8; ++l) {
        int s = tid + l * 256;
        int row = s >> 5, c = (s & 31) * 4;
        float4 v = *(const float4*)(qbase + (size_t)(t0 + row) * 128 + c);
        ushort4 H, L;
        splitw(v.x * 1024.f, H.x, L.x); splitw(v.y * 1024.f, H.y, L.y);
        splitw(v.z * 1024.f, H.z, L.z); splitw(v.w * 1024.f, H.w, L.w);
        int ad = row * 128 + (c ^ ((row & 7) << 3));
        *(ushort4*)&KQ0[ad] = H; *(ushort4*)&KQ1[ad] = L;
      }
    }
    __syncthreads();
    const float cc = cf[63];
    f32x4 Oacc[4];
    {
      const int arow = w * 16 + lr, swa = (arow & 7) << 3;
      for (int nt = 0; nt < 4; ++nt) {
        f32x4 acc = (f32x4){0.f, 0.f, 0.f, 0.f};
        const int n = nt * 16 + lr, swn = (n & 7) << 3;
#pragma unroll
        for (int ks = 0; ks < 4; ++ks) {
          int c = ks * 32 + g16 * 8;
          v8h ah = *(const v8h*)&KQ0[arow * 128 + (c ^ swa)];
          v8h al = *(const v8h*)&KQ1[arow * 128 + (c ^ swa)];
          v8h bhh = *(const v8h*)&St_h[n * 128 + (c ^ swn)];
          v8h bll = *(const v8h*)&St_l[n * 128 + (c ^ swn)];
          MFMA3(acc, ah, al, bhh, bll);
        }
        Oacc[nt] = acc;
      }
      float4 cav = *(float4*)&cf[w * 16 + g16 * 4];
#pragma unroll
      for (int nt = 0; nt < 4; ++nt) {
        Oacc[nt][0] *= cav.x * 16.f; Oacc[nt][1] *= cav.y * 16.f;
        Oacc[nt][2] *= cav.z * 16.f; Oacc[nt][3] *= cav.w * 16.f;
      }
    }
    __syncthreads();
#pragma unroll
    for (int l = 0; l < 8; ++l) {
      int s = tid + l * 256;
      int row = s >> 5, c = (s & 31) * 4;
      float4 v = *(const float4*)(kbase + (size_t)(t0 + row) * 128 + c);
      ushort4 H, L;
      splitw(v.x * 1024.f, H.x, L.x); splitw(v.y * 1024.f, H.y, L.y);
      splitw(v.z * 1024.f, H.z, L.z); splitw(v.w * 1024.f, H.w, L.w);
      int ad = row * 128 + (c ^ ((row & 7) << 3));
      *(ushort4*)&KQ0[ad] = H; *(ushort4*)&KQ1[ad] = L;
    }
    __syncthreads();
    ushort4 pBh[4], pBl[4];
    {
      const int arow = w * 16 + lr, swa = (arow & 7) << 3;
      float4 cb1v = *(float4*)&cf[64 + w * 16 + g16 * 4];
      float4 cb2v = *(float4*)&cf[128 + w * 16 + g16 * 4];
      for (int nt = 0; nt < 4; ++nt) {
        f32x4 acc = (f32x4){0.f, 0.f, 0.f, 0.f};
        const int n = nt * 16 + lr, swn = (n & 7) << 3;
#pragma unroll
        for (int ks = 0; ks < 4; ++ks) {
          int c = ks * 32 + g16 * 8;
          v8h ah = *(const v8h*)&KQ0[arow * 128 + (c ^ swa)];
          v8h al = *(const v8h*)&KQ1[arow * 128 + (c ^ swa)];
          v8h bhh = *(const v8h*)&St_h[n * 128 + (c ^ swn)];
          v8h bll = *(const v8h*)&St_l[n * 128 + (c ^ swn)];
          MFMA3(acc, ah, al, bhh, bll);
        }
        float cb1a[4] = {cb1v.x, cb1v.y, cb1v.z, cb1v.w};
        float cb2a[4] = {cb2v.x, cb2v.y, cb2v.z, cb2v.w};
        unsigned short* ph = (unsigned short*)&pBh[nt];
        unsigned short* pl = (unsigned short*)&pBl[nt];
#pragma unroll
        for (int r = 0; r < 4; ++r) {
          int t = w * 16 + g16 * 4 + r;
          float kv = acc[r] * i2_16;
          float Vv = vn[((size_t)bh * 2048 + t0 + t) * 256 + v0 + n];
          float Bv = cb1a[r] * Vv - cb2a[r] * kv;
          splitw(Bv * 64.f, ph[r], pl[r]);
        }
      }
    }
    __syncthreads();
    {
      const int tb = w * 16 + g16 * 4;
      for (int nt = 0; nt < 4; ++nt) {
        const int n = nt * 16 + lr, swn = (n & 7) << 3;
        int ad = n * 64 + (tb ^ swn);
        *(ushort4*)&BT_h[ad] = pBh[nt];
        *(ushort4*)&BT_l[ad] = pBl[nt];
      }
    }
    __syncthreads();
    {
      const int arow = w * 16 + lr, swa = (arow & 7) << 3;
      const int tb = w * 16 + g16 * 4;
      for (int nt = 0; nt < 4; ++nt) {
        f32x4 acc = (f32x4){0.f, 0.f, 0.f, 0.f};
        const int n = nt * 16 + lr, swn = (n & 7) << 3;
#pragma unroll
        for (int ks = 0; ks < 2; ++ks) {
          int c = ks * 32 + g16 * 8;
          v8h ah = *(const v8h*)&Ts_h[arow * 64 + (c ^ swa)];
          v8h al = *(const v8h*)&Ts_l[arow * 64 + (c ^ swa)];
          v8h bhh = *(const v8h*)&BT_h[n * 64 + (c ^ swn)];
          v8h bll = *(const v8h*)&BT_l[n * 64 + (c ^ swn)];
          MFMA3(acc, ah, al, bhh, bll);
        }
        ushort4 H, L;
        unsigned short* ph = (unsigned short*)&H;
        unsigned short* pl = (unsigned short*)&L;
#pragma unroll
        for (int r = 0; r < 4; ++r) splitw(acc[r] * uscale, ph[r], pl[r]);
        int ad = n * 64 + (tb ^ swn);
        *(ushort4*)&UT_h[ad] = H;
        *(ushort4*)&UT_l[ad] = L;
      }
    }
    __syncthreads();
    {
      const int arow = w * 16 + lr, swa = (arow & 7) << 3;
      for (int nt = 0; nt < 4; ++nt) {
        const int n = nt * 16 + lr, swn = (n & 7) << 3;
#pragma unroll
        for (int ks = 0; ks < 2; ++ks) {
          int c = ks * 32 + g16 * 8;
          v8h ah = *(const v8h*)&Hs_h[arow * 64 + (c ^ swa)];
          v8h al = *(const v8h*)&Hs_l[arow * 64 + (c ^ swa)];
          v8h bhh = *(const v8h*)&UT_h[n * 64 + (c ^ swn)];
          v8h bll = *(const v8h*)&UT_l[n * 64 + (c ^ swn)];
          MFMA3(Oacc[nt], ah, al, bhh, bll);
        }
      }
      for (int nt = 0; nt < 4; ++nt) {
        const int n = nt * 16 + lr;
#pragma unroll
        for (int r = 0; r < 4; ++r) {
          int t = t0 + w * 16 + g16 * 4 + r;
          float Ov = Oacc[nt][r] * i2_20;
          float gv = gp[(size_t)t * GW + n];
          out[((size_t)b * 2048 + t) * 4096 + h * 256 + v0 + n] = Ov * (gv / (1.f + expf(-gv)));
        }
      }
    }
    {
      const float cc1024 = cc * 1024.f;
#pragma unroll
      for (int m2 = w * 2; m2 < w * 2 + 2; ++m2) {
        const int arow = m2 * 16 + lr, swa = (arow & 7) << 3;
        const int fb = m2 * 16 + g16 * 4;
        for (int nt = 0; nt < 4; ++nt) {
          const int n = nt * 16 + lr, swn = (n & 7) << 3;
          int sad = n * 128 + (fb ^ swn);
          ushort4 sh4 = *(ushort4*)&St_h[sad];
          ushort4 sl4 = *(ushort4*)&St_l[sad];
          f32x4 acc;
          acc[0] = cc1024 * (h2f(sh4.x) + h2f(sl4.x));
          acc[1] = cc1024 * (h2f(sh4.y) + h2f(sl4.y));
          acc[2] = cc1024 * (h2f(sh4.z) + h2f(sl4.z));
          acc[3] = cc1024 * (h2f(sh4.w) + h2f(sl4.w));
#pragma unroll
          for (int ks = 0; ks < 2; ++ks) {
            int c = ks * 32 + g16 * 8;
            v8h ah = *(const v8h*)&KTs_h[arow * 64 + (c ^ swa)];
            v8h al = *(const v8h*)&KTs_l[arow * 64 + (c ^ swa)];
            v8h bhh = *(const v8h*)&UT_h[n * 64 + (c ^ swn)];
            v8h bll = *(const v8h*)&UT_l[n * 64 + (c ^ swn)];
            MFMA3(acc, ah, al, bhh, bll);
          }
          ushort4 H, L;
          unsigned short* ph = (unsigned short*)&H;
          unsigned short* pl = (unsigned short*)&L;
#pragma unroll
          for (int r = 0; r < 4; ++r) splitw(acc[r] * sscale, ph[r], pl[r]);
          *(ushort4*)&St_h[sad] = H;
          *(ushort4*)&St_l[sad] = L;
        }
      }
    }
    __syncthreads();
  }
}

extern "C" void kernel_launch(void* const* d_in, const int* in_sizes, int n_in,
                              void* d_out, int out_size, void* d_ws, size_t ws_size,
                              hipStream_t stream) {
  const float* hidden  = (const float*)d_in[0];
  const float* W       = (const float*)d_in[1];
  const float* Wc      = (const float*)d_in[2];
  const float* A_log   = (const float*)d_in[3];
  const float* dt_bias = (const float*)d_in[4];
  float* out = (float*)d_out;

  char* ws = (char*)d_ws;
  _Float16* Ap = (_Float16*)ws;
  _Float16* Bp = (_Float16*)(ws + (size_t)33554432);
  float* qn    = (float*)ws;
  float* kn    = qn + (size_t)8388608;
  float* vn    = kn + (size_t)8388608;
  float* g_arr = vn + (size_t)16777216;
  float* beta  = g_arr + (size_t)65536;
  float* projQKV = (float*)(ws + (size_t)135266304);
  char*  tb0 = ws + (size_t)135266304;
  _Float16* Tg_h  = (_Float16*)tb0;
  _Float16* Tg_l  = (_Float16*)(tb0 + (size_t)8388608);
  _Float16* Hg_h  = (_Float16*)(tb0 + (size_t)16777216);
  _Float16* Hg_l  = (_Float16*)(tb0 + (size_t)25165824);
  _Float16* KTg_h = (_Float16*)(tb0 + (size_t)33554432);
  _Float16* KTg_l = (_Float16*)(tb0 + (size_t)50331648);
  float*    coefG = (float*)   (tb0 + (size_t)67108864);
  float* projGate = (float*)(ws + (size_t)269484032);

  pack_A_k<<<32 * KSTEPS, 256, 0, stream>>>(hidden, Ap);
  pack_B_k<<<NTILE_N * KSTEPS, 256, 0, stream>>>(W, Bp);
  gemm_mfma_k<<<32 * NTILE_N, 256, 0, stream>>>(Ap, Bp, projQKV, projGate);

  conv_qk_k<<<dim3(32, 32, 2), 64, 0, stream>>>(projQKV, Wc, qn, kn);
  conv_v_k<<<dim3(32, 4, 2), 256, 0, stream>>>(projQKV, Wc, vn);
  beta_g_k<<<(2 * NH * L_SEQ + 255) / 256, 256, 0, stream>>>(projGate, A_log, dt_bias, beta, g_arr);

  p1a_k<<<1024, 256, 0, stream>>>(kn, g_arr, beta, Tg_h, Tg_l, KTg_h, KTg_l, coefG);
  p1b_k<<<1024, 256, 0, stream>>>(kn, qn, g_arr, Hg_h, Hg_l);
  p2_k<<<128, 256, 0, stream>>>(qn, kn, vn, projGate, Tg_h, Tg_l, Hg_h, Hg_l, KTg_h, KTg_l, coefG, out);
}

// Round 9
// 1091.387 us; speedup vs baseline: 3.5929x; 1.0770x over previous
//
#include <hip/hip_runtime.h>
#include <hip/hip_bf16.h>
#include <hip/hip_fp16.h>
#include <math.h>

#define L_SEQ 2048
#define DM    2048
#define NH    16
#define DH    128
#define HVD   256
#define NPROJ 12320
#define QKVW  8192
#define GW    4128

#define NTILE_N 97
#define KSTEPS  64

typedef _Float16 v8h __attribute__((ext_vector_type(8)));
typedef float f32x4 __attribute__((ext_vector_type(4)));
typedef float f32x16 __attribute__((ext_vector_type(16)));

__device__ __forceinline__ void gload_lds16(const void* g, void* l) {
  __builtin_amdgcn_global_load_lds((const __attribute__((address_space(1))) void*)g,
                                   (__attribute__((address_space(3))) void*)l, 16, 0, 0);
}

__device__ __forceinline__ void splitw(float x, unsigned short& h, unsigned short& l) {
  _Float16 hh = (_Float16)x;
  _Float16 ll = (_Float16)(x - (float)hh);
  h = *(unsigned short*)&hh;
  l = *(unsigned short*)&ll;
}
__device__ __forceinline__ float h2f(unsigned short u) {
  return (float)(*(_Float16*)&u);
}

#define MFMA3(acc, ah, al, bh_, bl_)                                          \
  acc = __builtin_amdgcn_mfma_f32_16x16x32_f16(ah, bh_, acc, 0, 0, 0);        \
  acc = __builtin_amdgcn_mfma_f32_16x16x32_f16(ah, bl_, acc, 0, 0, 0);        \
  acc = __builtin_amdgcn_mfma_f32_16x16x32_f16(al, bh_, acc, 0, 0, 0);

#define MFMA3W(acc, ah, al, bh_, bl_)                                         \
  acc = __builtin_amdgcn_mfma_f32_32x32x16_f16(ah, bh_, acc, 0, 0, 0);        \
  acc = __builtin_amdgcn_mfma_f32_32x32x16_f16(ah, bl_, acc, 0, 0, 0);        \
  acc = __builtin_amdgcn_mfma_f32_32x32x16_f16(al, bh_, acc, 0, 0, 0);

// ---------------- pack A: hidden(4096x2048) f32 -> fp16 hi/lo, x16 ----------------
__global__ __launch_bounds__(256) void pack_A_k(const float* __restrict__ H, _Float16* __restrict__ Ap) {
  const int mtile = blockIdx.x >> 6, kstep = blockIdx.x & 63;
  const size_t base = (size_t)blockIdx.x * 2 * 4096;
#pragma unroll
  for (int it = 0; it < 2; ++it) {
    int s = threadIdx.x + it * 256;
    int g = s >> 7, r = s & 127;
    const float* src = H + ((size_t)(mtile * 128 + r)) * 2048 + kstep * 32 + g * 8;
    float4 x0 = *(const float4*)src;
    float4 x1 = *(const float4*)(src + 4);
    float xs[8] = {x0.x, x0.y, x0.z, x0.w, x1.x, x1.y, x1.z, x1.w};
    v8h hi, lo;
#pragma unroll
    for (int j = 0; j < 8; ++j) {
      float v = xs[j] * 16.f;
      _Float16 h = (_Float16)v;
      hi[j] = h;
      lo[j] = (_Float16)(v - (float)h);
    }
    *(v8h*)(Ap + base + g * 1024 + r * 8) = hi;
    *(v8h*)(Ap + base + 4096 + g * 1024 + r * 8) = lo;
  }
}

// ---------------- pack B: W(2048x12320) f32 -> fp16 hi/lo, x1024 ----------------
__global__ __launch_bounds__(256) void pack_B_k(const float* __restrict__ W, _Float16* __restrict__ Bp) {
  const int ntile = blockIdx.x >> 6, kstep = blockIdx.x & 63;
  const size_t base = (size_t)blockIdx.x * 2 * 4096;
#pragma unroll
  for (int it = 0; it < 2; ++it) {
    int s = threadIdx.x + it * 256;
    int g = s >> 7, col = s & 127;
    int n = ntile * 128 + col;
    v8h hi, lo;
#pragma unroll
    for (int j = 0; j < 8; ++j) {
      int k = kstep * 32 + g * 8 + j;
      float v = (n < NPROJ) ? W[(size_t)k * NPROJ + n] * 1024.f : 0.f;
      _Float16 h = (_Float16)v;
      hi[j] = h;
      lo[j] = (_Float16)(v - (float)h);
    }
    *(v8h*)(Bp + base + g * 1024 + col * 8) = hi;
    *(v8h*)(Bp + base + 4096 + g * 1024 + col * 8) = lo;
  }
}

// ---------------- split-fp16 MFMA GEMM: 32x32x16, counted-vmcnt 2-buffer ----------------
__global__ __launch_bounds__(256) void gemm_mfma_k(const _Float16* __restrict__ Ap,
                                                   const _Float16* __restrict__ Bp,
                                                   float* __restrict__ Cq,
                                                   float* __restrict__ Cg) {
  __shared__ _Float16 lds[2][16384];   // per buf: Ahi Alo Bhi Blo
  const int tid = threadIdx.x;
  const int mtile = blockIdx.x & 31;
  const int ntile = blockIdx.x >> 5;
  const int wid = tid >> 6, lane = tid & 63;
  const int wm = wid >> 1, wn = wid & 1;
  const int lrow = lane & 31, kg = lane >> 5;   // 32-row index, k-half group

  f32x16 acc[2][2];
#pragma unroll
  for (int i = 0; i < 2; ++i)
#pragma unroll
    for (int j = 0; j < 2; ++j)
#pragma unroll
      for (int r = 0; r < 16; ++r) acc[i][j][r] = 0.f;

  const int arow0 = (wm * 64 + lrow) * 8;       // halfs offset within group
  const int bcol0 = (wn * 64 + lrow) * 8;

  const _Float16* Asrc = Ap + ((size_t)(mtile * KSTEPS) * 2) * 4096 + tid * 8;
  const _Float16* Bsrc = Bp + ((size_t)(ntile * KSTEPS) * 2) * 4096 + tid * 8;

#define STAGE(KS, BUF)                                                         \
  {                                                                            \
    const _Float16* An_ = Asrc + (size_t)(KS) * 8192;                          \
    const _Float16* Bn_ = Bsrc + (size_t)(KS) * 8192;                          \
    _Pragma("unroll")                                                          \
    for (int r = 0; r < 4; ++r) {                                              \
      gload_lds16(An_ + r * 2048, &lds[BUF][r * 2048 + tid * 8]);              \
      gload_lds16(Bn_ + r * 2048, &lds[BUF][8192 + r * 2048 + tid * 8]);       \
    }                                                                          \
  }

  STAGE(0, 0);
  STAGE(1, 1);

  for (int kstep = 0; kstep < KSTEPS; ++kstep) {
    const int p = kstep & 1;
    if (kstep + 1 < KSTEPS) {
      asm volatile("s_waitcnt vmcnt(8)" ::: "memory");
    } else {
      asm volatile("s_waitcnt vmcnt(0)" ::: "memory");
    }
    __builtin_amdgcn_sched_barrier(0);
    __builtin_amdgcn_s_barrier();
    __builtin_amdgcn_sched_barrier(0);

#pragma unroll
    for (int ksub = 0; ksub < 2; ++ksub) {
      const int base = (ksub * 2 + kg) * 1024;
      v8h ah0 = *(const v8h*)&lds[p][base + arow0];
      v8h ah1 = *(const v8h*)&lds[p][base + arow0 + 256];        // +32 rows
      v8h al0 = *(const v8h*)&lds[p][4096 + base + arow0];
      v8h al1 = *(const v8h*)&lds[p][4096 + base + arow0 + 256];
      v8h bh0 = *(const v8h*)&lds[p][8192 + base + bcol0];
      v8h bh1 = *(const v8h*)&lds[p][8192 + base + bcol0 + 256];
      v8h bl0 = *(const v8h*)&lds[p][12288 + base + bcol0];
      v8h bl1 = *(const v8h*)&lds[p][12288 + base + bcol0 + 256];
      MFMA3W(acc[0][0], ah0, al0, bh0, bl0);
      MFMA3W(acc[0][1], ah0, al0, bh1, bl1);
      MFMA3W(acc[1][0], ah1, al1, bh0, bl0);
      MFMA3W(acc[1][1], ah1, al1, bh1, bl1);
    }
    __builtin_amdgcn_sched_barrier(0);
    __builtin_amdgcn_s_barrier();
    __builtin_amdgcn_sched_barrier(0);
    if (kstep + 2 < KSTEPS) STAGE(kstep + 2, p);
  }
#undef STAGE

  const float sc = 1.f / 16384.f;
#pragma unroll
  for (int tm = 0; tm < 2; ++tm)
#pragma unroll
    for (int tn = 0; tn < 2; ++tn) {
      int col = ntile * 128 + wn * 64 + tn * 32 + lrow;
#pragma unroll
      for (int r = 0; r < 16; ++r) {
        int row = mtile * 128 + wm * 64 + tm * 32 + (r & 3) + 8 * (r >> 2) + 4 * kg;
        float v = acc[tm][tn][r] * sc;
        if (col < QKVW) {
          Cq[(size_t)row * QKVW + col] = v;
        } else if (col < NPROJ) {
          Cg[(size_t)row * GW + (col - QKVW)] = v;
        }
      }
    }
}

// ------------- conv+silu+l2norm for q/k: one wave per (head, t-chunk) -------------
__global__ __launch_bounds__(64) void conv_qk_k(
    const float* __restrict__ projQKV, const float* __restrict__ Wc,
    float* __restrict__ qn, float* __restrict__ kn)
{
  const int b = blockIdx.z, hg = blockIdx.y, tc = blockIdx.x;
  const int lane = threadIdx.x;
  const int ch = hg * 128 + lane * 2;
  float4 Wa = *(const float4*)(Wc + (size_t)ch * 4);
  float4 Wb = *(const float4*)(Wc + (size_t)ch * 4 + 4);
  const int t0 = tc * 64;
  const float* P = projQKV + (size_t)b * L_SEQ * QKVW + ch;
  float2 w0 = make_float2(0.f, 0.f), w1 = w0, w2 = w0;
  if (t0 >= 3) w0 = *(const float2*)(P + (size_t)(t0 - 3) * QKVW);
  if (t0 >= 2) w1 = *(const float2*)(P + (size_t)(t0 - 2) * QKVW);
  if (t0 >= 1) w2 = *(const float2*)(P + (size_t)(t0 - 1) * QKVW);
  const bool isq = hg < 16;
  const int h = isq ? hg : hg - 16;
  float* dst = (isq ? qn : kn) + (((size_t)b * NH + h) * L_SEQ) * DH + lane * 2;
  const float sc = isq ? 0.08838834764831845f : 1.f;
  for (int t = t0; t < t0 + 64; ++t) {
    float2 x = *(const float2*)(P + (size_t)t * QKVW);
    float y0 = w0.x * Wa.x + w1.x * Wa.y + w2.x * Wa.z + x.x * Wa.w;
    float y1 = w0.y * Wb.x + w1.y * Wb.y + w2.y * Wb.z + x.y * Wb.w;
    w0 = w1; w1 = w2; w2 = x;
    y0 = y0 / (1.f + expf(-y0));
    y1 = y1 / (1.f + expf(-y1));
    float ss = y0 * y0 + y1 * y1;
#pragma unroll
    for (int off = 1; off < 64; off <<= 1) ss += __shfl_xor(ss, off);
    float nrm = sc / sqrtf(ss + 1e-6f);
    *(float2*)(dst + (size_t)t * DH) = make_float2(y0 * nrm, y1 * nrm);
  }
}

// ------------- conv+silu for v: elementwise, float4 per thread -------------
__global__ __launch_bounds__(256) void conv_v_k(
    const float* __restrict__ projQKV, const float* __restrict__ Wc,
    float* __restrict__ vn)
{
  const int b = blockIdx.z, cg = blockIdx.y, tc = blockIdx.x;
  const int vc = (cg * 256 + threadIdx.x) * 4;
  const int ch = 4096 + vc;
  float4 Wv0 = *(const float4*)(Wc + (size_t)ch * 4);
  float4 Wv1 = *(const float4*)(Wc + (size_t)ch * 4 + 4);
  float4 Wv2 = *(const float4*)(Wc + (size_t)ch * 4 + 8);
  float4 Wv3 = *(const float4*)(Wc + (size_t)ch * 4 + 12);
  const int t0 = tc * 64;
  const float* P = projQKV + (size_t)b * L_SEQ * QKVW + ch;
  float4 w0 = make_float4(0.f, 0.f, 0.f, 0.f), w1 = w0, w2 = w0;
  if (t0 >= 3) w0 = *(const float4*)(P + (size_t)(t0 - 3) * QKVW);
  if (t0 >= 2) w1 = *(const float4*)(P + (size_t)(t0 - 2) * QKVW);
  if (t0 >= 1) w2 = *(const float4*)(P + (size_t)(t0 - 1) * QKVW);
  const int h = vc >> 8, vcol = vc & 255;
  float* dst = vn + (((size_t)b * NH + h) * L_SEQ) * HVD + vcol;
  for (int t = t0; t < t0 + 64; ++t) {
    float4 x = *(const float4*)(P + (size_t)t * QKVW);
    float4 y;
    y.x = w0.x * Wv0.x + w1.x * Wv0.y + w2.x * Wv0.z + x.x * Wv0.w;
    y.y = w0.y * Wv1.x + w1.y * Wv1.y + w2.y * Wv1.z + x.y * Wv1.w;
    y.z = w0.z * Wv2.x + w1.z * Wv2.y + w2.z * Wv2.z + x.z * Wv2.w;
    y.w = w0.w * Wv3.x + w1.w * Wv3.y + w2.w * Wv3.z + x.w * Wv3.w;
    w0 = w1; w1 = w2; w2 = x;
    y.x = y.x / (1.f + expf(-y.x));
    y.y = y.y / (1.f + expf(-y.y));
    y.z = y.z / (1.f + expf(-y.z));
    y.w = y.w / (1.f + expf(-y.w));
    *(float4*)(dst + (size_t)t * HVD) = y;
  }
}

// ------------- beta = sigmoid(b), g = -exp(A_log)*softplus(A+dt_bias) -------------
__global__ __launch_bounds__(256) void beta_g_k(
    const float* __restrict__ projGate, const float* __restrict__ A_log,
    const float* __restrict__ dt_bias, float* __restrict__ beta, float* __restrict__ g_out)
{
  int idx = blockIdx.x * 256 + threadIdx.x;
  if (idx >= 2 * NH * L_SEQ) return;
  int t = idx & (L_SEQ - 1);
  int h = (idx >> 11) & (NH - 1);
  int b = idx >> 15;
  size_t row = (size_t)(b * L_SEQ + t) * GW;
  float bv = projGate[row + 4096 + h];
  float av = projGate[row + 4112 + h];
  float be = 1.f / (1.f + expf(-bv));
  float xx = av + dt_bias[h];
  float sp = (xx > 20.f) ? xx : log1pf(expf(xx));
  float g = -expf(A_log[h]) * sp;
  beta[idx] = be;
  g_out[idx] = g;
}

// ------------- Phase 1 (fused): T=(I+A)^-1, Hq, KT, coef -------------
// grid 1024 = bh*32 + chunk, block 256
__global__ __launch_bounds__(256) void p1_k(
    const float* __restrict__ kn, const float* __restrict__ qn,
    const float* __restrict__ g_arr, const float* __restrict__ beta_arr,
    _Float16* __restrict__ Tg_h, _Float16* __restrict__ Tg_l,
    _Float16* __restrict__ Hg_h, _Float16* __restrict__ Hg_l,
    _Float16* __restrict__ KTg_h, _Float16* __restrict__ KTg_l,
    float* __restrict__ coefG)
{
  __shared__ _Float16 Kh[8192], Kl[8192];
  __shared__ _Float16 QS[16384];          // Qh|Ql; overlaid by Am|Tm after Hq
  __shared__ float lc[64], be[64], kw[64];
  _Float16* Qh = QS;
  _Float16* Ql = QS + 8192;
  float* Am = (float*)QS;
  float* Tm = Am + 4096;
  const int cid = blockIdx.x, bh = cid >> 5, ch = cid & 31, t0 = ch * 64;
  const int tid = threadIdx.x, w = tid >> 6, lane = tid & 63, lr = lane & 15, g16 = lane >> 4;

  const float* kb = kn + ((size_t)bh * 2048 + t0) * 128;
  const float* qb = qn + ((size_t)bh * 2048 + t0) * 128;
#pragma unroll
  for (int l = 0; l < 8; ++l) {
    int s = tid + l * 256;
    int row = s >> 5, c = (s & 31) * 4;
    int ad = row * 128 + (c ^ ((row & 7) << 3));
    float4 v = *(const float4*)(kb + (size_t)row * 128 + c);
    ushort4 H, L;
    splitw(v.x * 1024.f, H.x, L.x); splitw(v.y * 1024.f, H.y, L.y);
    splitw(v.z * 1024.f, H.z, L.z); splitw(v.w * 1024.f, H.w, L.w);
    *(ushort4*)&Kh[ad] = H; *(ushort4*)&Kl[ad] = L;
    float4 q = *(const float4*)(qb + (size_t)row * 128 + c);
    splitw(q.x * 1024.f, H.x, L.x); splitw(q.y * 1024.f, H.y, L.y);
    splitw(q.z * 1024.f, H.z, L.z); splitw(q.w * 1024.f, H.w, L.w);
    *(ushort4*)&Qh[ad] = H; *(ushort4*)&Ql[ad] = L;
  }
  if (tid < 64) {
    float x = g_arr[(size_t)bh * 2048 + t0 + tid];
#pragma unroll
    for (int off = 1; off < 64; off <<= 1) { float y = __shfl_up(x, off); if (tid >= off) x += y; }
    lc[tid] = x;
    float x63 = __shfl(x, 63);
    float b_ = beta_arr[(size_t)bh * 2048 + t0 + tid];
    be[tid] = b_;
    kw[tid] = expf(x63 - x);
    float ca = expf(x);
    coefG[(size_t)cid * 192 + tid] = ca;
    coefG[(size_t)cid * 192 + 64 + tid] = b_;
    coefG[(size_t)cid * 192 + 128 + tid] = b_ * ca;
  }
  __syncthreads();
  const float ds20 = 1.f / 1048576.f;
  const int arow = w * 16 + lr, swa = (arow & 7) << 3;
  // G = K K^T -> gacc (kept in regs until Q is dead)
  f32x4 gacc[4];
  for (int nt = 0; nt < 4; ++nt) {
    f32x4 acc = (f32x4){0.f, 0.f, 0.f, 0.f};
    int nrow = nt * 16 + lr, swn = (nrow & 7) << 3;
#pragma unroll
    for (int ks = 0; ks < 4; ++ks) {
      int c = ks * 32 + g16 * 8;
      v8h ah = *(const v8h*)&Kh[arow * 128 + (c ^ swa)];
      v8h al = *(const v8h*)&Kl[arow * 128 + (c ^ swa)];
      v8h bhh = *(const v8h*)&Kh[nrow * 128 + (c ^ swn)];
      v8h bll = *(const v8h*)&Kl[nrow * 128 + (c ^ swn)];
      MFMA3(acc, ah, al, bhh, bll);
    }
    gacc[nt] = acc;
  }
  // Hq = Q K^T, write to global (sigma 16384)
  for (int nt = 0; nt < 4; ++nt) {
    f32x4 acc = (f32x4){0.f, 0.f, 0.f, 0.f};
    int nrow = nt * 16 + lr, swn = (nrow & 7) << 3;
#pragma unroll
    for (int ks = 0; ks < 4; ++ks) {
      int c = ks * 32 + g16 * 8;
      v8h ah = *(const v8h*)&Qh[arow * 128 + (c ^ swa)];
      v8h al = *(const v8h*)&Ql[arow * 128 + (c ^ swa)];
      v8h bhh = *(const v8h*)&Kh[nrow * 128 + (c ^ swn)];
      v8h bll = *(const v8h*)&Kl[nrow * 128 + (c ^ swn)];
      MFMA3(acc, ah, al, bhh, bll);
    }
    int s_ = nt * 16 + lr;
#pragma unroll
    for (int r = 0; r < 4; ++r) {
      int t = w * 16 + g16 * 4 + r;
      float hv = (s_ <= t) ? acc[r] * ds20 * expf(lc[t] - lc[s_]) : 0.f;
      unsigned short hh, ll; splitw(hv * 16384.f, hh, ll);
      size_t go = (size_t)cid * 4096 + t * 64 + (s_ ^ ((t & 7) << 3));
      *(unsigned short*)&Hg_h[go] = hh;
      *(unsigned short*)&Hg_l[go] = ll;
    }
  }
  __syncthreads();   // Q LDS dead -> overlay Am/Tm
  for (int nt = 0; nt < 4; ++nt) {
    int s_ = nt * 16 + lr;
#pragma unroll
    for (int r = 0; r < 4; ++r) {
      int t = w * 16 + g16 * 4 + r;
      float av = (s_ < t) ? gacc[nt][r] * ds20 * be[t] * expf(lc[t] - lc[s_]) : 0.f;
      Am[t * 64 + s_] = av;
    }
  }
#pragma unroll
  for (int l = 0; l < 16; ++l) { int s2 = tid + l * 256; Tm[s2] = ((s2 >> 6) == (s2 & 63)) ? 1.f : 0.f; }
  // KT global (kw-folded, sigma 1024, pre-swizzled)
  for (int s = tid; s < 8192; s += 256) {
    int feat = s >> 6, t = s & 63;
    int ki = t * 128 + (feat ^ ((t & 7) << 3));
    float kvv = ((float)Kh[ki] + (float)Kl[ki]) * kw[t];
    unsigned short hh, ll; splitw(kvv, hh, ll);
    size_t go = (size_t)cid * 8192 + feat * 64 + (t ^ ((feat & 7) << 3));
    *(unsigned short*)&KTg_h[go] = hh;
    *(unsigned short*)&KTg_l[go] = ll;
  }
  __syncthreads();
  if (w == 0) {
    int j = lane;
    for (int t = 1; t < 64; ++t) {
      float sum = 0.f;
      for (int s = 0; s < t; ++s) sum = fmaf(Am[t * 64 + s], Tm[s * 64 + j], sum);
      Tm[t * 64 + j] = ((j == t) ? 1.f : 0.f) - sum;
    }
  }
  __syncthreads();
#pragma unroll
  for (int l = 0; l < 16; ++l) {
    int s2 = tid + l * 256;
    int t = s2 >> 6, sc_ = s2 & 63;
    unsigned short hh, ll; splitw(Tm[s2] * 256.f, hh, ll);
    size_t go = (size_t)cid * 4096 + t * 64 + (sc_ ^ ((t & 7) << 3));
    *(unsigned short*)&Tg_h[go] = hh;
    *(unsigned short*)&Tg_l[go] = ll;
  }
}

// ------------- Phase 2: sequential chunk scan, VW=32, 256 blocks (1/CU) -------------
__global__ __launch_bounds__(256) void p2_k(
    const float* __restrict__ qn, const float* __restrict__ kn, const float* __restrict__ vn,
    const float* __restrict__ projGate,
    const _Float16* __restrict__ Tg_h, const _Float16* __restrict__ Tg_l,
    const _Float16* __restrict__ Hg_h, const _Float16* __restrict__ Hg_l,
    const _Float16* __restrict__ KTg_h, const _Float16* __restrict__ KTg_l,
    const float* __restrict__ coefG, float* __restrict__ out)
{
  __shared__ _Float16 St_h[4096], St_l[4096];     // [32 v][128 feat]
  __shared__ _Float16 KQ0[8192], KQ1[8192];
  __shared__ _Float16 KTs_h[8192], KTs_l[8192];
  __shared__ _Float16 Ts_h[4096], Ts_l[4096];
  __shared__ _Float16 Hs_h[4096], Hs_l[4096];
  __shared__ float cf[192];

  const int blk = blockIdx.x;
  const int vb = blk >> 5, bh = blk & 31;          // vb 0..7
  const int b = bh >> 4, h = bh & 15, v0 = vb * 32;
  const int tid = threadIdx.x, w = tid >> 6, lane = tid & 63, lr = lane & 15, g16 = lane >> 4;

  _Float16* BT_h = &KQ0[0];
  _Float16* BT_l = &KQ0[4096];
  _Float16* UT_h = &KQ1[0];
  _Float16* UT_l = &KQ1[4096];

#pragma unroll
  for (int l = 0; l < 8; ++l) { ((unsigned int*)St_h)[tid + l * 256] = 0u; }
#pragma unroll
  for (int l = 0; l < 8; ++l) { ((unsigned int*)St_l)[tid + l * 256] = 0u; }

  const float* qbase = qn + ((size_t)bh * 2048) * 128;
  const float* kbase = kn + ((size_t)bh * 2048) * 128;
  const float* gp = projGate + ((size_t)b * 2048) * GW + h * 256 + v0;
  const float i2_16 = 1.f / 65536.f;
  const float i2_20 = 1.f / 1048576.f;
  const float uscale = 1.f / 256.f;
  const float sscale = 64.f / 65536.f;

  for (int ch = 0; ch < 32; ++ch) {
    const int cid = bh * 32 + ch, t0 = ch * 64;
    {
      const _Float16* th = Tg_h + (size_t)cid * 4096;
      const _Float16* tl = Tg_l + (size_t)cid * 4096;
      const _Float16* hh = Hg_h + (size_t)cid * 4096;
      const _Float16* hl = Hg_l + (size_t)cid * 4096;
      const _Float16* kth = KTg_h + (size_t)cid * 8192;
      const _Float16* ktl = KTg_l + (size_t)cid * 8192;
#pragma unroll
      for (int l = 0; l < 2; ++l) {
        int i = tid + l * 256;
        gload_lds16(th + i * 8, &Ts_h[i * 8]);
        gload_lds16(tl + i * 8, &Ts_l[i * 8]);
        gload_lds16(hh + i * 8, &Hs_h[i * 8]);
        gload_lds16(hl + i * 8, &Hs_l[i * 8]);
      }
#pragma unroll
      for (int l = 0; l < 4; ++l) {
        int i = tid + l * 256;
        gload_lds16(kth + i * 8, &KTs_h[i * 8]);
        gload_lds16(ktl + i * 8, &KTs_l[i * 8]);
      }
      if (tid < 48) gload_lds16(coefG + (size_t)cid * 192 + tid * 4, &cf[tid * 4]);
#pragma unroll
      for (int l = 0; l < 8; ++l) {
        int s = tid + l * 256;
        int row = s >> 5, c = (s & 31) * 4;
        float4 v = *(const float4*)(qbase + (size_t)(t0 + row) * 128 + c);
        ushort4 H, L;
        splitw(v.x * 1024.f, H.x, L.x); splitw(v.y * 1024.f, H.y, L.y);
        splitw(v.z * 1024.f, H.z, L.z); splitw(v.w * 1024.f, H.w, L.w);
        int ad = row * 128 + (c ^ ((row & 7) << 3));
        *(ushort4*)&KQ0[ad] = H; *(ushort4*)&KQ1[ad] = L;
      }
    }
    __syncthreads();
    const float cc = cf[63];
    f32x4 Oacc[2];
    {
      const int arow = w * 16 + lr, swa = (arow & 7) << 3;
      for (int nt = 0; nt < 2; ++nt) {
        f32x4 acc = (f32x4){0.f, 0.f, 0.f, 0.f};
        const int n = nt * 16 + lr, swn = (n & 7) << 3;
#pragma unroll
        for (int ks = 0; ks < 4; ++ks) {
          int c = ks * 32 + g16 * 8;
          v8h ah = *(const v8h*)&KQ0[arow * 128 + (c ^ swa)];
          v8h al = *(const v8h*)&KQ1[arow * 128 + (c ^ swa)];
          v8h bhh = *(const v8h*)&St_h[n * 128 + (c ^ swn)];
          v8h bll = *(const v8h*)&St_l[n * 128 + (c ^ swn)];
          MFMA3(acc, ah, al, bhh, bll);
        }
        Oacc[nt] = acc;
      }
      float4 cav = *(float4*)&cf[w * 16 + g16 * 4];
#pragma unroll
      for (int nt = 0; nt < 2; ++nt) {
        Oacc[nt][0] *= cav.x * 16.f; Oacc[nt][1] *= cav.y * 16.f;
        Oacc[nt][2] *= cav.z * 16.f; Oacc[nt][3] *= cav.w * 16.f;
      }
    }
    __syncthreads();
#pragma unroll
    for (int l = 0; l < 8; ++l) {
      int s = tid + l * 256;
      int row = s >> 5, c = (s & 31) * 4;
      float4 v = *(const float4*)(kbase + (size_t)(t0 + row) * 128 + c);
      ushort4 H, L;
      splitw(v.x * 1024.f, H.x, L.x); splitw(v.y * 1024.f, H.y, L.y);
      splitw(v.z * 1024.f, H.z, L.z); splitw(v.w * 1024.f, H.w, L.w);
      int ad = row * 128 + (c ^ ((row & 7) << 3));
      *(ushort4*)&KQ0[ad] = H; *(ushort4*)&KQ1[ad] = L;
    }
    __syncthreads();
    ushort4 pBh[2], pBl[2];
    {
      const int arow = w * 16 + lr, swa = (arow & 7) << 3;
      float4 cb1v = *(float4*)&cf[64 + w * 16 + g16 * 4];
      float4 cb2v = *(float4*)&cf[128 + w * 16 + g16 * 4];
      for (int nt = 0; nt < 2; ++nt) {
        f32x4 acc = (f32x4){0.f, 0.f, 0.f, 0.f};
        const int n = nt * 16 + lr, swn = (n & 7) << 3;
#pragma unroll
        for (int ks = 0; ks < 4; ++ks) {
          int c = ks * 32 + g16 * 8;
          v8h ah = *(const v8h*)&KQ0[arow * 128 + (c ^ swa)];
          v8h al = *(const v8h*)&KQ1[arow * 128 + (c ^ swa)];
          v8h bhh = *(const v8h*)&St_h[n * 128 + (c ^ swn)];
          v8h bll = *(const v8h*)&St_l[n * 128 + (c ^ swn)];
          MFMA3(acc, ah, al, bhh, bll);
        }
        float cb1a[4] = {cb1v.x, cb1v.y, cb1v.z, cb1v.w};
        float cb2a[4] = {cb2v.x, cb2v.y, cb2v.z, cb2v.w};
        unsigned short* ph = (unsigned short*)&pBh[nt];
        unsigned short* pl = (unsigned short*)&pBl[nt];
#pragma unroll
        for (int r = 0; r < 4; ++r) {
          int t = w * 16 + g16 * 4 + r;
          float kv = acc[r] * i2_16;
          float Vv = vn[((size_t)bh * 2048 + t0 + t) * 256 + v0 + n];
          float Bv = cb1a[r] * Vv - cb2a[r] * kv;
          splitw(Bv * 64.f, ph[r], pl[r]);
        }
      }
    }
    __syncthreads();
    {
      const int tb = w * 16 + g16 * 4;
      for (int nt = 0; nt < 2; ++nt) {
        const int n = nt * 16 + lr, swn = (n & 7) << 3;
        int ad = n * 64 + (tb ^ swn);
        *(ushort4*)&BT_h[ad] = pBh[nt];
        *(ushort4*)&BT_l[ad] = pBl[nt];
      }
    }
    __syncthreads();
    {
      const int arow = w * 16 + lr, swa = (arow & 7) << 3;
      const int tb = w * 16 + g16 * 4;
      for (int nt = 0; nt < 2; ++nt) {
        f32x4 acc = (f32x4){0.f, 0.f, 0.f, 0.f};
        const int n = nt * 16 + lr, swn = (n & 7) << 3;
#pragma unroll
        for (int ks = 0; ks < 2; ++ks) {
          int c = ks * 32 + g16 * 8;
          v8h ah = *(const v8h*)&Ts_h[arow * 64 + (c ^ swa)];
          v8h al = *(const v8h*)&Ts_l[arow * 64 + (c ^ swa)];
          v8h bhh = *(const v8h*)&BT_h[n * 64 + (c ^ swn)];
          v8h bll = *(const v8h*)&BT_l[n * 64 + (c ^ swn)];
          MFMA3(acc, ah, al, bhh, bll);
        }
        ushort4 H, L;
        unsigned short* ph = (unsigned short*)&H;
        unsigned short* pl = (unsigned short*)&L;
#pragma unroll
        for (int r = 0; r < 4; ++r) splitw(acc[r] * uscale, ph[r], pl[r]);
        int ad = n * 64 + (tb ^ swn);
        *(ushort4*)&UT_h[ad] = H;
        *(ushort4*)&UT_l[ad] = L;
      }
    }
    __syncthreads();
    {
      const int arow = w * 16 + lr, swa = (arow & 7) << 3;
      for (int nt = 0; nt < 2; ++nt) {
        const int n = nt * 16 + lr, swn = (n & 7) << 3;
#pragma unroll
        for (int ks = 0; ks < 2; ++ks) {
          int c = ks * 32 + g16 * 8;
          v8h ah = *(const v8h*)&Hs_h[arow * 64 + (c ^ swa)];
          v8h al = *(const v8h*)&Hs_l[arow * 64 + (c ^ swa)];
          v8h bhh = *(const v8h*)&UT_h[n * 64 + (c ^ swn)];
          v8h bll = *(const v8h*)&UT_l[n * 64 + (c ^ swn)];
          MFMA3(Oacc[nt], ah, al, bhh, bll);
        }
      }
      for (int nt = 0; nt < 2; ++nt) {
        const int n = nt * 16 + lr;
#pragma unroll
        for (int r = 0; r < 4; ++r) {
          int t = t0 + w * 16 + g16 * 4 + r;
          float Ov = Oacc[nt][r] * i2_20;
          float gv = gp[(size_t)t * GW + n];
          out[((size_t)b * 2048 + t) * 4096 + h * 256 + v0 + n] = Ov * (gv / (1.f + expf(-gv)));
        }
      }
    }
    {
      const float cc1024 = cc * 1024.f;
#pragma unroll
      for (int m2 = w * 2; m2 < w * 2 + 2; ++m2) {
        const int arow = m2 * 16 + lr, swa = (arow & 7) << 3;
        const int fb = m2 * 16 + g16 * 4;
        for (int nt = 0; nt < 2; ++nt) {
          const int n = nt * 16 + lr, swn = (n & 7) << 3;
          int sad = n * 128 + (fb ^ swn);
          ushort4 sh4 = *(ushort4*)&St_h[sad];
          ushort4 sl4 = *(ushort4*)&St_l[sad];
          f32x4 acc;
          acc[0] = cc1024 * (h2f(sh4.x) + h2f(sl4.x));
          acc[1] = cc1024 * (h2f(sh4.y) + h2f(sl4.y));
          acc[2] = cc1024 * (h2f(sh4.z) + h2f(sl4.z));
          acc[3] = cc1024 * (h2f(sh4.w) + h2f(sl4.w));
#pragma unroll
          for (int ks = 0; ks < 2; ++ks) {
            int c = ks * 32 + g16 * 8;
            v8h ah = *(const v8h*)&KTs_h[arow * 64 + (c ^ swa)];
            v8h al = *(const v8h*)&KTs_l[arow * 64 + (c ^ swa)];
            v8h bhh = *(const v8h*)&UT_h[n * 64 + (c ^ swn)];
            v8h bll = *(const v8h*)&UT_l[n * 64 + (c ^ swn)];
            MFMA3(acc, ah, al, bhh, bll);
          }
          ushort4 H, L;
          unsigned short* ph = (unsigned short*)&H;
          unsigned short* pl = (unsigned short*)&L;
#pragma unroll
          for (int r = 0; r < 4; ++r) splitw(acc[r] * sscale, ph[r], pl[r]);
          *(ushort4*)&St_h[sad] = H;
          *(ushort4*)&St_l[sad] = L;
        }
      }
    }
    __syncthreads();
  }
}

extern "C" void kernel_launch(void* const* d_in, const int* in_sizes, int n_in,
                              void* d_out, int out_size, void* d_ws, size_t ws_size,
                              hipStream_t stream) {
  const float* hidden  = (const float*)d_in[0];
  const float* W       = (const float*)d_in[1];
  const float* Wc      = (const float*)d_in[2];
  const float* A_log   = (const float*)d_in[3];
  const float* dt_bias = (const float*)d_in[4];
  float* out = (float*)d_out;

  char* ws = (char*)d_ws;
  _Float16* Ap = (_Float16*)ws;
  _Float16* Bp = (_Float16*)(ws + (size_t)33554432);
  float* qn    = (float*)ws;
  float* kn    = qn + (size_t)8388608;
  float* vn    = kn + (size_t)8388608;
  float* g_arr = vn + (size_t)16777216;
  float* beta  = g_arr + (size_t)65536;
  float* projQKV = (float*)(ws + (size_t)135266304);
  char*  tb0 = ws + (size_t)135266304;
  _Float16* Tg_h  = (_Float16*)tb0;
  _Float16* Tg_l  = (_Float16*)(tb0 + (size_t)8388608);
  _Float16* Hg_h  = (_Float16*)(tb0 + (size_t)16777216);
  _Float16* Hg_l  = (_Float16*)(tb0 + (size_t)25165824);
  _Float16* KTg_h = (_Float16*)(tb0 + (size_t)33554432);
  _Float16* KTg_l = (_Float16*)(tb0 + (size_t)50331648);
  float*    coefG = (float*)   (tb0 + (size_t)67108864);
  float* projGate = (float*)(ws + (size_t)269484032);

  pack_A_k<<<32 * KSTEPS, 256, 0, stream>>>(hidden, Ap);
  pack_B_k<<<NTILE_N * KSTEPS, 256, 0, stream>>>(W, Bp);
  gemm_mfma_k<<<32 * NTILE_N, 256, 0, stream>>>(Ap, Bp, projQKV, projGate);

  conv_qk_k<<<dim3(32, 32, 2), 64, 0, stream>>>(projQKV, Wc, qn, kn);
  conv_v_k<<<dim3(32, 4, 2), 256, 0, stream>>>(projQKV, Wc, vn);
  beta_g_k<<<(2 * NH * L_SEQ + 255) / 256, 256, 0, stream>>>(projGate, A_log, dt_bias, beta, g_arr);

  p1_k<<<1024, 256, 0, stream>>>(kn, qn, g_arr, beta, Tg_h, Tg_l, Hg_h, Hg_l, KTg_h, KTg_l, coefG);
  p2_k<<<256, 256, 0, stream>>>(qn, kn, vn, projGate, Tg_h, Tg_l, Hg_h, Hg_l, KTg_h, KTg_l, coefG, out);
}

// Round 10
// 1022.134 us; speedup vs baseline: 3.8363x; 1.0678x over previous
//
#include <hip/hip_runtime.h>
#include <hip/hip_bf16.h>
#include <hip/hip_fp16.h>
#include <math.h>

#define L_SEQ 2048
#define DM    2048
#define NH    16
#define DH    128
#define HVD   256
#define NPROJ 12320
#define QKVW  8192
#define GW    4128

#define NTILE_N 97
#define KSTEPS  64

typedef _Float16 v8h __attribute__((ext_vector_type(8)));
typedef float f32x4 __attribute__((ext_vector_type(4)));

__device__ __forceinline__ void gload_lds16(const void* g, void* l) {
  __builtin_amdgcn_global_load_lds((const __attribute__((address_space(1))) void*)g,
                                   (__attribute__((address_space(3))) void*)l, 16, 0, 0);
}

__device__ __forceinline__ void splitw(float x, unsigned short& h, unsigned short& l) {
  _Float16 hh = (_Float16)x;
  _Float16 ll = (_Float16)(x - (float)hh);
  h = *(unsigned short*)&hh;
  l = *(unsigned short*)&ll;
}
__device__ __forceinline__ float h2f(unsigned short u) {
  return (float)(*(_Float16*)&u);
}

#define MFMA3(acc, ah, al, bh_, bl_)                                          \
  acc = __builtin_amdgcn_mfma_f32_16x16x32_f16(ah, bh_, acc, 0, 0, 0);        \
  acc = __builtin_amdgcn_mfma_f32_16x16x32_f16(ah, bl_, acc, 0, 0, 0);        \
  acc = __builtin_amdgcn_mfma_f32_16x16x32_f16(al, bh_, acc, 0, 0, 0);

// ---------------- pack A: hidden(4096x2048) f32 -> fp16 hi/lo, x16 ----------------
__global__ __launch_bounds__(256) void pack_A_k(const float* __restrict__ H, _Float16* __restrict__ Ap) {
  const int mtile = blockIdx.x >> 6, kstep = blockIdx.x & 63;
  const size_t base = (size_t)blockIdx.x * 2 * 4096;
#pragma unroll
  for (int it = 0; it < 2; ++it) {
    int s = threadIdx.x + it * 256;
    int g = s >> 7, r = s & 127;
    const float* src = H + ((size_t)(mtile * 128 + r)) * 2048 + kstep * 32 + g * 8;
    float4 x0 = *(const float4*)src;
    float4 x1 = *(const float4*)(src + 4);
    float xs[8] = {x0.x, x0.y, x0.z, x0.w, x1.x, x1.y, x1.z, x1.w};
    v8h hi, lo;
#pragma unroll
    for (int j = 0; j < 8; ++j) {
      float v = xs[j] * 16.f;
      _Float16 h = (_Float16)v;
      hi[j] = h;
      lo[j] = (_Float16)(v - (float)h);
    }
    *(v8h*)(Ap + base + g * 1024 + r * 8) = hi;
    *(v8h*)(Ap + base + 4096 + g * 1024 + r * 8) = lo;
  }
}

// ---------------- pack B: W(2048x12320) f32 -> fp16 hi/lo, x1024 ----------------
__global__ __launch_bounds__(256) void pack_B_k(const float* __restrict__ W, _Float16* __restrict__ Bp) {
  const int ntile = blockIdx.x >> 6, kstep = blockIdx.x & 63;
  const size_t base = (size_t)blockIdx.x * 2 * 4096;
#pragma unroll
  for (int it = 0; it < 2; ++it) {
    int s = threadIdx.x + it * 256;
    int g = s >> 7, col = s & 127;
    int n = ntile * 128 + col;
    v8h hi, lo;
#pragma unroll
    for (int j = 0; j < 8; ++j) {
      int k = kstep * 32 + g * 8 + j;
      float v = (n < NPROJ) ? W[(size_t)k * NPROJ + n] * 1024.f : 0.f;
      _Float16 h = (_Float16)v;
      hi[j] = h;
      lo[j] = (_Float16)(v - (float)h);
    }
    *(v8h*)(Bp + base + g * 1024 + col * 8) = hi;
    *(v8h*)(Bp + base + 4096 + g * 1024 + col * 8) = lo;
  }
}

// ---------------- split-fp16 MFMA GEMM (R8-known-good: 16x16, counted-vmcnt 2-buffer) ----------------
__global__ __launch_bounds__(256) void gemm_mfma_k(const _Float16* __restrict__ Ap,
                                                   const _Float16* __restrict__ Bp,
                                                   float* __restrict__ Cq,
                                                   float* __restrict__ Cg) {
  __shared__ _Float16 lds[2][16384];
  const int tid = threadIdx.x;
  const int mtile = blockIdx.x & 31;
  const int ntile = blockIdx.x >> 5;
  const int wid = tid >> 6, lane = tid & 63;
  const int wm = wid >> 1, wn = wid & 1;
  const int lrow = lane & 15, g = lane >> 4;

  f32x4 acc[4][4];
#pragma unroll
  for (int i = 0; i < 4; ++i)
#pragma unroll
    for (int j = 0; j < 4; ++j) acc[i][j] = (f32x4){0.f, 0.f, 0.f, 0.f};

  const int aoff = (wm * 64 + lrow) * 8 + g * 1024;
  const int boff = (wn * 64 + lrow) * 8 + g * 1024;

  const _Float16* Asrc = Ap + ((size_t)(mtile * KSTEPS) * 2) * 4096 + tid * 8;
  const _Float16* Bsrc = Bp + ((size_t)(ntile * KSTEPS) * 2) * 4096 + tid * 8;

#define STAGE(KS, BUF)                                                         \
  {                                                                            \
    const _Float16* An_ = Asrc + (size_t)(KS) * 8192;                          \
    const _Float16* Bn_ = Bsrc + (size_t)(KS) * 8192;                          \
    _Pragma("unroll")                                                          \
    for (int r = 0; r < 4; ++r) {                                              \
      gload_lds16(An_ + r * 2048, &lds[BUF][r * 2048 + tid * 8]);              \
      gload_lds16(Bn_ + r * 2048, &lds[BUF][8192 + r * 2048 + tid * 8]);       \
    }                                                                          \
  }

  STAGE(0, 0);
  STAGE(1, 1);

  for (int kstep = 0; kstep < KSTEPS; ++kstep) {
    const int p = kstep & 1;
    if (kstep + 1 < KSTEPS) {
      asm volatile("s_waitcnt vmcnt(8)" ::: "memory");
    } else {
      asm volatile("s_waitcnt vmcnt(0)" ::: "memory");
    }
    __builtin_amdgcn_sched_barrier(0);
    __builtin_amdgcn_s_barrier();
    __builtin_amdgcn_sched_barrier(0);

    v8h ah[4], al[4], bh[4], bl[4];
#pragma unroll
    for (int f = 0; f < 4; ++f) {
      ah[f] = *(const v8h*)&lds[p][aoff + f * 128];
      al[f] = *(const v8h*)&lds[p][4096 + aoff + f * 128];
      bh[f] = *(const v8h*)&lds[p][8192 + boff + f * 128];
      bl[f] = *(const v8h*)&lds[p][12288 + boff + f * 128];
    }
#pragma unroll
    for (int fm = 0; fm < 4; ++fm)
#pragma unroll
      for (int fn = 0; fn < 4; ++fn) {
        acc[fm][fn] = __builtin_amdgcn_mfma_f32_16x16x32_f16(ah[fm], bh[fn], acc[fm][fn], 0, 0, 0);
        acc[fm][fn] = __builtin_amdgcn_mfma_f32_16x16x32_f16(ah[fm], bl[fn], acc[fm][fn], 0, 0, 0);
        acc[fm][fn] = __builtin_amdgcn_mfma_f32_16x16x32_f16(al[fm], bh[fn], acc[fm][fn], 0, 0, 0);
      }
    __builtin_amdgcn_sched_barrier(0);
    __builtin_amdgcn_s_barrier();
    __builtin_amdgcn_sched_barrier(0);
    if (kstep + 2 < KSTEPS) STAGE(kstep + 2, p);
  }
#undef STAGE

  const float sc = 1.f / 16384.f;
#pragma unroll
  for (int fm = 0; fm < 4; ++fm) {
    int row = mtile * 128 + wm * 64 + fm * 16 + g * 4;
#pragma unroll
    for (int fn = 0; fn < 4; ++fn) {
      int col = ntile * 128 + wn * 64 + fn * 16 + lrow;
      if (col < QKVW) {
#pragma unroll
        for (int r = 0; r < 4; ++r)
          Cq[(size_t)(row + r) * QKVW + col] = acc[fm][fn][r] * sc;
      } else if (col < NPROJ) {
        int lcol = col - QKVW;
#pragma unroll
        for (int r = 0; r < 4; ++r)
          Cg[(size_t)(row + r) * GW + lcol] = acc[fm][fn][r] * sc;
      }
    }
  }
}

// ------------- conv+silu+l2norm for q/k -> PRE-SPLIT fp16 hi/lo, pre-swizzled table layout -------------
// layout: idx = (bh*2048 + t)*128 + ((feat) ^ ((t&7)<<3)); q scaled by qscale, both x1024.
__global__ __launch_bounds__(64) void conv_qk_k(
    const float* __restrict__ projQKV, const float* __restrict__ Wc,
    _Float16* __restrict__ qh, _Float16* __restrict__ ql,
    _Float16* __restrict__ kh, _Float16* __restrict__ kl)
{
  const int b = blockIdx.z, hg = blockIdx.y, tc = blockIdx.x;
  const int lane = threadIdx.x;
  const int ch = hg * 128 + lane * 2;
  float4 Wa = *(const float4*)(Wc + (size_t)ch * 4);
  float4 Wb = *(const float4*)(Wc + (size_t)ch * 4 + 4);
  const int t0 = tc * 64;
  const float* P = projQKV + (size_t)b * L_SEQ * QKVW + ch;
  float2 w0 = make_float2(0.f, 0.f), w1 = w0, w2 = w0;
  if (t0 >= 3) w0 = *(const float2*)(P + (size_t)(t0 - 3) * QKVW);
  if (t0 >= 2) w1 = *(const float2*)(P + (size_t)(t0 - 2) * QKVW);
  if (t0 >= 1) w2 = *(const float2*)(P + (size_t)(t0 - 1) * QKVW);
  const bool isq = hg < 16;
  const int h = isq ? hg : hg - 16;
  _Float16* dh = (isq ? qh : kh) + (((size_t)b * NH + h) * L_SEQ) * 128;
  _Float16* dl = (isq ? ql : kl) + (((size_t)b * NH + h) * L_SEQ) * 128;
  const float sc = (isq ? 0.08838834764831845f : 1.f) * 1024.f;
  for (int t = t0; t < t0 + 64; ++t) {
    float2 x = *(const float2*)(P + (size_t)t * QKVW);
    float y0 = w0.x * Wa.x + w1.x * Wa.y + w2.x * Wa.z + x.x * Wa.w;
    float y1 = w0.y * Wb.x + w1.y * Wb.y + w2.y * Wb.z + x.y * Wb.w;
    w0 = w1; w1 = w2; w2 = x;
    y0 = y0 / (1.f + expf(-y0));
    y1 = y1 / (1.f + expf(-y1));
    float ss = y0 * y0 + y1 * y1;
#pragma unroll
    for (int off = 1; off < 64; off <<= 1) ss += __shfl_xor(ss, off);
    float nrm = sc / sqrtf(ss + 1e-6f);
    unsigned short h0, l0, h1, l1;
    splitw(y0 * nrm, h0, l0);
    splitw(y1 * nrm, h1, l1);
    int idx = t * 128 + ((lane * 2) ^ ((t & 7) << 3));
    *(unsigned int*)&dh[idx] = (unsigned int)h0 | ((unsigned int)h1 << 16);
    *(unsigned int*)&dl[idx] = (unsigned int)l0 | ((unsigned int)l1 << 16);
  }
}

// ------------- conv+silu for v: elementwise, float4 per thread -------------
__global__ __launch_bounds__(256) void conv_v_k(
    const float* __restrict__ projQKV, const float* __restrict__ Wc,
    float* __restrict__ vn)
{
  const int b = blockIdx.z, cg = blockIdx.y, tc = blockIdx.x;
  const int vc = (cg * 256 + threadIdx.x) * 4;
  const int ch = 4096 + vc;
  float4 Wv0 = *(const float4*)(Wc + (size_t)ch * 4);
  float4 Wv1 = *(const float4*)(Wc + (size_t)ch * 4 + 4);
  float4 Wv2 = *(const float4*)(Wc + (size_t)ch * 4 + 8);
  float4 Wv3 = *(const float4*)(Wc + (size_t)ch * 4 + 12);
  const int t0 = tc * 64;
  const float* P = projQKV + (size_t)b * L_SEQ * QKVW + ch;
  float4 w0 = make_float4(0.f, 0.f, 0.f, 0.f), w1 = w0, w2 = w0;
  if (t0 >= 3) w0 = *(const float4*)(P + (size_t)(t0 - 3) * QKVW);
  if (t0 >= 2) w1 = *(const float4*)(P + (size_t)(t0 - 2) * QKVW);
  if (t0 >= 1) w2 = *(const float4*)(P + (size_t)(t0 - 1) * QKVW);
  const int h = vc >> 8, vcol = vc & 255;
  float* dst = vn + (((size_t)b * NH + h) * L_SEQ) * HVD + vcol;
  for (int t = t0; t < t0 + 64; ++t) {
    float4 x = *(const float4*)(P + (size_t)t * QKVW);
    float4 y;
    y.x = w0.x * Wv0.x + w1.x * Wv0.y + w2.x * Wv0.z + x.x * Wv0.w;
    y.y = w0.y * Wv1.x + w1.y * Wv1.y + w2.y * Wv1.z + x.y * Wv1.w;
    y.z = w0.z * Wv2.x + w1.z * Wv2.y + w2.z * Wv2.z + x.z * Wv2.w;
    y.w = w0.w * Wv3.x + w1.w * Wv3.y + w2.w * Wv3.z + x.w * Wv3.w;
    w0 = w1; w1 = w2; w2 = x;
    y.x = y.x / (1.f + expf(-y.x));
    y.y = y.y / (1.f + expf(-y.y));
    y.z = y.z / (1.f + expf(-y.z));
    y.w = y.w / (1.f + expf(-y.w));
    *(float4*)(dst + (size_t)t * HVD) = y;
  }
}

// ------------- beta = sigmoid(b), g = -exp(A_log)*softplus(A+dt_bias) -------------
__global__ __launch_bounds__(256) void beta_g_k(
    const float* __restrict__ projGate, const float* __restrict__ A_log,
    const float* __restrict__ dt_bias, float* __restrict__ beta, float* __restrict__ g_out)
{
  int idx = blockIdx.x * 256 + threadIdx.x;
  if (idx >= 2 * NH * L_SEQ) return;
  int t = idx & (L_SEQ - 1);
  int h = (idx >> 11) & (NH - 1);
  int b = idx >> 15;
  size_t row = (size_t)(b * L_SEQ + t) * GW;
  float bv = projGate[row + 4096 + h];
  float av = projGate[row + 4112 + h];
  float be = 1.f / (1.f + expf(-bv));
  float xx = av + dt_bias[h];
  float sp = (xx > 20.f) ? xx : log1pf(expf(xx));
  float g = -expf(A_log[h]) * sp;
  beta[idx] = be;
  g_out[idx] = g;
}

// ------------- Phase 1 (fused): T=(I+A)^-1, Hq, KT, coef — gload-staged pre-split q/k -------------
__global__ __launch_bounds__(256) void p1_k(
    const _Float16* __restrict__ kh_g, const _Float16* __restrict__ kl_g,
    const _Float16* __restrict__ qh_g, const _Float16* __restrict__ ql_g,
    const float* __restrict__ g_arr, const float* __restrict__ beta_arr,
    _Float16* __restrict__ Tg_h, _Float16* __restrict__ Tg_l,
    _Float16* __restrict__ Hg_h, _Float16* __restrict__ Hg_l,
    _Float16* __restrict__ KTg_h, _Float16* __restrict__ KTg_l,
    float* __restrict__ coefG)
{
  __shared__ _Float16 Kh[8192], Kl[8192];
  __shared__ _Float16 QS[16384];          // Qh|Ql; overlaid by Am|Tm after Hq
  __shared__ float lc[64], be[64], kw[64];
  _Float16* Qh = QS;
  _Float16* Ql = QS + 8192;
  float* Am = (float*)QS;
  float* Tm = Am + 4096;
  const int cid = blockIdx.x, bh = cid >> 5, ch = cid & 31, t0 = ch * 64;
  const int tid = threadIdx.x, w = tid >> 6, lane = tid & 63, lr = lane & 15, g16 = lane >> 4;

  const size_t gb = ((size_t)bh * 2048 + t0) * 128;
#pragma unroll
  for (int l = 0; l < 4; ++l) {
    int i = (tid + l * 256) * 8;
    gload_lds16(kh_g + gb + i, &Kh[i]);
    gload_lds16(kl_g + gb + i, &Kl[i]);
    gload_lds16(qh_g + gb + i, &Qh[i]);
    gload_lds16(ql_g + gb + i, &Ql[i]);
  }
  if (tid < 64) {
    float x = g_arr[(size_t)bh * 2048 + t0 + tid];
#pragma unroll
    for (int off = 1; off < 64; off <<= 1) { float y = __shfl_up(x, off); if (tid >= off) x += y; }
    lc[tid] = x;
    float x63 = __shfl(x, 63);
    float b_ = beta_arr[(size_t)bh * 2048 + t0 + tid];
    be[tid] = b_;
    kw[tid] = expf(x63 - x);
    float ca = expf(x);
    coefG[(size_t)cid * 192 + tid] = ca;
    coefG[(size_t)cid * 192 + 64 + tid] = b_;
    coefG[(size_t)cid * 192 + 128 + tid] = b_ * ca;
  }
  __syncthreads();
  const float ds20 = 1.f / 1048576.f;
  const int arow = w * 16 + lr, swa = (arow & 7) << 3;
  // G = K K^T -> gacc (kept in regs until Q is dead)
  f32x4 gacc[4];
  for (int nt = 0; nt < 4; ++nt) {
    f32x4 acc = (f32x4){0.f, 0.f, 0.f, 0.f};
    int nrow = nt * 16 + lr, swn = (nrow & 7) << 3;
#pragma unroll
    for (int ks = 0; ks < 4; ++ks) {
      int c = ks * 32 + g16 * 8;
      v8h ah = *(const v8h*)&Kh[arow * 128 + (c ^ swa)];
      v8h al = *(const v8h*)&Kl[arow * 128 + (c ^ swa)];
      v8h bhh = *(const v8h*)&Kh[nrow * 128 + (c ^ swn)];
      v8h bll = *(const v8h*)&Kl[nrow * 128 + (c ^ swn)];
      MFMA3(acc, ah, al, bhh, bll);
    }
    gacc[nt] = acc;
  }
  // Hq = Q K^T, write to global (sigma 16384)
  for (int nt = 0; nt < 4; ++nt) {
    f32x4 acc = (f32x4){0.f, 0.f, 0.f, 0.f};
    int nrow = nt * 16 + lr, swn = (nrow & 7) << 3;
#pragma unroll
    for (int ks = 0; ks < 4; ++ks) {
      int c = ks * 32 + g16 * 8;
      v8h ah = *(const v8h*)&Qh[arow * 128 + (c ^ swa)];
      v8h al = *(const v8h*)&Ql[arow * 128 + (c ^ swa)];
      v8h bhh = *(const v8h*)&Kh[nrow * 128 + (c ^ swn)];
      v8h bll = *(const v8h*)&Kl[nrow * 128 + (c ^ swn)];
      MFMA3(acc, ah, al, bhh, bll);
    }
    int s_ = nt * 16 + lr;
#pragma unroll
    for (int r = 0; r < 4; ++r) {
      int t = w * 16 + g16 * 4 + r;
      float hv = (s_ <= t) ? acc[r] * ds20 * expf(lc[t] - lc[s_]) : 0.f;
      unsigned short hh, ll; splitw(hv * 16384.f, hh, ll);
      size_t go = (size_t)cid * 4096 + t * 64 + (s_ ^ ((t & 7) << 3));
      *(unsigned short*)&Hg_h[go] = hh;
      *(unsigned short*)&Hg_l[go] = ll;
    }
  }
  __syncthreads();   // Q LDS dead -> overlay Am/Tm
  for (int nt = 0; nt < 4; ++nt) {
    int s_ = nt * 16 + lr;
#pragma unroll
    for (int r = 0; r < 4; ++r) {
      int t = w * 16 + g16 * 4 + r;
      float av = (s_ < t) ? gacc[nt][r] * ds20 * be[t] * expf(lc[t] - lc[s_]) : 0.f;
      Am[t * 64 + s_] = av;
    }
  }
#pragma unroll
  for (int l = 0; l < 16; ++l) { int s2 = tid + l * 256; Tm[s2] = ((s2 >> 6) == (s2 & 63)) ? 1.f : 0.f; }
  // KT global (kw-folded, sigma 1024, pre-swizzled)
  for (int s = tid; s < 8192; s += 256) {
    int feat = s >> 6, t = s & 63;
    int ki = t * 128 + (feat ^ ((t & 7) << 3));
    float kvv = ((float)Kh[ki] + (float)Kl[ki]) * kw[t];
    unsigned short hh, ll; splitw(kvv, hh, ll);
    size_t go = (size_t)cid * 8192 + feat * 64 + (t ^ ((feat & 7) << 3));
    *(unsigned short*)&KTg_h[go] = hh;
    *(unsigned short*)&KTg_l[go] = ll;
  }
  __syncthreads();
  if (w == 0) {
    int j = lane;
    for (int t = 1; t < 64; ++t) {
      float sum = 0.f;
      for (int s = 0; s < t; ++s) sum = fmaf(Am[t * 64 + s], Tm[s * 64 + j], sum);
      Tm[t * 64 + j] = ((j == t) ? 1.f : 0.f) - sum;
    }
  }
  __syncthreads();
#pragma unroll
  for (int l = 0; l < 16; ++l) {
    int s2 = tid + l * 256;
    int t = s2 >> 6, sc_ = s2 & 63;
    unsigned short hh, ll; splitw(Tm[s2] * 256.f, hh, ll);
    size_t go = (size_t)cid * 4096 + t * 64 + (sc_ ^ ((t & 7) << 3));
    *(unsigned short*)&Tg_h[go] = hh;
    *(unsigned short*)&Tg_l[go] = ll;
  }
}

// ------------- Phase 2: sequential chunk scan, VW=32, 256 blocks, 5 barriers/chunk -------------
__global__ __launch_bounds__(256) void p2_k(
    const _Float16* __restrict__ qh_g, const _Float16* __restrict__ ql_g,
    const _Float16* __restrict__ kh_g, const _Float16* __restrict__ kl_g,
    const float* __restrict__ vn, const float* __restrict__ projGate,
    const _Float16* __restrict__ Tg_h, const _Float16* __restrict__ Tg_l,
    const _Float16* __restrict__ Hg_h, const _Float16* __restrict__ Hg_l,
    const _Float16* __restrict__ KTg_h, const _Float16* __restrict__ KTg_l,
    const float* __restrict__ coefG, float* __restrict__ out)
{
  __shared__ _Float16 St_h[4096], St_l[4096];     // [32 v][128 feat]
  __shared__ _Float16 KQ0[8192], KQ1[8192];       // Qh|Ql ; BT in KQ0, UT in KQ1
  __shared__ _Float16 KK0[8192], KK1[8192];       // Kh|Kl
  __shared__ _Float16 KTs_h[8192], KTs_l[8192];
  __shared__ _Float16 Ts_h[4096], Ts_l[4096];
  __shared__ _Float16 Hs_h[4096], Hs_l[4096];
  __shared__ float cf[192];

  const int blk = blockIdx.x;
  const int vb = blk >> 5, bh = blk & 31;
  const int b = bh >> 4, h = bh & 15, v0 = vb * 32;
  const int tid = threadIdx.x, w = tid >> 6, lane = tid & 63, lr = lane & 15, g16 = lane >> 4;

  _Float16* BT_h = &KQ0[0];
  _Float16* BT_l = &KQ0[4096];
  _Float16* UT_h = &KQ1[0];
  _Float16* UT_l = &KQ1[4096];

#pragma unroll
  for (int l = 0; l < 8; ++l) { ((unsigned int*)St_h)[tid + l * 256] = 0u; }
#pragma unroll
  for (int l = 0; l < 8; ++l) { ((unsigned int*)St_l)[tid + l * 256] = 0u; }

  const float* gp = projGate + ((size_t)b * 2048) * GW + h * 256 + v0;
  const float i2_16 = 1.f / 65536.f;
  const float i2_20 = 1.f / 1048576.f;
  const float uscale = 1.f / 256.f;
  const float sscale = 64.f / 65536.f;

  for (int ch = 0; ch < 32; ++ch) {
    const int cid = bh * 32 + ch, t0 = ch * 64;
    // ---- stage: all gloads (T/H/KT/Q/K/cf) + V->regs ----
    {
      const _Float16* th = Tg_h + (size_t)cid * 4096;
      const _Float16* tl = Tg_l + (size_t)cid * 4096;
      const _Float16* hh = Hg_h + (size_t)cid * 4096;
      const _Float16* hl = Hg_l + (size_t)cid * 4096;
      const _Float16* kth = KTg_h + (size_t)cid * 8192;
      const _Float16* ktl = KTg_l + (size_t)cid * 8192;
      const size_t gb = ((size_t)bh * 2048 + t0) * 128;
#pragma unroll
      for (int l = 0; l < 2; ++l) {
        int i = (tid + l * 256) * 8;
        gload_lds16(th + i, &Ts_h[i]);
        gload_lds16(tl + i, &Ts_l[i]);
        gload_lds16(hh + i, &Hs_h[i]);
        gload_lds16(hl + i, &Hs_l[i]);
      }
#pragma unroll
      for (int l = 0; l < 4; ++l) {
        int i = (tid + l * 256) * 8;
        gload_lds16(kth + i, &KTs_h[i]);
        gload_lds16(ktl + i, &KTs_l[i]);
        gload_lds16(qh_g + gb + i, &KQ0[i]);
        gload_lds16(ql_g + gb + i, &KQ1[i]);
        gload_lds16(kh_g + gb + i, &KK0[i]);
        gload_lds16(kl_g + gb + i, &KK1[i]);
      }
      if (tid < 48) gload_lds16(coefG + (size_t)cid * 192 + tid * 4, &cf[tid * 4]);
    }
    // V prefetch into regs (overlaps gloads)
    float Vv[2][4];
#pragma unroll
    for (int nt = 0; nt < 2; ++nt)
#pragma unroll
      for (int r = 0; r < 4; ++r)
        Vv[nt][r] = vn[((size_t)bh * 2048 + t0 + w * 16 + g16 * 4 + r) * 256 + v0 + nt * 16 + lr];
    __syncthreads();   // (b)
    const float cc = cf[63];
    const int arow = w * 16 + lr, swa = (arow & 7) << 3;
    // ---- merged phase: QS0 -> Oacc  AND  KS0 -> B (regs) ----
    f32x4 Oacc[2];
    {
      for (int nt = 0; nt < 2; ++nt) {
        f32x4 acc = (f32x4){0.f, 0.f, 0.f, 0.f};
        const int n = nt * 16 + lr, swn = (n & 7) << 3;
#pragma unroll
        for (int ks = 0; ks < 4; ++ks) {
          int c = ks * 32 + g16 * 8;
          v8h ah = *(const v8h*)&KQ0[arow * 128 + (c ^ swa)];
          v8h al = *(const v8h*)&KQ1[arow * 128 + (c ^ swa)];
          v8h bhh = *(const v8h*)&St_h[n * 128 + (c ^ swn)];
          v8h bll = *(const v8h*)&St_l[n * 128 + (c ^ swn)];
          MFMA3(acc, ah, al, bhh, bll);
        }
        Oacc[nt] = acc;
      }
      float4 cav = *(float4*)&cf[w * 16 + g16 * 4];
#pragma unroll
      for (int nt = 0; nt < 2; ++nt) {
        Oacc[nt][0] *= cav.x * 16.f; Oacc[nt][1] *= cav.y * 16.f;
        Oacc[nt][2] *= cav.z * 16.f; Oacc[nt][3] *= cav.w * 16.f;
      }
    }
    ushort4 pBh[2], pBl[2];
    {
      float4 cb1v = *(float4*)&cf[64 + w * 16 + g16 * 4];
      float4 cb2v = *(float4*)&cf[128 + w * 16 + g16 * 4];
      for (int nt = 0; nt < 2; ++nt) {
        f32x4 acc = (f32x4){0.f, 0.f, 0.f, 0.f};
        const int n = nt * 16 + lr, swn = (n & 7) << 3;
#pragma unroll
        for (int ks = 0; ks < 4; ++ks) {
          int c = ks * 32 + g16 * 8;
          v8h ah = *(const v8h*)&KK0[arow * 128 + (c ^ swa)];
          v8h al = *(const v8h*)&KK1[arow * 128 + (c ^ swa)];
          v8h bhh = *(const v8h*)&St_h[n * 128 + (c ^ swn)];
          v8h bll = *(const v8h*)&St_l[n * 128 + (c ^ swn)];
          MFMA3(acc, ah, al, bhh, bll);
        }
        float cb1a[4] = {cb1v.x, cb1v.y, cb1v.z, cb1v.w};
        float cb2a[4] = {cb2v.x, cb2v.y, cb2v.z, cb2v.w};
        unsigned short* ph = (unsigned short*)&pBh[nt];
        unsigned short* pl = (unsigned short*)&pBl[nt];
#pragma unroll
        for (int r = 0; r < 4; ++r) {
          float kv = acc[r] * i2_16;
          float Bv = cb1a[r] * Vv[nt][r] - cb2a[r] * kv;
          splitw(Bv * 64.f, ph[r], pl[r]);
        }
      }
    }
    __syncthreads();   // (c) Q dead -> BT may overwrite KQ0
    {
      const int tb = w * 16 + g16 * 4;
      for (int nt = 0; nt < 2; ++nt) {
        const int n = nt * 16 + lr, swn = (n & 7) << 3;
        int ad = n * 64 + (tb ^ swn);
        *(ushort4*)&BT_h[ad] = pBh[nt];
        *(ushort4*)&BT_l[ad] = pBl[nt];
      }
    }
    __syncthreads();   // (d) BT ready
    {
      const int tb = w * 16 + g16 * 4;
      for (int nt = 0; nt < 2; ++nt) {
        f32x4 acc = (f32x4){0.f, 0.f, 0.f, 0.f};
        const int n = nt * 16 + lr, swn = (n & 7) << 3;
#pragma unroll
        for (int ks = 0; ks < 2; ++ks) {
          int c = ks * 32 + g16 * 8;
          v8h ah = *(const v8h*)&Ts_h[arow * 64 + (c ^ swa)];
          v8h al = *(const v8h*)&Ts_l[arow * 64 + (c ^ swa)];
          v8h bhh = *(const v8h*)&BT_h[n * 64 + (c ^ swn)];
          v8h bll = *(const v8h*)&BT_l[n * 64 + (c ^ swn)];
          MFMA3(acc, ah, al, bhh, bll);
        }
        ushort4 H, L;
        unsigned short* ph = (unsigned short*)&H;
        unsigned short* pl = (unsigned short*)&L;
#pragma unroll
        for (int r = 0; r < 4; ++r) splitw(acc[r] * uscale, ph[r], pl[r]);
        int ad = n * 64 + (tb ^ swn);
        *(ushort4*)&UT_h[ad] = H;
        *(ushort4*)&UT_l[ad] = L;
      }
    }
    __syncthreads();   // (e) UT ready
    // ---- O += Hq@UT, write out ; S' = cc*S + KT@UT ----
    {
      for (int nt = 0; nt < 2; ++nt) {
        const int n = nt * 16 + lr, swn = (n & 7) << 3;
#pragma unroll
        for (int ks = 0; ks < 2; ++ks) {
          int c = ks * 32 + g16 * 8;
          v8h ah = *(const v8h*)&Hs_h[arow * 64 + (c ^ swa)];
          v8h al = *(const v8h*)&Hs_l[arow * 64 + (c ^ swa)];
          v8h bhh = *(const v8h*)&UT_h[n * 64 + (c ^ swn)];
          v8h bll = *(const v8h*)&UT_l[n * 64 + (c ^ swn)];
          MFMA3(Oacc[nt], ah, al, bhh, bll);
        }
      }
      for (int nt = 0; nt < 2; ++nt) {
        const int n = nt * 16 + lr;
#pragma unroll
        for (int r = 0; r < 4; ++r) {
          int t = t0 + w * 16 + g16 * 4 + r;
          float Ov = Oacc[nt][r] * i2_20;
          float gv = gp[(size_t)t * GW + n];
          out[((size_t)b * 2048 + t) * 4096 + h * 256 + v0 + n] = Ov * (gv / (1.f + expf(-gv)));
        }
      }
      const float cc1024 = cc * 1024.f;
#pragma unroll
      for (int m2 = w * 2; m2 < w * 2 + 2; ++m2) {
        const int ar2 = m2 * 16 + lr, swa2 = (ar2 & 7) << 3;
        const int fb = m2 * 16 + g16 * 4;
        for (int nt = 0; nt < 2; ++nt) {
          const int n = nt * 16 + lr, swn = (n & 7) << 3;
          int sad = n * 128 + (fb ^ swn);
          ushort4 sh4 = *(ushort4*)&St_h[sad];
          ushort4 sl4 = *(ushort4*)&St_l[sad];
          f32x4 acc;
          acc[0] = cc1024 * (h2f(sh4.x) + h2f(sl4.x));
          acc[1] = cc1024 * (h2f(sh4.y) + h2f(sl4.y));
          acc[2] = cc1024 * (h2f(sh4.z) + h2f(sl4.z));
          acc[3] = cc1024 * (h2f(sh4.w) + h2f(sl4.w));
#pragma unroll
          for (int ks = 0; ks < 2; ++ks) {
            int c = ks * 32 + g16 * 8;
            v8h ah = *(const v8h*)&KTs_h[ar2 * 64 + (c ^ swa2)];
            v8h al = *(const v8h*)&KTs_l[ar2 * 64 + (c ^ swa2)];
            v8h bhh = *(const v8h*)&UT_h[n * 64 + (c ^ swn)];
            v8h bll = *(const v8h*)&UT_l[n * 64 + (c ^ swn)];
            MFMA3(acc, ah, al, bhh, bll);
          }
          ushort4 H, L;
          unsigned short* ph = (unsigned short*)&H;
          unsigned short* pl = (unsigned short*)&L;
#pragma unroll
          for (int r = 0; r < 4; ++r) splitw(acc[r] * sscale, ph[r], pl[r]);
          *(ushort4*)&St_h[sad] = H;
          *(ushort4*)&St_l[sad] = L;
        }
      }
    }
    __syncthreads();   // (f) St + staging buffers safe for next chunk
  }
}

extern "C" void kernel_launch(void* const* d_in, const int* in_sizes, int n_in,
                              void* d_out, int out_size, void* d_ws, size_t ws_size,
                              hipStream_t stream) {
  const float* hidden  = (const float*)d_in[0];
  const float* W       = (const float*)d_in[1];
  const float* Wc      = (const float*)d_in[2];
  const float* A_log   = (const float*)d_in[3];
  const float* dt_bias = (const float*)d_in[4];
  float* out = (float*)d_out;

  char* ws = (char*)d_ws;
  // GEMM inputs (dead after GEMM):
  _Float16* Ap = (_Float16*)ws;                       // 33.55MB
  _Float16* Bp = (_Float16*)(ws + (size_t)33554432);  // 101.7MB
  // post-GEMM aliases over [0, 135.27MB):
  _Float16* qh = (_Float16*)ws;                          // 16.78MB
  _Float16* ql = (_Float16*)(ws + (size_t)16777216);
  _Float16* kh = (_Float16*)(ws + (size_t)33554432);
  _Float16* kl = (_Float16*)(ws + (size_t)50331648);
  float* vn    = (float*)(ws + (size_t)67108864);        // 67.11MB
  float* g_arr = (float*)(ws + (size_t)134217728);       // 262KB
  float* beta  = (float*)(ws + (size_t)134479872);       // 262KB, ends 134.74MB
  // [135.27MB, 269.48MB): projQKV -> aliased by chunk tables after conv
  float* projQKV = (float*)(ws + (size_t)135266304);
  char*  tb0 = ws + (size_t)135266304;
  _Float16* Tg_h  = (_Float16*)tb0;
  _Float16* Tg_l  = (_Float16*)(tb0 + (size_t)8388608);
  _Float16* Hg_h  = (_Float16*)(tb0 + (size_t)16777216);
  _Float16* Hg_l  = (_Float16*)(tb0 + (size_t)25165824);
  _Float16* KTg_h = (_Float16*)(tb0 + (size_t)33554432);
  _Float16* KTg_l = (_Float16*)(tb0 + (size_t)50331648);
  float*    coefG = (float*)   (tb0 + (size_t)67108864);
  // [269.48MB, 337.12MB): projGate, live until p2
  float* projGate = (float*)(ws + (size_t)269484032);

  pack_A_k<<<32 * KSTEPS, 256, 0, stream>>>(hidden, Ap);
  pack_B_k<<<NTILE_N * KSTEPS, 256, 0, stream>>>(W, Bp);
  gemm_mfma_k<<<32 * NTILE_N, 256, 0, stream>>>(Ap, Bp, projQKV, projGate);

  conv_qk_k<<<dim3(32, 32, 2), 64, 0, stream>>>(projQKV, Wc, qh, ql, kh, kl);
  conv_v_k<<<dim3(32, 4, 2), 256, 0, stream>>>(projQKV, Wc, vn);
  beta_g_k<<<(2 * NH * L_SEQ + 255) / 256, 256, 0, stream>>>(projGate, A_log, dt_bias, beta, g_arr);

  p1_k<<<1024, 256, 0, stream>>>(kh, kl, qh, ql, g_arr, beta, Tg_h, Tg_l, Hg_h, Hg_l, KTg_h, KTg_l, coefG);
  p2_k<<<256, 256, 0, stream>>>(qh, ql, kh, kl, vn, projGate, Tg_h, Tg_l, Hg_h, Hg_l, KTg_h, KTg_l, coefG, out);
}

// Round 11
// 971.403 us; speedup vs baseline: 4.0366x; 1.0522x over previous
//
#include <hip/hip_runtime.h>
#include <hip/hip_bf16.h>
#include <hip/hip_fp16.h>
#include <math.h>

#define L_SEQ 2048
#define DM    2048
#define NH    16
#define DH    128
#define HVD   256
#define NPROJ 12320
#define QKVW  8192
#define GW    4128

#define NTILE_N 97
#define KSTEPS  64

typedef _Float16 v8h __attribute__((ext_vector_type(8)));
typedef float f32x4 __attribute__((ext_vector_type(4)));

__device__ __forceinline__ void gload_lds16(const void* g, void* l) {
  __builtin_amdgcn_global_load_lds((const __attribute__((address_space(1))) void*)g,
                                   (__attribute__((address_space(3))) void*)l, 16, 0, 0);
}

__device__ __forceinline__ void splitw(float x, unsigned short& h, unsigned short& l) {
  _Float16 hh = (_Float16)x;
  _Float16 ll = (_Float16)(x - (float)hh);
  h = *(unsigned short*)&hh;
  l = *(unsigned short*)&ll;
}
__device__ __forceinline__ float h2f(unsigned short u) {
  return (float)(*(_Float16*)&u);
}

#define MFMA3(acc, ah, al, bh_, bl_)                                          \
  acc = __builtin_amdgcn_mfma_f32_16x16x32_f16(ah, bh_, acc, 0, 0, 0);        \
  acc = __builtin_amdgcn_mfma_f32_16x16x32_f16(ah, bl_, acc, 0, 0, 0);        \
  acc = __builtin_amdgcn_mfma_f32_16x16x32_f16(al, bh_, acc, 0, 0, 0);

// ---------------- pack A: hidden(4096x2048) f32 -> fp16 hi/lo, x16 ----------------
__global__ __launch_bounds__(256) void pack_A_k(const float* __restrict__ H, _Float16* __restrict__ Ap) {
  const int mtile = blockIdx.x >> 6, kstep = blockIdx.x & 63;
  const size_t base = (size_t)blockIdx.x * 2 * 4096;
#pragma unroll
  for (int it = 0; it < 2; ++it) {
    int s = threadIdx.x + it * 256;
    int g = s >> 7, r = s & 127;
    const float* src = H + ((size_t)(mtile * 128 + r)) * 2048 + kstep * 32 + g * 8;
    float4 x0 = *(const float4*)src;
    float4 x1 = *(const float4*)(src + 4);
    float xs[8] = {x0.x, x0.y, x0.z, x0.w, x1.x, x1.y, x1.z, x1.w};
    v8h hi, lo;
#pragma unroll
    for (int j = 0; j < 8; ++j) {
      float v = xs[j] * 16.f;
      _Float16 h = (_Float16)v;
      hi[j] = h;
      lo[j] = (_Float16)(v - (float)h);
    }
    *(v8h*)(Ap + base + g * 1024 + r * 8) = hi;
    *(v8h*)(Ap + base + 4096 + g * 1024 + r * 8) = lo;
  }
}

// ---------------- pack B: W(2048x12320) f32 -> fp16 hi/lo, x1024 ----------------
__global__ __launch_bounds__(256) void pack_B_k(const float* __restrict__ W, _Float16* __restrict__ Bp) {
  const int ntile = blockIdx.x >> 6, kstep = blockIdx.x & 63;
  const size_t base = (size_t)blockIdx.x * 2 * 4096;
#pragma unroll
  for (int it = 0; it < 2; ++it) {
    int s = threadIdx.x + it * 256;
    int g = s >> 7, col = s & 127;
    int n = ntile * 128 + col;
    v8h hi, lo;
#pragma unroll
    for (int j = 0; j < 8; ++j) {
      int k = kstep * 32 + g * 8 + j;
      float v = (n < NPROJ) ? W[(size_t)k * NPROJ + n] * 1024.f : 0.f;
      _Float16 h = (_Float16)v;
      hi[j] = h;
      lo[j] = (_Float16)(v - (float)h);
    }
    *(v8h*)(Bp + base + g * 1024 + col * 8) = hi;
    *(v8h*)(Bp + base + 4096 + g * 1024 + col * 8) = lo;
  }
}

// ---------------- 256x256 split-fp16 MFMA GEMM: 8 waves, BK=32 hi/lo, 1 barrier/K-step ----------------
// Wave tile 128x64 (2M x 4N). LDS 128KB: 2 bufs x [A0 hi|lo][A1 hi|lo][B0 hi|lo][B1 hi|lo] (4096 halfs each).
__global__ __launch_bounds__(512, 2) void gemm256_k(const _Float16* __restrict__ Ap,
                                                    const _Float16* __restrict__ Bp,
                                                    float* __restrict__ Cq,
                                                    float* __restrict__ Cg) {
  __shared__ _Float16 lds[2][32768];
  const int tid = threadIdx.x;
  const int supM = blockIdx.x & 15;
  const int supN = blockIdx.x >> 4;          // 0..47
  const int w = tid >> 6, lane = tid & 63;
  const int wm = w >> 2, wn = w & 3;
  const int lr = lane & 15, g16 = lane >> 4;

  f32x4 acc[8][4];
#pragma unroll
  for (int i = 0; i < 8; ++i)
#pragma unroll
    for (int j = 0; j < 4; ++j) acc[i][j] = (f32x4){0.f, 0.f, 0.f, 0.f};

  const size_t Ab0 = (size_t)(2 * supM) * KSTEPS * 8192;       // halfs
  const size_t Ab1 = Ab0 + (size_t)KSTEPS * 8192;
  const size_t Bb0 = (size_t)(2 * supN) * KSTEPS * 8192;
  const size_t Bb1 = Bb0 + (size_t)KSTEPS * 8192;
  const int so = tid * 8;                                      // 0..4088 halfs

#define STG(KS, BUF)                                                           \
  {                                                                            \
    const size_t ko = (size_t)(KS) * 8192;                                     \
    gload_lds16(Ap + Ab0 + ko + so,        &lds[BUF][so]);                     \
    gload_lds16(Ap + Ab0 + ko + so + 4096, &lds[BUF][so + 4096]);              \
    gload_lds16(Ap + Ab1 + ko + so,        &lds[BUF][8192 + so]);              \
    gload_lds16(Ap + Ab1 + ko + so + 4096, &lds[BUF][8192 + so + 4096]);       \
    gload_lds16(Bp + Bb0 + ko + so,        &lds[BUF][16384 + so]);             \
    gload_lds16(Bp + Bb0 + ko + so + 4096, &lds[BUF][16384 + so + 4096]);      \
    gload_lds16(Bp + Bb1 + ko + so,        &lds[BUF][24576 + so]);             \
    gload_lds16(Bp + Bb1 + ko + so + 4096, &lds[BUF][24576 + so + 4096]);      \
  }

  STG(0, 0);
  asm volatile("s_waitcnt vmcnt(0)" ::: "memory");
  __builtin_amdgcn_sched_barrier(0);
  __builtin_amdgcn_s_barrier();
  __builtin_amdgcn_sched_barrier(0);

  const int aoffB = wm * 8192 + lr * 8 + g16 * 1024;           // + mb*128
  const int boffB = 16384 + (wn >> 1) * 8192 + ((wn & 1) * 64 + lr) * 8 + g16 * 1024;  // + nt*128

  for (int kstep = 0; kstep < KSTEPS; ++kstep) {
    const int p = kstep & 1;
    if (kstep + 1 < KSTEPS) STG(kstep + 1, p ^ 1);

    v8h ah[8], al[8];
#pragma unroll
    for (int mb = 0; mb < 8; ++mb) {
      ah[mb] = *(const v8h*)&lds[p][aoffB + mb * 128];
      al[mb] = *(const v8h*)&lds[p][aoffB + mb * 128 + 4096];
    }
#pragma unroll
    for (int nt = 0; nt < 4; ++nt) {
      v8h bh = *(const v8h*)&lds[p][boffB + nt * 128];
      v8h bl = *(const v8h*)&lds[p][boffB + nt * 128 + 4096];
#pragma unroll
      for (int mb = 0; mb < 8; ++mb) {
        MFMA3(acc[mb][nt], ah[mb], al[mb], bh, bl);
      }
    }
    asm volatile("s_waitcnt vmcnt(0)" ::: "memory");   // next-buf stage landed (covered by MFMA)
    __builtin_amdgcn_sched_barrier(0);
    __builtin_amdgcn_s_barrier();                      // all waves done with buf p
    __builtin_amdgcn_sched_barrier(0);
  }
#undef STG

  const float sc = 1.f / 16384.f;
#pragma unroll
  for (int mb = 0; mb < 8; ++mb) {
#pragma unroll
    for (int nt = 0; nt < 4; ++nt) {
      int col = supN * 256 + wn * 64 + nt * 16 + lr;
#pragma unroll
      for (int r = 0; r < 4; ++r) {
        int row = supM * 256 + wm * 128 + mb * 16 + g16 * 4 + r;
        float v = acc[mb][nt][r] * sc;
        if (col < QKVW) Cq[(size_t)row * QKVW + col] = v;
        else            Cg[(size_t)row * GW + (col - QKVW)] = v;
      }
    }
  }
}

// ---------------- 128x128 tail GEMM (cols of ntile_base..): counted-vmcnt 2-buffer ----------------
__global__ __launch_bounds__(256) void gemm_mfma_k(const _Float16* __restrict__ Ap,
                                                   const _Float16* __restrict__ Bp,
                                                   float* __restrict__ Cq,
                                                   float* __restrict__ Cg,
                                                   int ntile_base) {
  __shared__ _Float16 lds[2][16384];
  const int tid = threadIdx.x;
  const int mtile = blockIdx.x & 31;
  const int ntile = ntile_base + (blockIdx.x >> 5);
  const int wid = tid >> 6, lane = tid & 63;
  const int wm = wid >> 1, wn = wid & 1;
  const int lrow = lane & 15, g = lane >> 4;

  f32x4 acc[4][4];
#pragma unroll
  for (int i = 0; i < 4; ++i)
#pragma unroll
    for (int j = 0; j < 4; ++j) acc[i][j] = (f32x4){0.f, 0.f, 0.f, 0.f};

  const int aoff = (wm * 64 + lrow) * 8 + g * 1024;
  const int boff = (wn * 64 + lrow) * 8 + g * 1024;

  const _Float16* Asrc = Ap + ((size_t)(mtile * KSTEPS) * 2) * 4096 + tid * 8;
  const _Float16* Bsrc = Bp + ((size_t)(ntile * KSTEPS) * 2) * 4096 + tid * 8;

#define STAGE(KS, BUF)                                                         \
  {                                                                            \
    const _Float16* An_ = Asrc + (size_t)(KS) * 8192;                          \
    const _Float16* Bn_ = Bsrc + (size_t)(KS) * 8192;                          \
    _Pragma("unroll")                                                          \
    for (int r = 0; r < 4; ++r) {                                              \
      gload_lds16(An_ + r * 2048, &lds[BUF][r * 2048 + tid * 8]);              \
      gload_lds16(Bn_ + r * 2048, &lds[BUF][8192 + r * 2048 + tid * 8]);       \
    }                                                                          \
  }

  STAGE(0, 0);
  STAGE(1, 1);

  for (int kstep = 0; kstep < KSTEPS; ++kstep) {
    const int p = kstep & 1;
    if (kstep + 1 < KSTEPS) {
      asm volatile("s_waitcnt vmcnt(8)" ::: "memory");
    } else {
      asm volatile("s_waitcnt vmcnt(0)" ::: "memory");
    }
    __builtin_amdgcn_sched_barrier(0);
    __builtin_amdgcn_s_barrier();
    __builtin_amdgcn_sched_barrier(0);

    v8h ah[4], al[4], bh[4], bl[4];
#pragma unroll
    for (int f = 0; f < 4; ++f) {
      ah[f] = *(const v8h*)&lds[p][aoff + f * 128];
      al[f] = *(const v8h*)&lds[p][4096 + aoff + f * 128];
      bh[f] = *(const v8h*)&lds[p][8192 + boff + f * 128];
      bl[f] = *(const v8h*)&lds[p][12288 + boff + f * 128];
    }
#pragma unroll
    for (int fm = 0; fm < 4; ++fm)
#pragma unroll
      for (int fn = 0; fn < 4; ++fn) {
        acc[fm][fn] = __builtin_amdgcn_mfma_f32_16x16x32_f16(ah[fm], bh[fn], acc[fm][fn], 0, 0, 0);
        acc[fm][fn] = __builtin_amdgcn_mfma_f32_16x16x32_f16(ah[fm], bl[fn], acc[fm][fn], 0, 0, 0);
        acc[fm][fn] = __builtin_amdgcn_mfma_f32_16x16x32_f16(al[fm], bh[fn], acc[fm][fn], 0, 0, 0);
      }
    __builtin_amdgcn_sched_barrier(0);
    __builtin_amdgcn_s_barrier();
    __builtin_amdgcn_sched_barrier(0);
    if (kstep + 2 < KSTEPS) STAGE(kstep + 2, p);
  }
#undef STAGE

  const float sc = 1.f / 16384.f;
#pragma unroll
  for (int fm = 0; fm < 4; ++fm) {
    int row = mtile * 128 + wm * 64 + fm * 16 + g * 4;
#pragma unroll
    for (int fn = 0; fn < 4; ++fn) {
      int col = ntile * 128 + wn * 64 + fn * 16 + lrow;
      if (col < QKVW) {
#pragma unroll
        for (int r = 0; r < 4; ++r)
          Cq[(size_t)(row + r) * QKVW + col] = acc[fm][fn][r] * sc;
      } else if (col < NPROJ) {
        int lcol = col - QKVW;
#pragma unroll
        for (int r = 0; r < 4; ++r)
          Cg[(size_t)(row + r) * GW + lcol] = acc[fm][fn][r] * sc;
      }
    }
  }
}

// ------------- conv+silu+l2norm for q/k -> PRE-SPLIT fp16 hi/lo, pre-swizzled table layout -------------
__global__ __launch_bounds__(64) void conv_qk_k(
    const float* __restrict__ projQKV, const float* __restrict__ Wc,
    _Float16* __restrict__ qh, _Float16* __restrict__ ql,
    _Float16* __restrict__ kh, _Float16* __restrict__ kl)
{
  const int b = blockIdx.z, hg = blockIdx.y, tc = blockIdx.x;
  const int lane = threadIdx.x;
  const int ch = hg * 128 + lane * 2;
  float4 Wa = *(const float4*)(Wc + (size_t)ch * 4);
  float4 Wb = *(const float4*)(Wc + (size_t)ch * 4 + 4);
  const int t0 = tc * 64;
  const float* P = projQKV + (size_t)b * L_SEQ * QKVW + ch;
  float2 w0 = make_float2(0.f, 0.f), w1 = w0, w2 = w0;
  if (t0 >= 3) w0 = *(const float2*)(P + (size_t)(t0 - 3) * QKVW);
  if (t0 >= 2) w1 = *(const float2*)(P + (size_t)(t0 - 2) * QKVW);
  if (t0 >= 1) w2 = *(const float2*)(P + (size_t)(t0 - 1) * QKVW);
  const bool isq = hg < 16;
  const int h = isq ? hg : hg - 16;
  _Float16* dh = (isq ? qh : kh) + (((size_t)b * NH + h) * L_SEQ) * 128;
  _Float16* dl = (isq ? ql : kl) + (((size_t)b * NH + h) * L_SEQ) * 128;
  const float sc = (isq ? 0.08838834764831845f : 1.f) * 1024.f;
  for (int t = t0; t < t0 + 64; ++t) {
    float2 x = *(const float2*)(P + (size_t)t * QKVW);
    float y0 = w0.x * Wa.x + w1.x * Wa.y + w2.x * Wa.z + x.x * Wa.w;
    float y1 = w0.y * Wb.x + w1.y * Wb.y + w2.y * Wb.z + x.y * Wb.w;
    w0 = w1; w1 = w2; w2 = x;
    y0 = y0 / (1.f + expf(-y0));
    y1 = y1 / (1.f + expf(-y1));
    float ss = y0 * y0 + y1 * y1;
#pragma unroll
    for (int off = 1; off < 64; off <<= 1) ss += __shfl_xor(ss, off);
    float nrm = sc / sqrtf(ss + 1e-6f);
    unsigned short h0, l0, h1, l1;
    splitw(y0 * nrm, h0, l0);
    splitw(y1 * nrm, h1, l1);
    int idx = t * 128 + ((lane * 2) ^ ((t & 7) << 3));
    *(unsigned int*)&dh[idx] = (unsigned int)h0 | ((unsigned int)h1 << 16);
    *(unsigned int*)&dl[idx] = (unsigned int)l0 | ((unsigned int)l1 << 16);
  }
}

// ------------- conv+silu for v: elementwise, float4 per thread -------------
__global__ __launch_bounds__(256) void conv_v_k(
    const float* __restrict__ projQKV, const float* __restrict__ Wc,
    float* __restrict__ vn)
{
  const int b = blockIdx.z, cg = blockIdx.y, tc = blockIdx.x;
  const int vc = (cg * 256 + threadIdx.x) * 4;
  const int ch = 4096 + vc;
  float4 Wv0 = *(const float4*)(Wc + (size_t)ch * 4);
  float4 Wv1 = *(const float4*)(Wc + (size_t)ch * 4 + 4);
  float4 Wv2 = *(const float4*)(Wc + (size_t)ch * 4 + 8);
  float4 Wv3 = *(const float4*)(Wc + (size_t)ch * 4 + 12);
  const int t0 = tc * 64;
  const float* P = projQKV + (size_t)b * L_SEQ * QKVW + ch;
  float4 w0 = make_float4(0.f, 0.f, 0.f, 0.f), w1 = w0, w2 = w0;
  if (t0 >= 3) w0 = *(const float4*)(P + (size_t)(t0 - 3) * QKVW);
  if (t0 >= 2) w1 = *(const float4*)(P + (size_t)(t0 - 2) * QKVW);
  if (t0 >= 1) w2 = *(const float4*)(P + (size_t)(t0 - 1) * QKVW);
  const int h = vc >> 8, vcol = vc & 255;
  float* dst = vn + (((size_t)b * NH + h) * L_SEQ) * HVD + vcol;
  for (int t = t0; t < t0 + 64; ++t) {
    float4 x = *(const float4*)(P + (size_t)t * QKVW);
    float4 y;
    y.x = w0.x * Wv0.x + w1.x * Wv0.y + w2.x * Wv0.z + x.x * Wv0.w;
    y.y = w0.y * Wv1.x + w1.y * Wv1.y + w2.y * Wv1.z + x.y * Wv1.w;
    y.z = w0.z * Wv2.x + w1.z * Wv2.y + w2.z * Wv2.z + x.z * Wv2.w;
    y.w = w0.w * Wv3.x + w1.w * Wv3.y + w2.w * Wv3.z + x.w * Wv3.w;
    w0 = w1; w1 = w2; w2 = x;
    y.x = y.x / (1.f + expf(-y.x));
    y.y = y.y / (1.f + expf(-y.y));
    y.z = y.z / (1.f + expf(-y.z));
    y.w = y.w / (1.f + expf(-y.w));
    *(float4*)(dst + (size_t)t * HVD) = y;
  }
}

// ------------- beta = sigmoid(b), g = -exp(A_log)*softplus(A+dt_bias) -------------
__global__ __launch_bounds__(256) void beta_g_k(
    const float* __restrict__ projGate, const float* __restrict__ A_log,
    const float* __restrict__ dt_bias, float* __restrict__ beta, float* __restrict__ g_out)
{
  int idx = blockIdx.x * 256 + threadIdx.x;
  if (idx >= 2 * NH * L_SEQ) return;
  int t = idx & (L_SEQ - 1);
  int h = (idx >> 11) & (NH - 1);
  int b = idx >> 15;
  size_t row = (size_t)(b * L_SEQ + t) * GW;
  float bv = projGate[row + 4096 + h];
  float av = projGate[row + 4112 + h];
  float be = 1.f / (1.f + expf(-bv));
  float xx = av + dt_bias[h];
  float sp = (xx > 20.f) ? xx : log1pf(expf(xx));
  float g = -expf(A_log[h]) * sp;
  beta[idx] = be;
  g_out[idx] = g;
}

// ------------- Phase 1 (fused): T=(I+A)^-1, Hq, KT, coef — gload-staged pre-split q/k -------------
__global__ __launch_bounds__(256) void p1_k(
    const _Float16* __restrict__ kh_g, const _Float16* __restrict__ kl_g,
    const _Float16* __restrict__ qh_g, const _Float16* __restrict__ ql_g,
    const float* __restrict__ g_arr, const float* __restrict__ beta_arr,
    _Float16* __restrict__ Tg_h, _Float16* __restrict__ Tg_l,
    _Float16* __restrict__ Hg_h, _Float16* __restrict__ Hg_l,
    _Float16* __restrict__ KTg_h, _Float16* __restrict__ KTg_l,
    float* __restrict__ coefG)
{
  __shared__ _Float16 Kh[8192], Kl[8192];
  __shared__ _Float16 QS[16384];
  __shared__ float lc[64], be[64], kw[64];
  _Float16* Qh = QS;
  _Float16* Ql = QS + 8192;
  float* Am = (float*)QS;
  float* Tm = Am + 4096;
  const int cid = blockIdx.x, bh = cid >> 5, ch = cid & 31, t0 = ch * 64;
  const int tid = threadIdx.x, w = tid >> 6, lane = tid & 63, lr = lane & 15, g16 = lane >> 4;

  const size_t gb = ((size_t)bh * 2048 + t0) * 128;
#pragma unroll
  for (int l = 0; l < 4; ++l) {
    int i = (tid + l * 256) * 8;
    gload_lds16(kh_g + gb + i, &Kh[i]);
    gload_lds16(kl_g + gb + i, &Kl[i]);
    gload_lds16(qh_g + gb + i, &Qh[i]);
    gload_lds16(ql_g + gb + i, &Ql[i]);
  }
  if (tid < 64) {
    float x = g_arr[(size_t)bh * 2048 + t0 + tid];
#pragma unroll
    for (int off = 1; off < 64; off <<= 1) { float y = __shfl_up(x, off); if (tid >= off) x += y; }
    lc[tid] = x;
    float x63 = __shfl(x, 63);
    float b_ = beta_arr[(size_t)bh * 2048 + t0 + tid];
    be[tid] = b_;
    kw[tid] = expf(x63 - x);
    float ca = expf(x);
    coefG[(size_t)cid * 192 + tid] = ca;
    coefG[(size_t)cid * 192 + 64 + tid] = b_;
    coefG[(size_t)cid * 192 + 128 + tid] = b_ * ca;
  }
  __syncthreads();
  const float ds20 = 1.f / 1048576.f;
  const int arow = w * 16 + lr, swa = (arow & 7) << 3;
  f32x4 gacc[4];
  for (int nt = 0; nt < 4; ++nt) {
    f32x4 acc = (f32x4){0.f, 0.f, 0.f, 0.f};
    int nrow = nt * 16 + lr, swn = (nrow & 7) << 3;
#pragma unroll
    for (int ks = 0; ks < 4; ++ks) {
      int c = ks * 32 + g16 * 8;
      v8h ah = *(const v8h*)&Kh[arow * 128 + (c ^ swa)];
      v8h al = *(const v8h*)&Kl[arow * 128 + (c ^ swa)];
      v8h bhh = *(const v8h*)&Kh[nrow * 128 + (c ^ swn)];
      v8h bll = *(const v8h*)&Kl[nrow * 128 + (c ^ swn)];
      MFMA3(acc, ah, al, bhh, bll);
    }
    gacc[nt] = acc;
  }
  for (int nt = 0; nt < 4; ++nt) {
    f32x4 acc = (f32x4){0.f, 0.f, 0.f, 0.f};
    int nrow = nt * 16 + lr, swn = (nrow & 7) << 3;
#pragma unroll
    for (int ks = 0; ks < 4; ++ks) {
      int c = ks * 32 + g16 * 8;
      v8h ah = *(const v8h*)&Qh[arow * 128 + (c ^ swa)];
      v8h al = *(const v8h*)&Ql[arow * 128 + (c ^ swa)];
      v8h bhh = *(const v8h*)&Kh[nrow * 128 + (c ^ swn)];
      v8h bll = *(const v8h*)&Kl[nrow * 128 + (c ^ swn)];
      MFMA3(acc, ah, al, bhh, bll);
    }
    int s_ = nt * 16 + lr;
#pragma unroll
    for (int r = 0; r < 4; ++r) {
      int t = w * 16 + g16 * 4 + r;
      float hv = (s_ <= t) ? acc[r] * ds20 * expf(lc[t] - lc[s_]) : 0.f;
      unsigned short hh, ll; splitw(hv * 16384.f, hh, ll);
      size_t go = (size_t)cid * 4096 + t * 64 + (s_ ^ ((t & 7) << 3));
      *(unsigned short*)&Hg_h[go] = hh;
      *(unsigned short*)&Hg_l[go] = ll;
    }
  }
  __syncthreads();
  for (int nt = 0; nt < 4; ++nt) {
    int s_ = nt * 16 + lr;
#pragma unroll
    for (int r = 0; r < 4; ++r) {
      int t = w * 16 + g16 * 4 + r;
      float av = (s_ < t) ? gacc[nt][r] * ds20 * be[t] * expf(lc[t] - lc[s_]) : 0.f;
      Am[t * 64 + s_] = av;
    }
  }
#pragma unroll
  for (int l = 0; l < 16; ++l) { int s2 = tid + l * 256; Tm[s2] = ((s2 >> 6) == (s2 & 63)) ? 1.f : 0.f; }
  for (int s = tid; s < 8192; s += 256) {
    int feat = s >> 6, t = s & 63;
    int ki = t * 128 + (feat ^ ((t & 7) << 3));
    float kvv = ((float)Kh[ki] + (float)Kl[ki]) * kw[t];
    unsigned short hh, ll; splitw(kvv, hh, ll);
    size_t go = (size_t)cid * 8192 + feat * 64 + (t ^ ((feat & 7) << 3));
    *(unsigned short*)&KTg_h[go] = hh;
    *(unsigned short*)&KTg_l[go] = ll;
  }
  __syncthreads();
  if (w == 0) {
    int j = lane;
    for (int t = 1; t < 64; ++t) {
      float sum = 0.f;
      for (int s = 0; s < t; ++s) sum = fmaf(Am[t * 64 + s], Tm[s * 64 + j], sum);
      Tm[t * 64 + j] = ((j == t) ? 1.f : 0.f) - sum;
    }
  }
  __syncthreads();
#pragma unroll
  for (int l = 0; l < 16; ++l) {
    int s2 = tid + l * 256;
    int t = s2 >> 6, sc_ = s2 & 63;
    unsigned short hh, ll; splitw(Tm[s2] * 256.f, hh, ll);
    size_t go = (size_t)cid * 4096 + t * 64 + (sc_ ^ ((t & 7) << 3));
    *(unsigned short*)&Tg_h[go] = hh;
    *(unsigned short*)&Tg_l[go] = ll;
  }
}

// ------------- Phase 2: sequential chunk scan, VW=32, 256 blocks, 5 barriers/chunk -------------
__global__ __launch_bounds__(256) void p2_k(
    const _Float16* __restrict__ qh_g, const _Float16* __restrict__ ql_g,
    const _Float16* __restrict__ kh_g, const _Float16* __restrict__ kl_g,
    const float* __restrict__ vn, const float* __restrict__ projGate,
    const _Float16* __restrict__ Tg_h, const _Float16* __restrict__ Tg_l,
    const _Float16* __restrict__ Hg_h, const _Float16* __restrict__ Hg_l,
    const _Float16* __restrict__ KTg_h, const _Float16* __restrict__ KTg_l,
    const float* __restrict__ coefG, float* __restrict__ out)
{
  __shared__ _Float16 St_h[4096], St_l[4096];
  __shared__ _Float16 KQ0[8192], KQ1[8192];
  __shared__ _Float16 KK0[8192], KK1[8192];
  __shared__ _Float16 KTs_h[8192], KTs_l[8192];
  __shared__ _Float16 Ts_h[4096], Ts_l[4096];
  __shared__ _Float16 Hs_h[4096], Hs_l[4096];
  __shared__ float cf[192];

  const int blk = blockIdx.x;
  const int vb = blk >> 5, bh = blk & 31;
  const int b = bh >> 4, h = bh & 15, v0 = vb * 32;
  const int tid = threadIdx.x, w = tid >> 6, lane = tid & 63, lr = lane & 15, g16 = lane >> 4;

  _Float16* BT_h = &KQ0[0];
  _Float16* BT_l = &KQ0[4096];
  _Float16* UT_h = &KQ1[0];
  _Float16* UT_l = &KQ1[4096];

#pragma unroll
  for (int l = 0; l < 8; ++l) { ((unsigned int*)St_h)[tid + l * 256] = 0u; }
#pragma unroll
  for (int l = 0; l < 8; ++l) { ((unsigned int*)St_l)[tid + l * 256] = 0u; }

  const float* gp = projGate + ((size_t)b * 2048) * GW + h * 256 + v0;
  const float i2_16 = 1.f / 65536.f;
  const float i2_20 = 1.f / 1048576.f;
  const float uscale = 1.f / 256.f;
  const float sscale = 64.f / 65536.f;

  for (int ch = 0; ch < 32; ++ch) {
    const int cid = bh * 32 + ch, t0 = ch * 64;
    {
      const _Float16* th = Tg_h + (size_t)cid * 4096;
      const _Float16* tl = Tg_l + (size_t)cid * 4096;
      const _Float16* hh = Hg_h + (size_t)cid * 4096;
      const _Float16* hl = Hg_l + (size_t)cid * 4096;
      const _Float16* kth = KTg_h + (size_t)cid * 8192;
      const _Float16* ktl = KTg_l + (size_t)cid * 8192;
      const size_t gb = ((size_t)bh * 2048 + t0) * 128;
#pragma unroll
      for (int l = 0; l < 2; ++l) {
        int i = (tid + l * 256) * 8;
        gload_lds16(th + i, &Ts_h[i]);
        gload_lds16(tl + i, &Ts_l[i]);
        gload_lds16(hh + i, &Hs_h[i]);
        gload_lds16(hl + i, &Hs_l[i]);
      }
#pragma unroll
      for (int l = 0; l < 4; ++l) {
        int i = (tid + l * 256) * 8;
        gload_lds16(kth + i, &KTs_h[i]);
        gload_lds16(ktl + i, &KTs_l[i]);
        gload_lds16(qh_g + gb + i, &KQ0[i]);
        gload_lds16(ql_g + gb + i, &KQ1[i]);
        gload_lds16(kh_g + gb + i, &KK0[i]);
        gload_lds16(kl_g + gb + i, &KK1[i]);
      }
      if (tid < 48) gload_lds16(coefG + (size_t)cid * 192 + tid * 4, &cf[tid * 4]);
    }
    float Vv[2][4];
#pragma unroll
    for (int nt = 0; nt < 2; ++nt)
#pragma unroll
      for (int r = 0; r < 4; ++r)
        Vv[nt][r] = vn[((size_t)bh * 2048 + t0 + w * 16 + g16 * 4 + r) * 256 + v0 + nt * 16 + lr];
    __syncthreads();
    const float cc = cf[63];
    const int arow = w * 16 + lr, swa = (arow & 7) << 3;
    f32x4 Oacc[2];
    {
      for (int nt = 0; nt < 2; ++nt) {
        f32x4 acc = (f32x4){0.f, 0.f, 0.f, 0.f};
        const int n = nt * 16 + lr, swn = (n & 7) << 3;
#pragma unroll
        for (int ks = 0; ks < 4; ++ks) {
          int c = ks * 32 + g16 * 8;
          v8h ah = *(const v8h*)&KQ0[arow * 128 + (c ^ swa)];
          v8h al = *(const v8h*)&KQ1[arow * 128 + (c ^ swa)];
          v8h bhh = *(const v8h*)&St_h[n * 128 + (c ^ swn)];
          v8h bll = *(const v8h*)&St_l[n * 128 + (c ^ swn)];
          MFMA3(acc, ah, al, bhh, bll);
        }
        Oacc[nt] = acc;
      }
      float4 cav = *(float4*)&cf[w * 16 + g16 * 4];
#pragma unroll
      for (int nt = 0; nt < 2; ++nt) {
        Oacc[nt][0] *= cav.x * 16.f; Oacc[nt][1] *= cav.y * 16.f;
        Oacc[nt][2] *= cav.z * 16.f; Oacc[nt][3] *= cav.w * 16.f;
      }
    }
    ushort4 pBh[2], pBl[2];
    {
      float4 cb1v = *(float4*)&cf[64 + w * 16 + g16 * 4];
      float4 cb2v = *(float4*)&cf[128 + w * 16 + g16 * 4];
      for (int nt = 0; nt < 2; ++nt) {
        f32x4 acc = (f32x4){0.f, 0.f, 0.f, 0.f};
        const int n = nt * 16 + lr, swn = (n & 7) << 3;
#pragma unroll
        for (int ks = 0; ks < 4; ++ks) {
          int c = ks * 32 + g16 * 8;
          v8h ah = *(const v8h*)&KK0[arow * 128 + (c ^ swa)];
          v8h al = *(const v8h*)&KK1[arow * 128 + (c ^ swa)];
          v8h bhh = *(const v8h*)&St_h[n * 128 + (c ^ swn)];
          v8h bll = *(const v8h*)&St_l[n * 128 + (c ^ swn)];
          MFMA3(acc, ah, al, bhh, bll);
        }
        float cb1a[4] = {cb1v.x, cb1v.y, cb1v.z, cb1v.w};
        float cb2a[4] = {cb2v.x, cb2v.y, cb2v.z, cb2v.w};
        unsigned short* ph = (unsigned short*)&pBh[nt];
        unsigned short* pl = (unsigned short*)&pBl[nt];
#pragma unroll
        for (int r = 0; r < 4; ++r) {
          float kv = acc[r] * i2_16;
          float Bv = cb1a[r] * Vv[nt][r] - cb2a[r] * kv;
          splitw(Bv * 64.f, ph[r], pl[r]);
        }
      }
    }
    __syncthreads();
    {
      const int tb = w * 16 + g16 * 4;
      for (int nt = 0; nt < 2; ++nt) {
        const int n = nt * 16 + lr, swn = (n & 7) << 3;
        int ad = n * 64 + (tb ^ swn);
        *(ushort4*)&BT_h[ad] = pBh[nt];
        *(ushort4*)&BT_l[ad] = pBl[nt];
      }
    }
    __syncthreads();
    {
      const int tb = w * 16 + g16 * 4;
      for (int nt = 0; nt < 2; ++nt) {
        f32x4 acc = (f32x4){0.f, 0.f, 0.f, 0.f};
        const int n = nt * 16 + lr, swn = (n & 7) << 3;
#pragma unroll
        for (int ks = 0; ks < 2; ++ks) {
          int c = ks * 32 + g16 * 8;
          v8h ah = *(const v8h*)&Ts_h[arow * 64 + (c ^ swa)];
          v8h al = *(const v8h*)&Ts_l[arow * 64 + (c ^ swa)];
          v8h bhh = *(const v8h*)&BT_h[n * 64 + (c ^ swn)];
          v8h bll = *(const v8h*)&BT_l[n * 64 + (c ^ swn)];
          MFMA3(acc, ah, al, bhh, bll);
        }
        ushort4 H, L;
        unsigned short* ph = (unsigned short*)&H;
        unsigned short* pl = (unsigned short*)&L;
#pragma unroll
        for (int r = 0; r < 4; ++r) splitw(acc[r] * uscale, ph[r], pl[r]);
        int ad = n * 64 + (tb ^ swn);
        *(ushort4*)&UT_h[ad] = H;
        *(ushort4*)&UT_l[ad] = L;
      }
    }
    __syncthreads();
    {
      for (int nt = 0; nt < 2; ++nt) {
        const int n = nt * 16 + lr, swn = (n & 7) << 3;
#pragma unroll
        for (int ks = 0; ks < 2; ++ks) {
          int c = ks * 32 + g16 * 8;
          v8h ah = *(const v8h*)&Hs_h[arow * 64 + (c ^ swa)];
          v8h al = *(const v8h*)&Hs_l[arow * 64 + (c ^ swa)];
          v8h bhh = *(const v8h*)&UT_h[n * 64 + (c ^ swn)];
          v8h bll = *(const v8h*)&UT_l[n * 64 + (c ^ swn)];
          MFMA3(Oacc[nt], ah, al, bhh, bll);
        }
      }
      for (int nt = 0; nt < 2; ++nt) {
        const int n = nt * 16 + lr;
#pragma unroll
        for (int r = 0; r < 4; ++r) {
          int t = t0 + w * 16 + g16 * 4 + r;
          float Ov = Oacc[nt][r] * i2_20;
          float gv = gp[(size_t)t * GW + n];
          out[((size_t)b * 2048 + t) * 4096 + h * 256 + v0 + n] = Ov * (gv / (1.f + expf(-gv)));
        }
      }
      const float cc1024 = cc * 1024.f;
#pragma unroll
      for (int m2 = w * 2; m2 < w * 2 + 2; ++m2) {
        const int ar2 = m2 * 16 + lr, swa2 = (ar2 & 7) << 3;
        const int fb = m2 * 16 + g16 * 4;
        for (int nt = 0; nt < 2; ++nt) {
          const int n = nt * 16 + lr, swn = (n & 7) << 3;
          int sad = n * 128 + (fb ^ swn);
          ushort4 sh4 = *(ushort4*)&St_h[sad];
          ushort4 sl4 = *(ushort4*)&St_l[sad];
          f32x4 acc;
          acc[0] = cc1024 * (h2f(sh4.x) + h2f(sl4.x));
          acc[1] = cc1024 * (h2f(sh4.y) + h2f(sl4.y));
          acc[2] = cc1024 * (h2f(sh4.z) + h2f(sl4.z));
          acc[3] = cc1024 * (h2f(sh4.w) + h2f(sl4.w));
#pragma unroll
          for (int ks = 0; ks < 2; ++ks) {
            int c = ks * 32 + g16 * 8;
            v8h ah = *(const v8h*)&KTs_h[ar2 * 64 + (c ^ swa2)];
            v8h al = *(const v8h*)&KTs_l[ar2 * 64 + (c ^ swa2)];
            v8h bhh = *(const v8h*)&UT_h[n * 64 + (c ^ swn)];
            v8h bll = *(const v8h*)&UT_l[n * 64 + (c ^ swn)];
            MFMA3(acc, ah, al, bhh, bll);
          }
          ushort4 H, L;
          unsigned short* ph = (unsigned short*)&H;
          unsigned short* pl = (unsigned short*)&L;
#pragma unroll
          for (int r = 0; r < 4; ++r) splitw(acc[r] * sscale, ph[r], pl[r]);
          *(ushort4*)&St_h[sad] = H;
          *(ushort4*)&St_l[sad] = L;
        }
      }
    }
    __syncthreads();
  }
}

extern "C" void kernel_launch(void* const* d_in, const int* in_sizes, int n_in,
                              void* d_out, int out_size, void* d_ws, size_t ws_size,
                              hipStream_t stream) {
  const float* hidden  = (const float*)d_in[0];
  const float* W       = (const float*)d_in[1];
  const float* Wc      = (const float*)d_in[2];
  const float* A_log   = (const float*)d_in[3];
  const float* dt_bias = (const float*)d_in[4];
  float* out = (float*)d_out;

  char* ws = (char*)d_ws;
  _Float16* Ap = (_Float16*)ws;
  _Float16* Bp = (_Float16*)(ws + (size_t)33554432);
  _Float16* qh = (_Float16*)ws;
  _Float16* ql = (_Float16*)(ws + (size_t)16777216);
  _Float16* kh = (_Float16*)(ws + (size_t)33554432);
  _Float16* kl = (_Float16*)(ws + (size_t)50331648);
  float* vn    = (float*)(ws + (size_t)67108864);
  float* g_arr = (float*)(ws + (size_t)134217728);
  float* beta  = (float*)(ws + (size_t)134479872);
  float* projQKV = (float*)(ws + (size_t)135266304);
  char*  tb0 = ws + (size_t)135266304;
  _Float16* Tg_h  = (_Float16*)tb0;
  _Float16* Tg_l  = (_Float16*)(tb0 + (size_t)8388608);
  _Float16* Hg_h  = (_Float16*)(tb0 + (size_t)16777216);
  _Float16* Hg_l  = (_Float16*)(tb0 + (size_t)25165824);
  _Float16* KTg_h = (_Float16*)(tb0 + (size_t)33554432);
  _Float16* KTg_l = (_Float16*)(tb0 + (size_t)50331648);
  float*    coefG = (float*)   (tb0 + (size_t)67108864);
  float* projGate = (float*)(ws + (size_t)269484032);

  pack_A_k<<<32 * KSTEPS, 256, 0, stream>>>(hidden, Ap);
  pack_B_k<<<NTILE_N * KSTEPS, 256, 0, stream>>>(W, Bp);
  // main 256x256 GEMM over ntiles 0..95, plus 128-wide tail for ntile 96
  gemm256_k<<<16 * 48, 512, 0, stream>>>(Ap, Bp, projQKV, projGate);
  gemm_mfma_k<<<32, 256, 0, stream>>>(Ap, Bp, projQKV, projGate, 96);

  conv_qk_k<<<dim3(32, 32, 2), 64, 0, stream>>>(projQKV, Wc, qh, ql, kh, kl);
  conv_v_k<<<dim3(32, 4, 2), 256, 0, stream>>>(projQKV, Wc, vn);
  beta_g_k<<<(2 * NH * L_SEQ + 255) / 256, 256, 0, stream>>>(projGate, A_log, dt_bias, beta, g_arr);

  p1_k<<<1024, 256, 0, stream>>>(kh, kl, qh, ql, g_arr, beta, Tg_h, Tg_l, Hg_h, Hg_l, KTg_h, KTg_l, coefG);
  p2_k<<<256, 256, 0, stream>>>(qh, ql, kh, kl, vn, projGate, Tg_h, Tg_l, Hg_h, Hg_l, KTg_h, KTg_l, coefG, out);
}

// Round 12
// 966.988 us; speedup vs baseline: 4.0551x; 1.0046x over previous
//
#include <hip/hip_runtime.h>
#include <hip/hip_bf16.h>
#include <hip/hip_fp16.h>
#include <math.h>

#define L_SEQ 2048
#define DM    2048
#define NH    16
#define DH    128
#define HVD   256
#define NPROJ 12320
#define QKVW  8192
#define GW    4128

#define NTILE_N 97
#define KSTEPS  64

typedef _Float16 v8h __attribute__((ext_vector_type(8)));
typedef float f32x4 __attribute__((ext_vector_type(4)));

__device__ __forceinline__ void gload_lds16(const void* g, void* l) {
  __builtin_amdgcn_global_load_lds((const __attribute__((address_space(1))) void*)g,
                                   (__attribute__((address_space(3))) void*)l, 16, 0, 0);
}

__device__ __forceinline__ void splitw(float x, unsigned short& h, unsigned short& l) {
  _Float16 hh = (_Float16)x;
  _Float16 ll = (_Float16)(x - (float)hh);
  h = *(unsigned short*)&hh;
  l = *(unsigned short*)&ll;
}
__device__ __forceinline__ float h2f(unsigned short u) {
  return (float)(*(_Float16*)&u);
}

#define MFMA3(acc, ah, al, bh_, bl_)                                          \
  acc = __builtin_amdgcn_mfma_f32_16x16x32_f16(ah, bh_, acc, 0, 0, 0);        \
  acc = __builtin_amdgcn_mfma_f32_16x16x32_f16(ah, bl_, acc, 0, 0, 0);        \
  acc = __builtin_amdgcn_mfma_f32_16x16x32_f16(al, bh_, acc, 0, 0, 0);

// ---------------- pack A: hidden(4096x2048) f32 -> fp16 hi/lo, x16 ----------------
__global__ __launch_bounds__(256) void pack_A_k(const float* __restrict__ H, _Float16* __restrict__ Ap) {
  const int mtile = blockIdx.x >> 6, kstep = blockIdx.x & 63;
  const size_t base = (size_t)blockIdx.x * 2 * 4096;
#pragma unroll
  for (int it = 0; it < 2; ++it) {
    int s = threadIdx.x + it * 256;
    int g = s >> 7, r = s & 127;
    const float* src = H + ((size_t)(mtile * 128 + r)) * 2048 + kstep * 32 + g * 8;
    float4 x0 = *(const float4*)src;
    float4 x1 = *(const float4*)(src + 4);
    float xs[8] = {x0.x, x0.y, x0.z, x0.w, x1.x, x1.y, x1.z, x1.w};
    v8h hi, lo;
#pragma unroll
    for (int j = 0; j < 8; ++j) {
      float v = xs[j] * 16.f;
      _Float16 h = (_Float16)v;
      hi[j] = h;
      lo[j] = (_Float16)(v - (float)h);
    }
    *(v8h*)(Ap + base + g * 1024 + r * 8) = hi;
    *(v8h*)(Ap + base + 4096 + g * 1024 + r * 8) = lo;
  }
}

// ---------------- pack B: W(2048x12320) f32 -> fp16 hi/lo, x1024 ----------------
__global__ __launch_bounds__(256) void pack_B_k(const float* __restrict__ W, _Float16* __restrict__ Bp) {
  const int ntile = blockIdx.x >> 6, kstep = blockIdx.x & 63;
  const size_t base = (size_t)blockIdx.x * 2 * 4096;
#pragma unroll
  for (int it = 0; it < 2; ++it) {
    int s = threadIdx.x + it * 256;
    int g = s >> 7, col = s & 127;
    int n = ntile * 128 + col;
    v8h hi, lo;
#pragma unroll
    for (int j = 0; j < 8; ++j) {
      int k = kstep * 32 + g * 8 + j;
      float v = (n < NPROJ) ? W[(size_t)k * NPROJ + n] * 1024.f : 0.f;
      _Float16 h = (_Float16)v;
      hi[j] = h;
      lo[j] = (_Float16)(v - (float)h);
    }
    *(v8h*)(Bp + base + g * 1024 + col * 8) = hi;
    *(v8h*)(Bp + base + 4096 + g * 1024 + col * 8) = lo;
  }
}

// ---------------- merged GEMM: bid<768 -> 256x256 8-wave main; bid>=768 -> dual-128x128 tail ----------------
__global__ __launch_bounds__(512, 2) void gemm256_k(const _Float16* __restrict__ Ap,
                                                    const _Float16* __restrict__ Bp,
                                                    float* __restrict__ Cq,
                                                    float* __restrict__ Cg) {
  __shared__ _Float16 lds[2][32768];
  const int tid = threadIdx.x;
  const int bid = blockIdx.x;
  const float sc = 1.f / 16384.f;

  if (bid < 768) {
    // ================== main 256x256 path ==================
    const int supM = bid & 15;
    const int supN = bid >> 4;          // 0..47
    const int w = tid >> 6, lane = tid & 63;
    const int wm = w >> 2, wn = w & 3;
    const int lr = lane & 15, g16 = lane >> 4;

    f32x4 acc[8][4];
#pragma unroll
    for (int i = 0; i < 8; ++i)
#pragma unroll
      for (int j = 0; j < 4; ++j) acc[i][j] = (f32x4){0.f, 0.f, 0.f, 0.f};

    const size_t Ab0 = (size_t)(2 * supM) * KSTEPS * 8192;
    const size_t Ab1 = Ab0 + (size_t)KSTEPS * 8192;
    const size_t Bb0 = (size_t)(2 * supN) * KSTEPS * 8192;
    const size_t Bb1 = Bb0 + (size_t)KSTEPS * 8192;
    const int so = tid * 8;

#define STG(KS, BUF)                                                           \
  {                                                                            \
    const size_t ko = (size_t)(KS) * 8192;                                     \
    gload_lds16(Ap + Ab0 + ko + so,        &lds[BUF][so]);                     \
    gload_lds16(Ap + Ab0 + ko + so + 4096, &lds[BUF][so + 4096]);              \
    gload_lds16(Ap + Ab1 + ko + so,        &lds[BUF][8192 + so]);              \
    gload_lds16(Ap + Ab1 + ko + so + 4096, &lds[BUF][8192 + so + 4096]);       \
    gload_lds16(Bp + Bb0 + ko + so,        &lds[BUF][16384 + so]);             \
    gload_lds16(Bp + Bb0 + ko + so + 4096, &lds[BUF][16384 + so + 4096]);      \
    gload_lds16(Bp + Bb1 + ko + so,        &lds[BUF][24576 + so]);             \
    gload_lds16(Bp + Bb1 + ko + so + 4096, &lds[BUF][24576 + so + 4096]);      \
  }

    STG(0, 0);
    asm volatile("s_waitcnt vmcnt(0)" ::: "memory");
    __builtin_amdgcn_sched_barrier(0);
    __builtin_amdgcn_s_barrier();
    __builtin_amdgcn_sched_barrier(0);

    const int aoffB = wm * 8192 + lr * 8 + g16 * 1024;
    const int boffB = 16384 + (wn >> 1) * 8192 + ((wn & 1) * 64 + lr) * 8 + g16 * 1024;

    for (int kstep = 0; kstep < KSTEPS; ++kstep) {
      const int p = kstep & 1;
      if (kstep + 1 < KSTEPS) STG(kstep + 1, p ^ 1);

      v8h ah[8], al[8];
#pragma unroll
      for (int mb = 0; mb < 8; ++mb) {
        ah[mb] = *(const v8h*)&lds[p][aoffB + mb * 128];
        al[mb] = *(const v8h*)&lds[p][aoffB + mb * 128 + 4096];
      }
      __builtin_amdgcn_s_setprio(1);
#pragma unroll
      for (int nt = 0; nt < 4; ++nt) {
        v8h bh = *(const v8h*)&lds[p][boffB + nt * 128];
        v8h bl = *(const v8h*)&lds[p][boffB + nt * 128 + 4096];
#pragma unroll
        for (int mb = 0; mb < 8; ++mb) {
          MFMA3(acc[mb][nt], ah[mb], al[mb], bh, bl);
        }
      }
      __builtin_amdgcn_s_setprio(0);
      asm volatile("s_waitcnt vmcnt(0)" ::: "memory");
      __builtin_amdgcn_sched_barrier(0);
      __builtin_amdgcn_s_barrier();
      __builtin_amdgcn_sched_barrier(0);
    }
#undef STG

#pragma unroll
    for (int mb = 0; mb < 8; ++mb) {
#pragma unroll
      for (int nt = 0; nt < 4; ++nt) {
        int col = supN * 256 + wn * 64 + nt * 16 + lr;
#pragma unroll
        for (int r = 0; r < 4; ++r) {
          int row = supM * 256 + wm * 128 + mb * 16 + g16 * 4 + r;
          float v = acc[mb][nt][r] * sc;
          if (col < QKVW) Cq[(size_t)row * QKVW + col] = v;
          else            Cg[(size_t)row * GW + (col - QKVW)] = v;
        }
      }
    }
  } else {
    // ================== tail: ntile 96, two 128x128 tiles per block ==================
    const int tb = bid - 768;           // 0..15
    const int half = tid >> 8;          // 0/1: which 128-tile
    const int htid = tid & 255;
    const int mtile = tb * 2 + half;
    const int hb = half * 16384;        // LDS half base (halfs)
    const int wid = (tid >> 6) & 3, lane = tid & 63;
    const int wm = wid >> 1, wn = wid & 1;
    const int lrow = lane & 15, g = lane >> 4;

    f32x4 acc[4][4];
#pragma unroll
    for (int i = 0; i < 4; ++i)
#pragma unroll
      for (int j = 0; j < 4; ++j) acc[i][j] = (f32x4){0.f, 0.f, 0.f, 0.f};

    const int aoff = hb + (wm * 64 + lrow) * 8 + g * 1024;
    const int boff = hb + 8192 + (wn * 64 + lrow) * 8 + g * 1024;

    const _Float16* Asrc = Ap + ((size_t)(mtile * KSTEPS) * 2) * 4096 + htid * 8;
    const _Float16* Bsrc = Bp + ((size_t)(96 * KSTEPS) * 2) * 4096 + htid * 8;

#define STAGET(KS, BUF)                                                        \
  {                                                                            \
    const _Float16* An_ = Asrc + (size_t)(KS) * 8192;                          \
    const _Float16* Bn_ = Bsrc + (size_t)(KS) * 8192;                          \
    _Pragma("unroll")                                                          \
    for (int r = 0; r < 4; ++r) {                                              \
      gload_lds16(An_ + r * 2048, &lds[BUF][hb + r * 2048 + htid * 8]);        \
      gload_lds16(Bn_ + r * 2048, &lds[BUF][hb + 8192 + r * 2048 + htid * 8]); \
    }                                                                          \
  }

    STAGET(0, 0);
    STAGET(1, 1);

    for (int kstep = 0; kstep < KSTEPS; ++kstep) {
      const int p = kstep & 1;
      if (kstep + 1 < KSTEPS) {
        asm volatile("s_waitcnt vmcnt(8)" ::: "memory");
      } else {
        asm volatile("s_waitcnt vmcnt(0)" ::: "memory");
      }
      __builtin_amdgcn_sched_barrier(0);
      __builtin_amdgcn_s_barrier();
      __builtin_amdgcn_sched_barrier(0);

      v8h ah[4], al[4], bh[4], bl[4];
#pragma unroll
      for (int f = 0; f < 4; ++f) {
        ah[f] = *(const v8h*)&lds[p][aoff + f * 128];
        al[f] = *(const v8h*)&lds[p][aoff + 4096 + f * 128];
        bh[f] = *(const v8h*)&lds[p][boff + f * 128];
        bl[f] = *(const v8h*)&lds[p][boff + 4096 + f * 128];
      }
#pragma unroll
      for (int fm = 0; fm < 4; ++fm)
#pragma unroll
        for (int fn = 0; fn < 4; ++fn) {
          MFMA3(acc[fm][fn], ah[fm], al[fm], bh[fn], bl[fn]);
        }
      __builtin_amdgcn_sched_barrier(0);
      __builtin_amdgcn_s_barrier();
      __builtin_amdgcn_sched_barrier(0);
      if (kstep + 2 < KSTEPS) STAGET(kstep + 2, p);
    }
#undef STAGET

#pragma unroll
    for (int fm = 0; fm < 4; ++fm) {
      int row = mtile * 128 + wm * 64 + fm * 16 + g * 4;
#pragma unroll
      for (int fn = 0; fn < 4; ++fn) {
        int col = 96 * 128 + wn * 64 + fn * 16 + lrow;
        if (col < NPROJ) {
          int lcol = col - QKVW;   // tail cols all >= QKVW
#pragma unroll
          for (int r = 0; r < 4; ++r)
            Cg[(size_t)(row + r) * GW + lcol] = acc[fm][fn][r] * sc;
        }
      }
    }
  }
}

// ------------- conv+silu+l2norm for q/k -> PRE-SPLIT fp16 hi/lo, pre-swizzled table layout -------------
__global__ __launch_bounds__(64) void conv_qk_k(
    const float* __restrict__ projQKV, const float* __restrict__ Wc,
    _Float16* __restrict__ qh, _Float16* __restrict__ ql,
    _Float16* __restrict__ kh, _Float16* __restrict__ kl)
{
  const int b = blockIdx.z, hg = blockIdx.y, tc = blockIdx.x;
  const int lane = threadIdx.x;
  const int ch = hg * 128 + lane * 2;
  float4 Wa = *(const float4*)(Wc + (size_t)ch * 4);
  float4 Wb = *(const float4*)(Wc + (size_t)ch * 4 + 4);
  const int t0 = tc * 64;
  const float* P = projQKV + (size_t)b * L_SEQ * QKVW + ch;
  float2 w0 = make_float2(0.f, 0.f), w1 = w0, w2 = w0;
  if (t0 >= 3) w0 = *(const float2*)(P + (size_t)(t0 - 3) * QKVW);
  if (t0 >= 2) w1 = *(const float2*)(P + (size_t)(t0 - 2) * QKVW);
  if (t0 >= 1) w2 = *(const float2*)(P + (size_t)(t0 - 1) * QKVW);
  const bool isq = hg < 16;
  const int h = isq ? hg : hg - 16;
  _Float16* dh = (isq ? qh : kh) + (((size_t)b * NH + h) * L_SEQ) * 128;
  _Float16* dl = (isq ? ql : kl) + (((size_t)b * NH + h) * L_SEQ) * 128;
  const float sc = (isq ? 0.08838834764831845f : 1.f) * 1024.f;
  for (int t = t0; t < t0 + 64; ++t) {
    float2 x = *(const float2*)(P + (size_t)t * QKVW);
    float y0 = w0.x * Wa.x + w1.x * Wa.y + w2.x * Wa.z + x.x * Wa.w;
    float y1 = w0.y * Wb.x + w1.y * Wb.y + w2.y * Wb.z + x.y * Wb.w;
    w0 = w1; w1 = w2; w2 = x;
    y0 = y0 / (1.f + expf(-y0));
    y1 = y1 / (1.f + expf(-y1));
    float ss = y0 * y0 + y1 * y1;
#pragma unroll
    for (int off = 1; off < 64; off <<= 1) ss += __shfl_xor(ss, off);
    float nrm = sc / sqrtf(ss + 1e-6f);
    unsigned short h0, l0, h1, l1;
    splitw(y0 * nrm, h0, l0);
    splitw(y1 * nrm, h1, l1);
    int idx = t * 128 + ((lane * 2) ^ ((t & 7) << 3));
    *(unsigned int*)&dh[idx] = (unsigned int)h0 | ((unsigned int)h1 << 16);
    *(unsigned int*)&dl[idx] = (unsigned int)l0 | ((unsigned int)l1 << 16);
  }
}

// ------------- conv+silu for v: elementwise, float4 per thread -------------
__global__ __launch_bounds__(256) void conv_v_k(
    const float* __restrict__ projQKV, const float* __restrict__ Wc,
    float* __restrict__ vn)
{
  const int b = blockIdx.z, cg = blockIdx.y, tc = blockIdx.x;
  const int vc = (cg * 256 + threadIdx.x) * 4;
  const int ch = 4096 + vc;
  float4 Wv0 = *(const float4*)(Wc + (size_t)ch * 4);
  float4 Wv1 = *(const float4*)(Wc + (size_t)ch * 4 + 4);
  float4 Wv2 = *(const float4*)(Wc + (size_t)ch * 4 + 8);
  float4 Wv3 = *(const float4*)(Wc + (size_t)ch * 4 + 12);
  const int t0 = tc * 64;
  const float* P = projQKV + (size_t)b * L_SEQ * QKVW + ch;
  float4 w0 = make_float4(0.f, 0.f, 0.f, 0.f), w1 = w0, w2 = w0;
  if (t0 >= 3) w0 = *(const float4*)(P + (size_t)(t0 - 3) * QKVW);
  if (t0 >= 2) w1 = *(const float4*)(P + (size_t)(t0 - 2) * QKVW);
  if (t0 >= 1) w2 = *(const float4*)(P + (size_t)(t0 - 1) * QKVW);
  const int h = vc >> 8, vcol = vc & 255;
  float* dst = vn + (((size_t)b * NH + h) * L_SEQ) * HVD + vcol;
  for (int t = t0; t < t0 + 64; ++t) {
    float4 x = *(const float4*)(P + (size_t)t * QKVW);
    float4 y;
    y.x = w0.x * Wv0.x + w1.x * Wv0.y + w2.x * Wv0.z + x.x * Wv0.w;
    y.y = w0.y * Wv1.x + w1.y * Wv1.y + w2.y * Wv1.z + x.y * Wv1.w;
    y.z = w0.z * Wv2.x + w1.z * Wv2.y + w2.z * Wv2.z + x.z * Wv2.w;
    y.w = w0.w * Wv3.x + w1.w * Wv3.y + w2.w * Wv3.z + x.w * Wv3.w;
    w0 = w1; w1 = w2; w2 = x;
    y.x = y.x / (1.f + expf(-y.x));
    y.y = y.y / (1.f + expf(-y.y));
    y.z = y.z / (1.f + expf(-y.z));
    y.w = y.w / (1.f + expf(-y.w));
    *(float4*)(dst + (size_t)t * HVD) = y;
  }
}

// ------------- beta = sigmoid(b), g = -exp(A_log)*softplus(A+dt_bias) -------------
__global__ __launch_bounds__(256) void beta_g_k(
    const float* __restrict__ projGate, const float* __restrict__ A_log,
    const float* __restrict__ dt_bias, float* __restrict__ beta, float* __restrict__ g_out)
{
  int idx = blockIdx.x * 256 + threadIdx.x;
  if (idx >= 2 * NH * L_SEQ) return;
  int t = idx & (L_SEQ - 1);
  int h = (idx >> 11) & (NH - 1);
  int b = idx >> 15;
  size_t row = (size_t)(b * L_SEQ + t) * GW;
  float bv = projGate[row + 4096 + h];
  float av = projGate[row + 4112 + h];
  float be = 1.f / (1.f + expf(-bv));
  float xx = av + dt_bias[h];
  float sp = (xx > 20.f) ? xx : log1pf(expf(xx));
  float g = -expf(A_log[h]) * sp;
  beta[idx] = be;
  g_out[idx] = g;
}

// ------------- Phase 1 (fused): T=(I+A)^-1, Hq, KT, coef — gload-staged pre-split q/k -------------
__global__ __launch_bounds__(256) void p1_k(
    const _Float16* __restrict__ kh_g, const _Float16* __restrict__ kl_g,
    const _Float16* __restrict__ qh_g, const _Float16* __restrict__ ql_g,
    const float* __restrict__ g_arr, const float* __restrict__ beta_arr,
    _Float16* __restrict__ Tg_h, _Float16* __restrict__ Tg_l,
    _Float16* __restrict__ Hg_h, _Float16* __restrict__ Hg_l,
    _Float16* __restrict__ KTg_h, _Float16* __restrict__ KTg_l,
    float* __restrict__ coefG)
{
  __shared__ _Float16 Kh[8192], Kl[8192];
  __shared__ _Float16 QS[16384];
  __shared__ float lc[64], be[64], kw[64];
  _Float16* Qh = QS;
  _Float16* Ql = QS + 8192;
  float* Am = (float*)QS;
  float* Tm = Am + 4096;
  const int cid = blockIdx.x, bh = cid >> 5, ch = cid & 31, t0 = ch * 64;
  const int tid = threadIdx.x, w = tid >> 6, lane = tid & 63, lr = lane & 15, g16 = lane >> 4;

  const size_t gb = ((size_t)bh * 2048 + t0) * 128;
#pragma unroll
  for (int l = 0; l < 4; ++l) {
    int i = (tid + l * 256) * 8;
    gload_lds16(kh_g + gb + i, &Kh[i]);
    gload_lds16(kl_g + gb + i, &Kl[i]);
    gload_lds16(qh_g + gb + i, &Qh[i]);
    gload_lds16(ql_g + gb + i, &Ql[i]);
  }
  if (tid < 64) {
    float x = g_arr[(size_t)bh * 2048 + t0 + tid];
#pragma unroll
    for (int off = 1; off < 64; off <<= 1) { float y = __shfl_up(x, off); if (tid >= off) x += y; }
    lc[tid] = x;
    float x63 = __shfl(x, 63);
    float b_ = beta_arr[(size_t)bh * 2048 + t0 + tid];
    be[tid] = b_;
    kw[tid] = expf(x63 - x);
    float ca = expf(x);
    coefG[(size_t)cid * 192 + tid] = ca;
    coefG[(size_t)cid * 192 + 64 + tid] = b_;
    coefG[(size_t)cid * 192 + 128 + tid] = b_ * ca;
  }
  __syncthreads();
  const float ds20 = 1.f / 1048576.f;
  const int arow = w * 16 + lr, swa = (arow & 7) << 3;
  f32x4 gacc[4];
  for (int nt = 0; nt < 4; ++nt) {
    f32x4 acc = (f32x4){0.f, 0.f, 0.f, 0.f};
    int nrow = nt * 16 + lr, swn = (nrow & 7) << 3;
#pragma unroll
    for (int ks = 0; ks < 4; ++ks) {
      int c = ks * 32 + g16 * 8;
      v8h ah = *(const v8h*)&Kh[arow * 128 + (c ^ swa)];
      v8h al = *(const v8h*)&Kl[arow * 128 + (c ^ swa)];
      v8h bhh = *(const v8h*)&Kh[nrow * 128 + (c ^ swn)];
      v8h bll = *(const v8h*)&Kl[nrow * 128 + (c ^ swn)];
      MFMA3(acc, ah, al, bhh, bll);
    }
    gacc[nt] = acc;
  }
  for (int nt = 0; nt < 4; ++nt) {
    f32x4 acc = (f32x4){0.f, 0.f, 0.f, 0.f};
    int nrow = nt * 16 + lr, swn = (nrow & 7) << 3;
#pragma unroll
    for (int ks = 0; ks < 4; ++ks) {
      int c = ks * 32 + g16 * 8;
      v8h ah = *(const v8h*)&Qh[arow * 128 + (c ^ swa)];
      v8h al = *(const v8h*)&Ql[arow * 128 + (c ^ swa)];
      v8h bhh = *(const v8h*)&Kh[nrow * 128 + (c ^ swn)];
      v8h bll = *(const v8h*)&Kl[nrow * 128 + (c ^ swn)];
      MFMA3(acc, ah, al, bhh, bll);
    }
    int s_ = nt * 16 + lr;
#pragma unroll
    for (int r = 0; r < 4; ++r) {
      int t = w * 16 + g16 * 4 + r;
      float hv = (s_ <= t) ? acc[r] * ds20 * expf(lc[t] - lc[s_]) : 0.f;
      unsigned short hh, ll; splitw(hv * 16384.f, hh, ll);
      size_t go = (size_t)cid * 4096 + t * 64 + (s_ ^ ((t & 7) << 3));
      *(unsigned short*)&Hg_h[go] = hh;
      *(unsigned short*)&Hg_l[go] = ll;
    }
  }
  __syncthreads();
  for (int nt = 0; nt < 4; ++nt) {
    int s_ = nt * 16 + lr;
#pragma unroll
    for (int r = 0; r < 4; ++r) {
      int t = w * 16 + g16 * 4 + r;
      float av = (s_ < t) ? gacc[nt][r] * ds20 * be[t] * expf(lc[t] - lc[s_]) : 0.f;
      Am[t * 64 + s_] = av;
    }
  }
#pragma unroll
  for (int l = 0; l < 16; ++l) { int s2 = tid + l * 256; Tm[s2] = ((s2 >> 6) == (s2 & 63)) ? 1.f : 0.f; }
  for (int s = tid; s < 8192; s += 256) {
    int feat = s >> 6, t = s & 63;
    int ki = t * 128 + (feat ^ ((t & 7) << 3));
    float kvv = ((float)Kh[ki] + (float)Kl[ki]) * kw[t];
    unsigned short hh, ll; splitw(kvv, hh, ll);
    size_t go = (size_t)cid * 8192 + feat * 64 + (t ^ ((feat & 7) << 3));
    *(unsigned short*)&KTg_h[go] = hh;
    *(unsigned short*)&KTg_l[go] = ll;
  }
  __syncthreads();
  if (w == 0) {
    int j = lane;
    for (int t = 1; t < 64; ++t) {
      float sum = 0.f;
      for (int s = 0; s < t; ++s) sum = fmaf(Am[t * 64 + s], Tm[s * 64 + j], sum);
      Tm[t * 64 + j] = ((j == t) ? 1.f : 0.f) - sum;
    }
  }
  __syncthreads();
#pragma unroll
  for (int l = 0; l < 16; ++l) {
    int s2 = tid + l * 256;
    int t = s2 >> 6, sc_ = s2 & 63;
    unsigned short hh, ll; splitw(Tm[s2] * 256.f, hh, ll);
    size_t go = (size_t)cid * 4096 + t * 64 + (sc_ ^ ((t & 7) << 3));
    *(unsigned short*)&Tg_h[go] = hh;
    *(unsigned short*)&Tg_l[go] = ll;
  }
}

// ------------- Phase 2: sequential chunk scan, VW=32, 256 blocks, 5 barriers/chunk -------------
__global__ __launch_bounds__(256) void p2_k(
    const _Float16* __restrict__ qh_g, const _Float16* __restrict__ ql_g,
    const _Float16* __restrict__ kh_g, const _Float16* __restrict__ kl_g,
    const float* __restrict__ vn, const float* __restrict__ projGate,
    const _Float16* __restrict__ Tg_h, const _Float16* __restrict__ Tg_l,
    const _Float16* __restrict__ Hg_h, const _Float16* __restrict__ Hg_l,
    const _Float16* __restrict__ KTg_h, const _Float16* __restrict__ KTg_l,
    const float* __restrict__ coefG, float* __restrict__ out)
{
  __shared__ _Float16 St_h[4096], St_l[4096];
  __shared__ _Float16 KQ0[8192], KQ1[8192];
  __shared__ _Float16 KK0[8192], KK1[8192];
  __shared__ _Float16 KTs_h[8192], KTs_l[8192];
  __shared__ _Float16 Ts_h[4096], Ts_l[4096];
  __shared__ _Float16 Hs_h[4096], Hs_l[4096];
  __shared__ float cf[192];

  const int blk = blockIdx.x;
  const int vb = blk >> 5, bh = blk & 31;
  const int b = bh >> 4, h = bh & 15, v0 = vb * 32;
  const int tid = threadIdx.x, w = tid >> 6, lane = tid & 63, lr = lane & 15, g16 = lane >> 4;

  _Float16* BT_h = &KQ0[0];
  _Float16* BT_l = &KQ0[4096];
  _Float16* UT_h = &KQ1[0];
  _Float16* UT_l = &KQ1[4096];

#pragma unroll
  for (int l = 0; l < 8; ++l) { ((unsigned int*)St_h)[tid + l * 256] = 0u; }
#pragma unroll
  for (int l = 0; l < 8; ++l) { ((unsigned int*)St_l)[tid + l * 256] = 0u; }

  const float* gp = projGate + ((size_t)b * 2048) * GW + h * 256 + v0;
  const float i2_16 = 1.f / 65536.f;
  const float i2_20 = 1.f / 1048576.f;
  const float uscale = 1.f / 256.f;
  const float sscale = 64.f / 65536.f;

  for (int ch = 0; ch < 32; ++ch) {
    const int cid = bh * 32 + ch, t0 = ch * 64;
    {
      const _Float16* th = Tg_h + (size_t)cid * 4096;
      const _Float16* tl = Tg_l + (size_t)cid * 4096;
      const _Float16* hh = Hg_h + (size_t)cid * 4096;
      const _Float16* hl = Hg_l + (size_t)cid * 4096;
      const _Float16* kth = KTg_h + (size_t)cid * 8192;
      const _Float16* ktl = KTg_l + (size_t)cid * 8192;
      const size_t gb = ((size_t)bh * 2048 + t0) * 128;
#pragma unroll
      for (int l = 0; l < 2; ++l) {
        int i = (tid + l * 256) * 8;
        gload_lds16(th + i, &Ts_h[i]);
        gload_lds16(tl + i, &Ts_l[i]);
        gload_lds16(hh + i, &Hs_h[i]);
        gload_lds16(hl + i, &Hs_l[i]);
      }
#pragma unroll
      for (int l = 0; l < 4; ++l) {
        int i = (tid + l * 256) * 8;
        gload_lds16(kth + i, &KTs_h[i]);
        gload_lds16(ktl + i, &KTs_l[i]);
        gload_lds16(qh_g + gb + i, &KQ0[i]);
        gload_lds16(ql_g + gb + i, &KQ1[i]);
        gload_lds16(kh_g + gb + i, &KK0[i]);
        gload_lds16(kl_g + gb + i, &KK1[i]);
      }
      if (tid < 48) gload_lds16(coefG + (size_t)cid * 192 + tid * 4, &cf[tid * 4]);
    }
    float Vv[2][4];
#pragma unroll
    for (int nt = 0; nt < 2; ++nt)
#pragma unroll
      for (int r = 0; r < 4; ++r)
        Vv[nt][r] = vn[((size_t)bh * 2048 + t0 + w * 16 + g16 * 4 + r) * 256 + v0 + nt * 16 + lr];
    __syncthreads();
    const float cc = cf[63];
    const int arow = w * 16 + lr, swa = (arow & 7) << 3;
    f32x4 Oacc[2];
    {
      for (int nt = 0; nt < 2; ++nt) {
        f32x4 acc = (f32x4){0.f, 0.f, 0.f, 0.f};
        const int n = nt * 16 + lr, swn = (n & 7) << 3;
#pragma unroll
        for (int ks = 0; ks < 4; ++ks) {
          int c = ks * 32 + g16 * 8;
          v8h ah = *(const v8h*)&KQ0[arow * 128 + (c ^ swa)];
          v8h al = *(const v8h*)&KQ1[arow * 128 + (c ^ swa)];
          v8h bhh = *(const v8h*)&St_h[n * 128 + (c ^ swn)];
          v8h bll = *(const v8h*)&St_l[n * 128 + (c ^ swn)];
          MFMA3(acc, ah, al, bhh, bll);
        }
        Oacc[nt] = acc;
      }
      float4 cav = *(float4*)&cf[w * 16 + g16 * 4];
#pragma unroll
      for (int nt = 0; nt < 2; ++nt) {
        Oacc[nt][0] *= cav.x * 16.f; Oacc[nt][1] *= cav.y * 16.f;
        Oacc[nt][2] *= cav.z * 16.f; Oacc[nt][3] *= cav.w * 16.f;
      }
    }
    ushort4 pBh[2], pBl[2];
    {
      float4 cb1v = *(float4*)&cf[64 + w * 16 + g16 * 4];
      float4 cb2v = *(float4*)&cf[128 + w * 16 + g16 * 4];
      for (int nt = 0; nt < 2; ++nt) {
        f32x4 acc = (f32x4){0.f, 0.f, 0.f, 0.f};
        const int n = nt * 16 + lr, swn = (n & 7) << 3;
#pragma unroll
        for (int ks = 0; ks < 4; ++ks) {
          int c = ks * 32 + g16 * 8;
          v8h ah = *(const v8h*)&KK0[arow * 128 + (c ^ swa)];
          v8h al = *(const v8h*)&KK1[arow * 128 + (c ^ swa)];
          v8h bhh = *(const v8h*)&St_h[n * 128 + (c ^ swn)];
          v8h bll = *(const v8h*)&St_l[n * 128 + (c ^ swn)];
          MFMA3(acc, ah, al, bhh, bll);
        }
        float cb1a[4] = {cb1v.x, cb1v.y, cb1v.z, cb1v.w};
        float cb2a[4] = {cb2v.x, cb2v.y, cb2v.z, cb2v.w};
        unsigned short* ph = (unsigned short*)&pBh[nt];
        unsigned short* pl = (unsigned short*)&pBl[nt];
#pragma unroll
        for (int r = 0; r < 4; ++r) {
          float kv = acc[r] * i2_16;
          float Bv = cb1a[r] * Vv[nt][r] - cb2a[r] * kv;
          splitw(Bv * 64.f, ph[r], pl[r]);
        }
      }
    }
    __syncthreads();
    {
      const int tb = w * 16 + g16 * 4;
      for (int nt = 0; nt < 2; ++nt) {
        const int n = nt * 16 + lr, swn = (n & 7) << 3;
        int ad = n * 64 + (tb ^ swn);
        *(ushort4*)&BT_h[ad] = pBh[nt];
        *(ushort4*)&BT_l[ad] = pBl[nt];
      }
    }
    __syncthreads();
    {
      const int tb = w * 16 + g16 * 4;
      for (int nt = 0; nt < 2; ++nt) {
        f32x4 acc = (f32x4){0.f, 0.f, 0.f, 0.f};
        const int n = nt * 16 + lr, swn = (n & 7) << 3;
#pragma unroll
        for (int ks = 0; ks < 2; ++ks) {
          int c = ks * 32 + g16 * 8;
          v8h ah = *(const v8h*)&Ts_h[arow * 64 + (c ^ swa)];
          v8h al = *(const v8h*)&Ts_l[arow * 64 + (c ^ swa)];
          v8h bhh = *(const v8h*)&BT_h[n * 64 + (c ^ swn)];
          v8h bll = *(const v8h*)&BT_l[n * 64 + (c ^ swn)];
          MFMA3(acc, ah, al, bhh, bll);
        }
        ushort4 H, L;
        unsigned short* ph = (unsigned short*)&H;
        unsigned short* pl = (unsigned short*)&L;
#pragma unroll
        for (int r = 0; r < 4; ++r) splitw(acc[r] * uscale, ph[r], pl[r]);
        int ad = n * 64 + (tb ^ swn);
        *(ushort4*)&UT_h[ad] = H;
        *(ushort4*)&UT_l[ad] = L;
      }
    }
    __syncthreads();
    {
      for (int nt = 0; nt < 2; ++nt) {
        const int n = nt * 16 + lr, swn = (n & 7) << 3;
#pragma unroll
        for (int ks = 0; ks < 2; ++ks) {
          int c = ks * 32 + g16 * 8;
          v8h ah = *(const v8h*)&Hs_h[arow * 64 + (c ^ swa)];
          v8h al = *(const v8h*)&Hs_l[arow * 64 + (c ^ swa)];
          v8h bhh = *(const v8h*)&UT_h[n * 64 + (c ^ swn)];
          v8h bll = *(const v8h*)&UT_l[n * 64 + (c ^ swn)];
          MFMA3(Oacc[nt], ah, al, bhh, bll);
        }
      }
      for (int nt = 0; nt < 2; ++nt) {
        const int n = nt * 16 + lr;
#pragma unroll
        for (int r = 0; r < 4; ++r) {
          int t = t0 + w * 16 + g16 * 4 + r;
          float Ov = Oacc[nt][r] * i2_20;
          float gv = gp[(size_t)t * GW + n];
          out[((size_t)b * 2048 + t) * 4096 + h * 256 + v0 + n] = Ov * (gv / (1.f + expf(-gv)));
        }
      }
      const float cc1024 = cc * 1024.f;
#pragma unroll
      for (int m2 = w * 2; m2 < w * 2 + 2; ++m2) {
        const int ar2 = m2 * 16 + lr, swa2 = (ar2 & 7) << 3;
        const int fb = m2 * 16 + g16 * 4;
        for (int nt = 0; nt < 2; ++nt) {
          const int n = nt * 16 + lr, swn = (n & 7) << 3;
          int sad = n * 128 + (fb ^ swn);
          ushort4 sh4 = *(ushort4*)&St_h[sad];
          ushort4 sl4 = *(ushort4*)&St_l[sad];
          f32x4 acc;
          acc[0] = cc1024 * (h2f(sh4.x) + h2f(sl4.x));
          acc[1] = cc1024 * (h2f(sh4.y) + h2f(sl4.y));
          acc[2] = cc1024 * (h2f(sh4.z) + h2f(sl4.z));
          acc[3] = cc1024 * (h2f(sh4.w) + h2f(sl4.w));
#pragma unroll
          for (int ks = 0; ks < 2; ++ks) {
            int c = ks * 32 + g16 * 8;
            v8h ah = *(const v8h*)&KTs_h[ar2 * 64 + (c ^ swa2)];
            v8h al = *(const v8h*)&KTs_l[ar2 * 64 + (c ^ swa2)];
            v8h bhh = *(const v8h*)&UT_h[n * 64 + (c ^ swn)];
            v8h bll = *(const v8h*)&UT_l[n * 64 + (c ^ swn)];
            MFMA3(acc, ah, al, bhh, bll);
          }
          ushort4 H, L;
          unsigned short* ph = (unsigned short*)&H;
          unsigned short* pl = (unsigned short*)&L;
#pragma unroll
          for (int r = 0; r < 4; ++r) splitw(acc[r] * sscale, ph[r], pl[r]);
          *(ushort4*)&St_h[sad] = H;
          *(ushort4*)&St_l[sad] = L;
        }
      }
    }
    __syncthreads();
  }
}

extern "C" void kernel_launch(void* const* d_in, const int* in_sizes, int n_in,
                              void* d_out, int out_size, void* d_ws, size_t ws_size,
                              hipStream_t stream) {
  const float* hidden  = (const float*)d_in[0];
  const float* W       = (const float*)d_in[1];
  const float* Wc      = (const float*)d_in[2];
  const float* A_log   = (const float*)d_in[3];
  const float* dt_bias = (const float*)d_in[4];
  float* out = (float*)d_out;

  char* ws = (char*)d_ws;
  _Float16* Ap = (_Float16*)ws;
  _Float16* Bp = (_Float16*)(ws + (size_t)33554432);
  _Float16* qh = (_Float16*)ws;
  _Float16* ql = (_Float16*)(ws + (size_t)16777216);
  _Float16* kh = (_Float16*)(ws + (size_t)33554432);
  _Float16* kl = (_Float16*)(ws + (size_t)50331648);
  float* vn    = (float*)(ws + (size_t)67108864);
  float* g_arr = (float*)(ws + (size_t)134217728);
  float* beta  = (float*)(ws + (size_t)134479872);
  float* projQKV = (float*)(ws + (size_t)135266304);
  char*  tb0 = ws + (size_t)135266304;
  _Float16* Tg_h  = (_Float16*)tb0;
  _Float16* Tg_l  = (_Float16*)(tb0 + (size_t)8388608);
  _Float16* Hg_h  = (_Float16*)(tb0 + (size_t)16777216);
  _Float16* Hg_l  = (_Float16*)(tb0 + (size_t)25165824);
  _Float16* KTg_h = (_Float16*)(tb0 + (size_t)33554432);
  _Float16* KTg_l = (_Float16*)(tb0 + (size_t)50331648);
  float*    coefG = (float*)   (tb0 + (size_t)67108864);
  float* projGate = (float*)(ws + (size_t)269484032);

  pack_A_k<<<32 * KSTEPS, 256, 0, stream>>>(hidden, Ap);
  pack_B_k<<<NTILE_N * KSTEPS, 256, 0, stream>>>(W, Bp);
  gemm256_k<<<784, 512, 0, stream>>>(Ap, Bp, projQKV, projGate);

  conv_qk_k<<<dim3(32, 32, 2), 64, 0, stream>>>(projQKV, Wc, qh, ql, kh, kl);
  conv_v_k<<<dim3(32, 4, 2), 256, 0, stream>>>(projQKV, Wc, vn);
  beta_g_k<<<(2 * NH * L_SEQ + 255) / 256, 256, 0, stream>>>(projGate, A_log, dt_bias, beta, g_arr);

  p1_k<<<1024, 256, 0, stream>>>(kh, kl, qh, ql, g_arr, beta, Tg_h, Tg_l, Hg_h, Hg_l, KTg_h, KTg_l, coefG);
  p2_k<<<256, 256, 0, stream>>>(qh, ql, kh, kl, vn, projGate, Tg_h, Tg_l, Hg_h, Hg_l, KTg_h, KTg_l, coefG, out);
}